// Round 9
// baseline (316.927 us; speedup 1.0000x reference)
//
#include <hip/hip_runtime.h>
#include <hip/hip_bf16.h>
#include <cstdint>
#include <cstddef>

typedef __bf16 bf16;
typedef unsigned short ushort_t;
typedef __attribute__((ext_vector_type(8))) __bf16 bf16x8;
typedef __attribute__((ext_vector_type(4))) __bf16 bf16x4;
typedef __attribute__((ext_vector_type(4))) float f32x4;

#define NB 2
#define NS 2048
#define ND 768
#define NH 12
#define NF 3072
#define NT (NB * NS)   // 4096 tokens

__device__ __forceinline__ f32x4 mfma16(bf16x8 a, bf16x8 b, f32x4 c) {
  return __builtin_amdgcn_mfma_f32_16x16x32_bf16(a, b, c, 0, 0, 0);
}

__device__ __forceinline__ void gl_lds16(const bf16* g, bf16* l) {
  __builtin_amdgcn_global_load_lds(
      (__attribute__((address_space(1))) void*)(uintptr_t)g,
      (__attribute__((address_space(3))) void*)l,
      16, 0, 0);
}

// Bijective XCD-chunked swizzle (m204).
__device__ __forceinline__ int xcd_swz(int lin, int nwg) {
  const int q = nwg >> 3, r = nwg & 7;
  const int x = lin & 7, i = lin >> 3;
  return (x < r ? x * (q + 1) : r * (q + 1) + (x - r) * q) + i;
}

// gelu(x) ~= x * sigmoid(2*0.79788456*(x + 0.044715 x^3)); |err| < ~3e-3
__device__ __forceinline__ float gelu_fast(float v) {
  const float u = v * (0.7978845608028654f + 0.03567740814f * v * v);
  const float e = exp2f(u * 2.885390081777927f);  // e^(2u)
  return v - v / (1.f + e);                       // v*e/(1+e)
}

// ---------------- dtype sniffer (flag=1 -> I/O is float32) ----------------
__global__ __launch_bounds__(256) void sniff_kernel(
    const ushort_t* __restrict__ x, int* __restrict__ flag) {
  __shared__ int s[4];
  int bad = 0;
  for (int i = threadIdx.x; i < 4096; i += 256) {
    const int e = (x[i] >> 7) & 0xFF;
    bad |= (e >= 0xC0);
  }
  bad = __any(bad) ? 1 : 0;
  if ((threadIdx.x & 63) == 0) s[threadIdx.x >> 6] = bad;
  __syncthreads();
  if (threadIdx.x == 0) *flag = s[0] | s[1] | s[2] | s[3];
}

// ---------------- merged weight/bias conversion (1 launch) ----------------
struct CvtArgs {
  const void* s[8];
  bf16* d[8];
  int n8[8];
  int total8;
};

__global__ __launch_bounds__(256) void cvt_all(CvtArgs a,
                                               const int* __restrict__ flag) {
  const int isf = *flag;
  const int stride = gridDim.x * 256;
  for (int i = blockIdx.x * 256 + threadIdx.x; i < a.total8; i += stride) {
    int seg = 0, off = i;
    while (off >= a.n8[seg]) { off -= a.n8[seg]; ++seg; }
    bf16x8 o;
    if (isf) {
      const float* s = (const float*)a.s[seg] + (size_t)off * 8;
      const f32x4 f0 = *(const f32x4*)s;
      const f32x4 f1 = *(const f32x4*)(s + 4);
#pragma unroll
      for (int j = 0; j < 4; ++j) {
        o[j] = (bf16)f0[j];
        o[4 + j] = (bf16)f1[j];
      }
    } else {
      o = *((const bf16x8*)a.s[seg] + off);
    }
    *((bf16x8*)a.d[seg] + off) = o;
  }
}

// ---------------- LayerNorm: one wave per row of 768; output bf16 ---------
__global__ __launch_bounds__(256) void ln_kernel(
    const void* __restrict__ xv, const void* __restrict__ wv,
    const void* __restrict__ bv, bf16* __restrict__ y,
    const int* __restrict__ flag) {
  const int isf = *flag;
  const int row = blockIdx.x * 4 + (threadIdx.x >> 6);
  const int L = threadIdx.x & 63;
  const float* xf = (const float*)xv;
  const bf16* xh = (const bf16*)xv;
  const float* wf = (const float*)wv;
  const bf16* wh = (const bf16*)wv;
  const float* bf_ = (const float*)bv;
  const bf16* bh = (const bf16*)bv;
  const size_t base = (size_t)row * ND;
  float v[12];
  float s = 0.f, s2 = 0.f;
#pragma unroll
  for (int i = 0; i < 12; ++i) {
    const int c = L + i * 64;
    v[i] = isf ? xf[base + c] : (float)xh[base + c];
    s += v[i];
    s2 += v[i] * v[i];
  }
#pragma unroll
  for (int off = 1; off < 64; off <<= 1) {
    s += __shfl_xor(s, off);
    s2 += __shfl_xor(s2, off);
  }
  const float mean = s * (1.f / 768.f);
  const float var = s2 * (1.f / 768.f) - mean * mean;
  const float rstd = rsqrtf(var + 1e-5f);
  bf16* yr = y + base;
#pragma unroll
  for (int i = 0; i < 12; ++i) {
    const int c = L + i * 64;
    const float ww = isf ? wf[c] : (float)wh[c];
    const float bb = isf ? bf_[c] : (float)bh[c];
    yr[c] = (bf16)((v[i] - mean) * rstd * ww + bb);
  }
}

// ---------------- V transpose kernel (fallback only) ----------------------
__global__ __launch_bounds__(256) void vt_kernel(
    const bf16* __restrict__ qkv, bf16* __restrict__ vT) {
  const int bh = blockIdx.y;
  const int b = bh / NH, h = bh % NH;
  const int st = blockIdx.x;
  __shared__ bf16 Vs[64 * 72];
  const int tid = threadIdx.x;
  {
    const int r = tid >> 2, c = (tid & 3) * 16;
    const bf16* src =
        qkv + (size_t)(b * NS + st * 64 + r) * (3 * ND) + 2 * ND + h * 64 + c;
    *(bf16x8*)&Vs[r * 72 + c] = *(const bf16x8*)src;
    *(bf16x8*)&Vs[r * 72 + c + 8] = *(const bf16x8*)(src + 8);
  }
  __syncthreads();
  {
    const int hd = tid >> 2, t0 = (tid & 3) * 16;
    bf16x8 o0, o1;
#pragma unroll
    for (int j = 0; j < 8; ++j) {
      o0[j] = Vs[(t0 + j) * 72 + hd];
      o1[j] = Vs[(t0 + 8 + j) * 72 + hd];
    }
    bf16* dst = vT + ((size_t)bh * 64 + hd) * NS + st * 64 + t0;
    *(bf16x8*)dst = o0;
    *(bf16x8*)(dst + 8) = o1;
  }
}

// ---------------- gemm64: 64x128 tile, BK=64 --------------------------------
template <int EPI>
__global__ __launch_bounds__(256) void gemm64(
    const bf16* __restrict__ A, const bf16* __restrict__ Bt,
    const bf16* __restrict__ bias, const void* resid, void* C,
    int N, int K, int row0, const int* __restrict__ flag) {
  constexpr int NBUF = 3;
  __shared__ bf16 As[NBUF][64 * 64];
  __shared__ bf16 Bs[NBUF][128 * 64];
  int isf = 0;
  if (EPI == 2) {
    isf = *flag;
    asm volatile("" ::"s"(isf));
  }
  const int tid = threadIdx.x;
  const int w = tid >> 6, L = tid & 63;
  const int lg = L >> 4, lc = L & 15;
  const int wm = (w >> 1) * 32, wn = (w & 1) * 64;
  const int nwg = gridDim.x * gridDim.y;
  const int lin = xcd_swz(blockIdx.y * gridDim.x + blockIdx.x, nwg);
  const int bm = lin / gridDim.x, bn = lin % gridDim.x;

  const bf16* Ab = A + (size_t)bm * 64 * K;
  const bf16* Bb = Bt + (size_t)bn * 128 * K;

  const int srw = tid >> 3;                      // dest row 0..31 per load
  const int scw = ((tid & 7) ^ (srw & 7)) * 8;   // pre-swizzled source col

  f32x4 acc[2][4];
#pragma unroll
  for (int i = 0; i < 2; ++i)
#pragma unroll
    for (int j = 0; j < 4; ++j) acc[i][j] = (f32x4){0.f, 0.f, 0.f, 0.f};

#define G64_STAGE(buf, kk)                                                  \
  do {                                                                      \
    gl_lds16(Ab + (size_t)srw * K + (kk) + scw, As[buf] + tid * 8);         \
    gl_lds16(Ab + (size_t)(srw + 32) * K + (kk) + scw,                      \
             As[buf] + 2048 + tid * 8);                                     \
    gl_lds16(Bb + (size_t)srw * K + (kk) + scw, Bs[buf] + tid * 8);         \
    gl_lds16(Bb + (size_t)(srw + 32) * K + (kk) + scw,                      \
             Bs[buf] + 2048 + tid * 8);                                     \
    gl_lds16(Bb + (size_t)(srw + 64) * K + (kk) + scw,                      \
             Bs[buf] + 4096 + tid * 8);                                     \
    gl_lds16(Bb + (size_t)(srw + 96) * K + (kk) + scw,                      \
             Bs[buf] + 6144 + tid * 8);                                     \
  } while (0)

#define G64_COMP(cb)                                                        \
  do {                                                                      \
    bf16x8 af[2][2], bfr[2][4];                                             \
    _Pragma("unroll") for (int kk2 = 0; kk2 < 2; ++kk2) {                   \
      _Pragma("unroll") for (int mt = 0; mt < 2; ++mt) {                    \
        const int ra = wm + mt * 16 + lc;                                   \
        af[kk2][mt] = *(const bf16x8*)&As[cb][ra * 64 +                     \
                                             (((kk2 * 4 + lg) ^ (ra & 7))   \
                                              << 3)];                       \
      }                                                                     \
      _Pragma("unroll") for (int nt = 0; nt < 4; ++nt) {                    \
        const int rb = wn + nt * 16 + lc;                                   \
        bfr[kk2][nt] = *(const bf16x8*)&Bs[cb][rb * 64 +                    \
                                              (((kk2 * 4 + lg) ^ (rb & 7))  \
                                               << 3)];                      \
      }                                                                     \
    }                                                                       \
    _Pragma("unroll") for (int kk2 = 0; kk2 < 2; ++kk2)                     \
        _Pragma("unroll") for (int mt = 0; mt < 2; ++mt)                    \
            _Pragma("unroll") for (int nt = 0; nt < 4; ++nt)                \
                acc[mt][nt] = mfma16(af[kk2][mt], bfr[kk2][nt],             \
                                     acc[mt][nt]);                          \
  } while (0)

  const int nk = K >> 6;
  G64_STAGE(0, 0);
  int cur = 0, stg = 1;
  int k = 0;
  for (; k < nk - 1; ++k) {
    G64_STAGE(stg, (k + 1) * 64);
    asm volatile("s_waitcnt vmcnt(6)" ::: "memory");
    asm volatile("s_barrier" ::: "memory");
    G64_COMP(cur);
    cur = (cur + 1 == NBUF) ? 0 : cur + 1;
    stg = (stg + 1 == NBUF) ? 0 : stg + 1;
  }
  __syncthreads();  // drain last stage (vmcnt(0) + barrier)
  G64_COMP(cur);
#undef G64_STAGE
#undef G64_COMP

  const float* rf = (const float*)resid;
  const bf16* rh = (const bf16*)resid;
  float* Cf = (float*)C;
  bf16* Ch = (bf16*)C;
#pragma unroll
  for (int mt = 0; mt < 2; ++mt) {
#pragma unroll
    for (int nt = 0; nt < 4; ++nt) {
      const int col = bn * 128 + wn + nt * 16 + lc;
      const float bv = (float)bias[col];
#pragma unroll
      for (int r = 0; r < 4; ++r) {
        const int row = bm * 64 + wm + mt * 16 + lg * 4 + r;
        float v = acc[mt][nt][r] + bv;
        if (EPI == 1) v = gelu_fast(v);
        const size_t idx = (size_t)(row0 + row) * N + col;
        if (EPI == 2) {
          v += isf ? rf[idx] : (float)rh[idx];
          if (isf) Cf[idx] = v; else Ch[idx] = (bf16)v;
        } else {
          Ch[idx] = (bf16)v;
        }
      }
    }
  }
}

// ---------------- fast GEMM (TM=128): counted-vmcnt + T2 swizzle ----------
template <int EPI, int TM>
__global__ __launch_bounds__(256) void gemm_fast(
    const bf16* __restrict__ A, const bf16* __restrict__ Bt,
    const bf16* __restrict__ bias, const void* resid, void* C,
    int N, int K, int row0, const int* __restrict__ flag) {
  constexpr int NBUF = (TM == 64) ? 5 : 3;
  constexpr int LOOK = NBUF - 2;
  constexpr int MT = TM / 32;
  __shared__ bf16 As[NBUF][TM * 32];
  __shared__ bf16 Bs[NBUF][128 * 32];
  int isf = 0;
  if (EPI == 2) {
    isf = *flag;
    asm volatile("" ::"s"(isf));
  }
  const int tid = threadIdx.x;
  const int w = tid >> 6, L = tid & 63;
  const int lg = L >> 4, lc = L & 15;
  const int lgx = (lg ^ ((lc >> 1) & 3)) * 8;
  const int wm = (w >> 1) * (TM / 2), wn = (w & 1) * 64;
  const int nwg = gridDim.x * gridDim.y;
  const int lin = xcd_swz(blockIdx.y * gridDim.x + blockIdx.x, nwg);
  const int bm = lin / gridDim.x, bn = lin % gridDim.x;

  const bf16* Ab = A + (size_t)bm * TM * K;
  const bf16* Bb = Bt + (size_t)bn * 128 * K;

  const int sr = tid >> 2;
  const int sc = ((tid & 3) ^ ((tid >> 3) & 3)) * 8;

  f32x4 acc[MT][4];
#pragma unroll
  for (int i = 0; i < MT; ++i)
#pragma unroll
    for (int j = 0; j < 4; ++j) acc[i][j] = (f32x4){0.f, 0.f, 0.f, 0.f};

#define GF_STAGE(buf, kk)                                                   \
  do {                                                                      \
    gl_lds16(Ab + (size_t)sr * K + (kk) + sc, As[buf] + tid * 8);           \
    if (TM == 128)                                                          \
      gl_lds16(Ab + (size_t)(sr + 64) * K + (kk) + sc,                      \
               As[buf] + 2048 + tid * 8);                                   \
    gl_lds16(Bb + (size_t)sr * K + (kk) + sc, Bs[buf] + tid * 8);           \
    gl_lds16(Bb + (size_t)(sr + 64) * K + (kk) + sc,                        \
             Bs[buf] + 2048 + tid * 8);                                     \
  } while (0)

#define GF_COMP(cb)                                                         \
  do {                                                                      \
    bf16x8 af[MT], bfr[4];                                                  \
    _Pragma("unroll") for (int mt = 0; mt < MT; ++mt) af[mt] =              \
        *(const bf16x8*)&As[cb][(wm + mt * 16 + lc) * 32 + lgx];            \
    _Pragma("unroll") for (int nt = 0; nt < 4; ++nt) bfr[nt] =              \
        *(const bf16x8*)&Bs[cb][(wn + nt * 16 + lc) * 32 + lgx];            \
    _Pragma("unroll") for (int mt = 0; mt < MT; ++mt)                       \
        _Pragma("unroll") for (int nt = 0; nt < 4; ++nt) acc[mt][nt] =      \
            mfma16(af[mt], bfr[nt], acc[mt][nt]);                           \
  } while (0)

  const int nk = K >> 5;
#pragma unroll
  for (int s = 0; s < LOOK; ++s)
    if (s < nk) GF_STAGE(s, s * 32);
  int cur = 0, stg = LOOK;
  int k = 0;
  const int kmain = (nk > LOOK) ? nk - LOOK : 0;
  for (; k < kmain; ++k) {
    GF_STAGE(stg, (k + LOOK) * 32);
    if (TM == 64)
      asm volatile("s_waitcnt vmcnt(9)" ::: "memory");
    else
      asm volatile("s_waitcnt vmcnt(4)" ::: "memory");
    asm volatile("s_barrier" ::: "memory");
    GF_COMP(cur);
    cur = (cur + 1 == NBUF) ? 0 : cur + 1;
    stg = (stg + 1 == NBUF) ? 0 : stg + 1;
  }
  __syncthreads();
  for (; k < nk; ++k) {
    GF_COMP(cur);
    cur = (cur + 1 == NBUF) ? 0 : cur + 1;
  }
#undef GF_STAGE
#undef GF_COMP

  const float* rf = (const float*)resid;
  const bf16* rh = (const bf16*)resid;
  float* Cf = (float*)C;
  bf16* Ch = (bf16*)C;
#pragma unroll
  for (int mt = 0; mt < MT; ++mt) {
#pragma unroll
    for (int nt = 0; nt < 4; ++nt) {
      const int col = bn * 128 + wn + nt * 16 + lc;
      const float bv = (float)bias[col];
#pragma unroll
      for (int r = 0; r < 4; ++r) {
        const int row = bm * TM + wm + mt * 16 + lg * 4 + r;
        float v = acc[mt][nt][r] + bv;
        if (EPI == 1) v = gelu_fast(v);
        const size_t idx = (size_t)(row0 + row) * N + col;
        if (EPI == 2) {
          v += isf ? rf[idx] : (float)rh[idx];
          if (isf) Cf[idx] = v; else Ch[idx] = (bf16)v;
        } else {
          Ch[idx] = (bf16)v;
        }
      }
    }
  }
}

// ---------------- QKV GEMM with fused V-transpose epilogue ----------------
__global__ __launch_bounds__(256) void gemm_qkv(
    const bf16* __restrict__ A, const bf16* __restrict__ Bt,
    const bf16* __restrict__ bias, bf16* __restrict__ qkvout,
    bf16* __restrict__ vT) {
  const int K = ND, N = 3 * ND;
  constexpr int NBUF = 3;
  constexpr int LOOK = 1;
  __shared__ bf16 As[NBUF][128 * 32];
  __shared__ bf16 Bs[NBUF][128 * 32];
  const int tid = threadIdx.x;
  const int w = tid >> 6, L = tid & 63;
  const int lg = L >> 4, lc = L & 15;
  const int lgx = (lg ^ ((lc >> 1) & 3)) * 8;
  const int wm = (w >> 1) * 64, wn = (w & 1) * 64;
  const int nwg = gridDim.x * gridDim.y;
  const int lin = xcd_swz(blockIdx.y * gridDim.x + blockIdx.x, nwg);
  const int bm = lin / gridDim.x, bn = lin % gridDim.x;

  const bf16* Ab = A + (size_t)bm * 128 * K;
  const bf16* Bb = Bt + (size_t)bn * 128 * K;

  const int sr = tid >> 2;
  const int sc = ((tid & 3) ^ ((tid >> 3) & 3)) * 8;

  f32x4 acc[4][4];
#pragma unroll
  for (int i = 0; i < 4; ++i)
#pragma unroll
    for (int j = 0; j < 4; ++j) acc[i][j] = (f32x4){0.f, 0.f, 0.f, 0.f};

#define QKV_STAGE(buf, kk)                                                  \
  do {                                                                      \
    gl_lds16(Ab + (size_t)sr * K + (kk) + sc, As[buf] + tid * 8);           \
    gl_lds16(Ab + (size_t)(sr + 64) * K + (kk) + sc,                        \
             As[buf] + 2048 + tid * 8);                                     \
    gl_lds16(Bb + (size_t)sr * K + (kk) + sc, Bs[buf] + tid * 8);           \
    gl_lds16(Bb + (size_t)(sr + 64) * K + (kk) + sc,                        \
             Bs[buf] + 2048 + tid * 8);                                     \
  } while (0)

#define QKV_COMP(cb)                                                        \
  do {                                                                      \
    bf16x8 af[4], bfr[4];                                                   \
    _Pragma("unroll") for (int mt = 0; mt < 4; ++mt) af[mt] =               \
        *(const bf16x8*)&As[cb][(wm + mt * 16 + lc) * 32 + lgx];            \
    _Pragma("unroll") for (int nt = 0; nt < 4; ++nt) bfr[nt] =              \
        *(const bf16x8*)&Bs[cb][(wn + nt * 16 + lc) * 32 + lgx];            \
    _Pragma("unroll") for (int mt = 0; mt < 4; ++mt)                        \
        _Pragma("unroll") for (int nt = 0; nt < 4; ++nt) acc[mt][nt] =      \
            mfma16(af[mt], bfr[nt], acc[mt][nt]);                           \
  } while (0)

  const int nk = K >> 5;  // 24
  QKV_STAGE(0, 0);
  int cur = 0, stg = LOOK;
  int k = 0;
  const int kmain = nk - LOOK;
  for (; k < kmain; ++k) {
    QKV_STAGE(stg, (k + LOOK) * 32);
    asm volatile("s_waitcnt vmcnt(4)" ::: "memory");
    asm volatile("s_barrier" ::: "memory");
    QKV_COMP(cur);
    cur = (cur + 1 == NBUF) ? 0 : cur + 1;
    stg = (stg + 1 == NBUF) ? 0 : stg + 1;
  }
  __syncthreads();
  for (; k < nk; ++k) {
    QKV_COMP(cur);
    cur = (cur + 1 == NBUF) ? 0 : cur + 1;
  }
#undef QKV_STAGE
#undef QKV_COMP

#pragma unroll
  for (int mt = 0; mt < 4; ++mt) {
#pragma unroll
    for (int nt = 0; nt < 4; ++nt) {
      const int col = bn * 128 + wn + nt * 16 + lc;
      const float bv = (float)bias[col];
      if (col < 2 * ND) {  // Q or K -> qkv buffer
#pragma unroll
        for (int r = 0; r < 4; ++r) {
          const int row = bm * 128 + wm + mt * 16 + lg * 4 + r;
          qkvout[(size_t)row * N + col] = (bf16)(acc[mt][nt][r] + bv);
        }
      } else {  // V -> vT[bh][hd][token], 4 consecutive tokens per lane
        const int colv = col - 2 * ND;
        const int h_ = colv >> 6, hd = colv & 63;
        bf16x4 pk;
#pragma unroll
        for (int r = 0; r < 4; ++r) pk[r] = (bf16)(acc[mt][nt][r] + bv);
        const int tok0 = bm * 128 + wm + mt * 16 + lg * 4;
        const int b_ = tok0 >> 11, s0 = tok0 & (NS - 1);
        *(bf16x4*)&vT[((size_t)(b_ * NH + h_) * 64 + hd) * NS + s0] = pk;
      }
    }
  }
}

// ---------------- fallback GEMM (dtype-branch staging, round-3) -----------
template <int EPI>
__global__ __launch_bounds__(256) void gemm_bt(
    const bf16* __restrict__ A, const void* __restrict__ Bt,
    const void* __restrict__ bias, const void* resid, void* C,
    int N, int K, int row0, const int* __restrict__ flag) {
  __shared__ bf16 As[128 * 32];
  __shared__ bf16 Bs[128 * 32];
  const int isf = *flag;
  const int tid = threadIdx.x;
  const int w = tid >> 6, L = tid & 63;
  const int lg = L >> 4, lc = L & 15;
  const int wm = (w >> 1) * 64, wn = (w & 1) * 64;
  const int nwg = gridDim.x * gridDim.y;
  const int lin = xcd_swz(blockIdx.y * gridDim.x + blockIdx.x, nwg);
  const int bm = lin / gridDim.x, bn = lin % gridDim.x;

  const bf16* Ab = A + (size_t)bm * 128 * K;
  const bf16* Bth = (const bf16*)Bt + (size_t)bn * 128 * K;
  const float* Btf = (const float*)Bt + (size_t)bn * 128 * K;

  const int sr = tid >> 1;
  const int sc = (tid & 1) * 16;

  f32x4 acc[4][4];
#pragma unroll
  for (int i = 0; i < 4; ++i)
#pragma unroll
    for (int j = 0; j < 4; ++j) acc[i][j] = (f32x4){0.f, 0.f, 0.f, 0.f};

  for (int k0 = 0; k0 < K; k0 += 32) {
    const bf16* ap = Ab + (size_t)sr * K + k0 + sc;
    const bf16x8 a0 = *(const bf16x8*)ap;
    const bf16x8 a1 = *(const bf16x8*)(ap + 8);
    bf16x8 b0, b1;
    if (isf) {
      const float* bp = Btf + (size_t)sr * K + k0 + sc;
      const f32x4 f0 = *(const f32x4*)bp;
      const f32x4 f1 = *(const f32x4*)(bp + 4);
      const f32x4 f2 = *(const f32x4*)(bp + 8);
      const f32x4 f3 = *(const f32x4*)(bp + 12);
#pragma unroll
      for (int j = 0; j < 4; ++j) {
        b0[j] = (bf16)f0[j];
        b0[4 + j] = (bf16)f1[j];
        b1[j] = (bf16)f2[j];
        b1[4 + j] = (bf16)f3[j];
      }
    } else {
      const bf16* bp = Bth + (size_t)sr * K + k0 + sc;
      b0 = *(const bf16x8*)bp;
      b1 = *(const bf16x8*)(bp + 8);
    }
    __syncthreads();
    *(bf16x8*)&As[sr * 32 + sc] = a0;
    *(bf16x8*)&As[sr * 32 + sc + 8] = a1;
    *(bf16x8*)&Bs[sr * 32 + sc] = b0;
    *(bf16x8*)&Bs[sr * 32 + sc + 8] = b1;
    __syncthreads();

    bf16x8 af[4], bfr[4];
#pragma unroll
    for (int mt = 0; mt < 4; ++mt)
      af[mt] = *(const bf16x8*)&As[(wm + mt * 16 + lc) * 32 + lg * 8];
#pragma unroll
    for (int nt = 0; nt < 4; ++nt)
      bfr[nt] = *(const bf16x8*)&Bs[(wn + nt * 16 + lc) * 32 + lg * 8];
#pragma unroll
    for (int mt = 0; mt < 4; ++mt)
#pragma unroll
      for (int nt = 0; nt < 4; ++nt)
        acc[mt][nt] = mfma16(af[mt], bfr[nt], acc[mt][nt]);
  }

  const float* biasf = (const float*)bias;
  const bf16* biash = (const bf16*)bias;
  const float* rf = (const float*)resid;
  const bf16* rh = (const bf16*)resid;
  float* Cf = (float*)C;
  bf16* Ch = (bf16*)C;
#pragma unroll
  for (int mt = 0; mt < 4; ++mt) {
#pragma unroll
    for (int nt = 0; nt < 4; ++nt) {
      const int col = bn * 128 + wn + nt * 16 + lc;
      const float bv = isf ? biasf[col] : (float)biash[col];
#pragma unroll
      for (int r = 0; r < 4; ++r) {
        const int row = bm * 128 + wm + mt * 16 + lg * 4 + r;
        float v = acc[mt][nt][r] + bv;
        if (EPI == 1) v = gelu_fast(v);
        const size_t idx = (size_t)(row0 + row) * N + col;
        if (EPI == 2) {
          v += isf ? rf[idx] : (float)rh[idx];
          if (isf) Cf[idx] = v; else Ch[idx] = (bf16)v;
        } else {
          Ch[idx] = (bf16)v;
        }
      }
    }
  }
}

// ---------------- Flash attention v11: split-KV, 2 tiles per barrier ------
// r8 counters: flash_sp 47us with MfmaUtil 10%, VALUBusy 40%, occupancy
// ~2.2 blocks/CU effective -> each KV tile pays a full barrier+LDS-write
// serial window (~2300 cy). r9: stage TWO KV tiles (two LDS buffers) under
// ONE barrier pair, compute both back-to-back, prefetch next two during
// compute (the BK=32->64 lever that won 3x on the GEMMs). Mask logic
// unchanged (per sub-tile at ktv==qt). LDS 46.1KB -> 3 blocks/CU.
__global__ __launch_bounds__(128) void flash_attn_sp(
    const bf16* __restrict__ qkv, const bf16* __restrict__ vT,
    bf16* __restrict__ o, float* __restrict__ po, float* __restrict__ pl) {
  const int nwg = gridDim.x * gridDim.y;  // 1128 = 8 XCD * 141 (3 bh each)
  const int lin = xcd_swz(blockIdx.y * gridDim.x + blockIdx.x, nwg);
  const int bh = lin / 47;
  const int c = lin % 47;
  const int b = bh / NH, h = bh % NH;
  int qt, kt_lo, kt_hi, direct, cc = 0;
  if (c == 0) {
    qt = 16; kt_lo = 0; kt_hi = 16; direct = 1;
  } else if (c <= 30) {
    qt = 31 - ((c - 1) >> 1);
    const int hh = (qt + 1) >> 1;
    cc = (c - 1) & 1;
    if (cc) { kt_lo = hh; kt_hi = qt; }
    else    { kt_lo = 0;  kt_hi = hh - 1; }
    direct = 0;
  } else {
    qt = 46 - c; kt_lo = 0; kt_hi = qt; direct = 1;
  }
  const int q0 = qt * 64;
  const int tid = threadIdx.x;  // 128 threads = 2 waves
  const int w = tid >> 6, L = tid & 63;
  const int lg = L >> 4, lc = L & 15;

  __shared__ bf16 Ks[2][64 * 72];   // [tile-slot][kv][hd]
  __shared__ bf16 Vts[2][64 * 72];  // [tile-slot][hd][kv]
  __shared__ bf16 Ps[2][32 * 72];

  const float QSCALE = 0.18033688011112042f;  // (1/8) * log2(e)
  bf16x8 qf[2][2];
#pragma unroll
  for (int m = 0; m < 2; ++m) {
    const size_t tokq = (size_t)(b * NS + q0 + w * 32 + m * 16 + lc);
    const bf16* qp = qkv + tokq * (3 * ND) + h * 64 + lg * 8;
    const bf16x8 q0r = *(const bf16x8*)qp;
    const bf16x8 q1r = *(const bf16x8*)(qp + 32);
#pragma unroll
    for (int jj = 0; jj < 8; ++jj) {
      qf[m][0][jj] = (bf16)((float)q0r[jj] * QSCALE);
      qf[m][1][jj] = (bf16)((float)q1r[jj] * QSCALE);
    }
  }

  const int kr = tid >> 1, kc = (tid & 1) * 32;
  const bf16* kbase =
      qkv + (size_t)(b * NS + kr) * (3 * ND) + ND + h * 64 + kc;
  const bf16* vbase = vT + ((size_t)bh * 64 + kr) * NS + kc;

  f32x4 oacc[2][4];
#pragma unroll
  for (int m = 0; m < 2; ++m)
#pragma unroll
    for (int nt = 0; nt < 4; ++nt) oacc[m][nt] = (f32x4){0.f, 0.f, 0.f, 0.f};
  float lacc[2] = {0.f, 0.f};

  bf16x8 kreg[2][4], vreg[2][4];
#define FS_LOADREG(slot, ktv)                                               \
  do {                                                                      \
    const bf16* kn_ = kbase + (size_t)(ktv) * 64 * (3 * ND);                \
    const bf16* vn_ = vbase + (size_t)(ktv) * 64;                           \
    _Pragma("unroll") for (int p = 0; p < 4; ++p) {                         \
      kreg[slot][p] = *(const bf16x8*)(kn_ + p * 8);                        \
      vreg[slot][p] = *(const bf16x8*)(vn_ + p * 8);                        \
    }                                                                       \
  } while (0)

#define FS_COMPUTE(slot, ktv)                                               \
  do {                                                                      \
    f32x4 s[2][4];                                                          \
    __builtin_amdgcn_s_setprio(1);                                          \
    _Pragma("unroll") for (int nt = 0; nt < 4; ++nt) {                      \
      const bf16x8 kb0 =                                                    \
          *(const bf16x8*)&Ks[slot][(nt * 16 + lc) * 72 + lg * 8];          \
      const bf16x8 kb1 =                                                    \
          *(const bf16x8*)&Ks[slot][(nt * 16 + lc) * 72 + 32 + lg * 8];     \
      _Pragma("unroll") for (int m = 0; m < 2; ++m) {                       \
        f32x4 z = (f32x4){0.f, 0.f, 0.f, 0.f};                              \
        s[m][nt] = mfma16(kb0, qf[m][0], z);                                \
        s[m][nt] = mfma16(kb1, qf[m][1], s[m][nt]);                         \
      }                                                                     \
    }                                                                       \
    __builtin_amdgcn_s_setprio(0);                                          \
    if ((ktv) == qt) {                                                      \
      _Pragma("unroll") for (int m = 0; m < 2; ++m)                         \
          _Pragma("unroll") for (int nt = 0; nt < 4; ++nt)                  \
              _Pragma("unroll") for (int r = 0; r < 4; ++r) {               \
        const int kv = nt * 16 + lg * 4 + r;                                \
        const int qrow = w * 32 + m * 16 + lc;                              \
        if (kv > qrow) s[m][nt][r] = -1.0e30f;                              \
      }                                                                     \
    }                                                                       \
    _Pragma("unroll") for (int m = 0; m < 2; ++m)                           \
        _Pragma("unroll") for (int nt = 0; nt < 4; ++nt) {                  \
      bf16x4 pk;                                                            \
      _Pragma("unroll") for (int r = 0; r < 4; ++r) {                       \
        const float p = exp2f(fminf(s[m][nt][r], 20.f));                    \
        lacc[m] += p;                                                       \
        pk[r] = (bf16)p;                                                    \
      }                                                                     \
      *(bf16x4*)&Ps[w][(m * 16 + lc) * 72 + nt * 16 + lg * 4] = pk;         \
    }                                                                       \
    bf16x8 pa[2][2];                                                        \
    _Pragma("unroll") for (int m = 0; m < 2; ++m) {                         \
      pa[m][0] = *(const bf16x8*)&Ps[w][(m * 16 + lc) * 72 + lg * 8];       \
      pa[m][1] = *(const bf16x8*)&Ps[w][(m * 16 + lc) * 72 + 32 + lg * 8];  \
    }                                                                       \
    __builtin_amdgcn_s_setprio(1);                                          \
    _Pragma("unroll") for (int nt = 0; nt < 4; ++nt) {                      \
      const bf16x8 v0 =                                                     \
          *(const bf16x8*)&Vts[slot][(nt * 16 + lc) * 72 + lg * 8];         \
      const bf16x8 v1 =                                                     \
          *(const bf16x8*)&Vts[slot][(nt * 16 + lc) * 72 + 32 + lg * 8];    \
      _Pragma("unroll") for (int m = 0; m < 2; ++m) {                       \
        oacc[m][nt] = mfma16(pa[m][0], v0, oacc[m][nt]);                    \
        oacc[m][nt] = mfma16(pa[m][1], v1, oacc[m][nt]);                    \
      }                                                                     \
    }                                                                       \
    __builtin_amdgcn_s_setprio(0);                                          \
  } while (0)

  FS_LOADREG(0, kt_lo);
  if (kt_lo + 1 <= kt_hi) FS_LOADREG(1, kt_lo + 1);

  for (int kt = kt_lo; kt <= kt_hi; kt += 2) {
    const bool two = (kt + 1 <= kt_hi);
    __syncthreads();  // prior iteration's LDS reads done
#pragma unroll
    for (int p = 0; p < 4; ++p) {
      *(bf16x8*)&Ks[0][kr * 72 + kc + p * 8] = kreg[0][p];
      *(bf16x8*)&Vts[0][kr * 72 + kc + p * 8] = vreg[0][p];
    }
    if (two) {
#pragma unroll
      for (int p = 0; p < 4; ++p) {
        *(bf16x8*)&Ks[1][kr * 72 + kc + p * 8] = kreg[1][p];
        *(bf16x8*)&Vts[1][kr * 72 + kc + p * 8] = vreg[1][p];
      }
    }
    __syncthreads();  // both tiles staged

    if (kt + 2 <= kt_hi) FS_LOADREG(0, kt + 2);
    if (kt + 3 <= kt_hi) FS_LOADREG(1, kt + 3);

    FS_COMPUTE(0, kt);
    if (two) FS_COMPUTE(1, kt + 1);
  }
#undef FS_LOADREG
#undef FS_COMPUTE

#pragma unroll
  for (int m = 0; m < 2; ++m) {
    lacc[m] += __shfl_xor(lacc[m], 16);
    lacc[m] += __shfl_xor(lacc[m], 32);
  }

  if (direct) {
    float lr[2][4];
#pragma unroll
    for (int m = 0; m < 2; ++m)
#pragma unroll
      for (int r = 0; r < 4; ++r) lr[m][r] = __shfl(lacc[m], lg * 4 + r);
#pragma unroll
    for (int m = 0; m < 2; ++m)
#pragma unroll
      for (int nt = 0; nt < 4; ++nt)
#pragma unroll
        for (int r = 0; r < 4; ++r) {
          const int qrow = q0 + w * 32 + m * 16 + lg * 4 + r;
          const float val = oacc[m][nt][r] / lr[m][r];
          o[(size_t)(b * NS + qrow) * ND + h * 64 + nt * 16 + lc] =
              (bf16)val;
        }
  } else {
    const int slot = qt - 17;  // 0..14
    float* pob = po + (((size_t)(bh * 15 + slot)) * 2 + cc) * 4096;
#pragma unroll
    for (int m = 0; m < 2; ++m)
#pragma unroll
      for (int nt = 0; nt < 4; ++nt)
#pragma unroll
        for (int r = 0; r < 4; ++r) {
          const int row = w * 32 + m * 16 + lg * 4 + r;
          const int col = nt * 16 + lc;
          pob[row * 64 + col] = oacc[m][nt][r];
        }
    if (L < 16) {
      float* plb = pl + ((bh * 15 + slot) * 2 + cc) * 64;
      plb[w * 32 + L] = lacc[0];
      plb[w * 32 + 16 + L] = lacc[1];
    }
  }
}

// ---------------- attention partial combine (qt>=17 tiles) ----------------
__global__ __launch_bounds__(256) void attn_combine(
    const float* __restrict__ po, const float* __restrict__ pl,
    bf16* __restrict__ o) {
  const int slot = blockIdx.x;  // 0..14 -> qt = slot+17
  const int bh = blockIdx.y;    // 0..23
  const int qt = slot + 17;
  const int b = bh / NH, h = bh % NH;
  const float* poA = po + ((size_t)(bh * 15 + slot)) * 2 * 4096;
  const float* poB = poA + 4096;
  const float* plA = pl + (bh * 15 + slot) * 2 * 64;
  const float* plB = plA + 64;
  for (int e = threadIdx.x; e < 4096; e += 256) {
    const int q = e >> 6, hd = e & 63;
    const float val = (poA[e] + poB[e]) / (plA[q] + plB[q]);
    o[(size_t)(b * NS + qt * 64 + q) * ND + h * 64 + hd] = (bf16)val;
  }
}

// ---------------- Flash attention v9 (T2 tier: no partial workspace) ------
__global__ __launch_bounds__(128) void flash_attn_v7(
    const bf16* __restrict__ qkv, const bf16* __restrict__ vT,
    bf16* __restrict__ o) {
  const int nwg = gridDim.x * gridDim.y;  // 768 = 8 XCD * 96
  const int lin = xcd_swz(blockIdx.y * gridDim.x + blockIdx.x, nwg);
  const int xcd = lin / 96;
  const int i96 = lin % 96;
  const int bl = i96 >> 5;
  const int j = i96 & 31;
  const int bh = xcd * 3 + bl;
  const int b = bh / NH, h = bh % NH;
  int qt;
  if (bl == 0) qt = j;
  else if (bl == 1) qt = (j + 16) & 31;
  else qt = (j < 16) ? (31 - 2 * j) : (62 - 2 * j);
  const int q0 = qt * 64;
  const int tid = threadIdx.x;
  const int w = tid >> 6, L = tid & 63;
  const int lg = L >> 4, lc = L & 15;

  __shared__ bf16 Ks[2][64 * 72];
  __shared__ bf16 Vts[2][64 * 72];
  __shared__ bf16 Ps[2][32 * 72];

  const float QSCALE = 0.18033688011112042f;
  bf16x8 qf[2][2];
#pragma unroll
  for (int m = 0; m < 2; ++m) {
    const size_t tokq = (size_t)(b * NS + q0 + w * 32 + m * 16 + lc);
    const bf16* qp = qkv + tokq * (3 * ND) + h * 64 + lg * 8;
    const bf16x8 q0r = *(const bf16x8*)qp;
    const bf16x8 q1r = *(const bf16x8*)(qp + 32);
#pragma unroll
    for (int jj = 0; jj < 8; ++jj) {
      qf[m][0][jj] = (bf16)((float)q0r[jj] * QSCALE);
      qf[m][1][jj] = (bf16)((float)q1r[jj] * QSCALE);
    }
  }

  const int kr = tid >> 1, kc = (tid & 1) * 32;
  const bf16* kbase =
      qkv + (size_t)(b * NS + kr) * (3 * ND) + ND + h * 64 + kc;
  const bf16* vbase = vT + ((size_t)bh * 64 + kr) * NS + kc;

  f32x4 oacc[2][4];
#pragma unroll
  for (int m = 0; m < 2; ++m)
#pragma unroll
    for (int nt = 0; nt < 4; ++nt) oacc[m][nt] = (f32x4){0.f, 0.f, 0.f, 0.f};
  float lacc[2] = {0.f, 0.f};

  const int nkt = qt + 1;

  bf16x8 kreg[4], vreg[4];
#pragma unroll
  for (int p = 0; p < 4; ++p) {
    kreg[p] = *(const bf16x8*)(kbase + p * 8);
    vreg[p] = *(const bf16x8*)(vbase + p * 8);
  }
#pragma unroll
  for (int p = 0; p < 4; ++p) {
    *(bf16x8*)&Ks[0][kr * 72 + kc + p * 8] = kreg[p];
    *(bf16x8*)&Vts[0][kr * 72 + kc + p * 8] = vreg[p];
  }

  for (int kt = 0; kt < nkt; ++kt) {
    __syncthreads();
    const int cur = kt & 1;

    if (kt + 1 < nkt) {
      const bf16* kn = kbase + (size_t)(kt + 1) * 64 * (3 * ND);
      const bf16* vn = vbase + (size_t)(kt + 1) * 64;
#pragma unroll
      for (int p = 0; p < 4; ++p) {
        kreg[p] = *(const bf16x8*)(kn + p * 8);
        vreg[p] = *(const bf16x8*)(vn + p * 8);
      }
    }

    f32x4 s[2][4];
    __builtin_amdgcn_s_setprio(1);
#pragma unroll
    for (int nt = 0; nt < 4; ++nt) {
      const bf16x8 kb0 =
          *(const bf16x8*)&Ks[cur][(nt * 16 + lc) * 72 + lg * 8];
      const bf16x8 kb1 =
          *(const bf16x8*)&Ks[cur][(nt * 16 + lc) * 72 + 32 + lg * 8];
#pragma unroll
      for (int m = 0; m < 2; ++m) {
        f32x4 z = (f32x4){0.f, 0.f, 0.f, 0.f};
        s[m][nt] = mfma16(kb0, qf[m][0], z);
        s[m][nt] = mfma16(kb1, qf[m][1], s[m][nt]);
      }
    }
    __builtin_amdgcn_s_setprio(0);
    if (kt == nkt - 1) {
#pragma unroll
      for (int m = 0; m < 2; ++m)
#pragma unroll
        for (int nt = 0; nt < 4; ++nt)
#pragma unroll
          for (int r = 0; r < 4; ++r) {
            const int kv = nt * 16 + lg * 4 + r;
            const int qrow = w * 32 + m * 16 + lc;
            if (kv > qrow) s[m][nt][r] = -1.0e30f;
          }
    }
#pragma unroll
    for (int m = 0; m < 2; ++m)
#pragma unroll
      for (int nt = 0; nt < 4; ++nt) {
        bf16x4 pk;
#pragma unroll
        for (int r = 0; r < 4; ++r) {
          const float p = exp2f(fminf(s[m][nt][r], 20.f));
          lacc[m] += p;
          pk[r] = (bf16)p;
        }
        *(bf16x4*)&Ps[w][(m * 16 + lc) * 72 + nt * 16 + lg * 4] = pk;
      }
    bf16x8 pa[2][2];
#pragma unroll
    for (int m = 0; m < 2; ++m) {
      pa[m][0] = *(const bf16x8*)&Ps[w][(m * 16 + lc) * 72 + lg * 8];
      pa[m][1] = *(const bf16x8*)&Ps[w][(m * 16 + lc) * 72 + 32 + lg * 8];
    }

    if (kt + 1 < nkt) {
      const int nxt = cur ^ 1;
#pragma unroll
      for (int p = 0; p < 4; ++p) {
        *(bf16x8*)&Ks[nxt][kr * 72 + kc + p * 8] = kreg[p];
        *(bf16x8*)&Vts[nxt][kr * 72 + kc + p * 8] = vreg[p];
      }
    }

    __builtin_amdgcn_s_setprio(1);
#pragma unroll
    for (int nt = 0; nt < 4; ++nt) {
      const bf16x8 v0 =
          *(const bf16x8*)&Vts[cur][(nt * 16 + lc) * 72 + lg * 8];
      const bf16x8 v1 =
          *(const bf16x8*)&Vts[cur][(nt * 16 + lc) * 72 + 32 + lg * 8];
#pragma unroll
      for (int m = 0; m < 2; ++m) {
        oacc[m][nt] = mfma16(pa[m][0], v0, oacc[m][nt]);
        oacc[m][nt] = mfma16(pa[m][1], v1, oacc[m][nt]);
      }
    }
    __builtin_amdgcn_s_setprio(0);
  }

#pragma unroll
  for (int m = 0; m < 2; ++m) {
    lacc[m] += __shfl_xor(lacc[m], 16);
    lacc[m] += __shfl_xor(lacc[m], 32);
  }
  float lr[2][4];
#pragma unroll
  for (int m = 0; m < 2; ++m)
#pragma unroll
    for (int r = 0; r < 4; ++r) lr[m][r] = __shfl(lacc[m], lg * 4 + r);

#pragma unroll
  for (int m = 0; m < 2; ++m)
#pragma unroll
    for (int nt = 0; nt < 4; ++nt)
#pragma unroll
      for (int r = 0; r < 4; ++r) {
        const int qrow = q0 + w * 32 + m * 16 + lg * 4 + r;
        const float val = oacc[m][nt][r] / lr[m][r];
        o[(size_t)(b * NS + qrow) * ND + h * 64 + nt * 16 + lc] = (bf16)val;
      }
}

// ---------------- Flash attention v1 (fallback tiers, no vT) --------------
__global__ __launch_bounds__(256) void flash_attn_v1(
    const bf16* __restrict__ qkv, bf16* __restrict__ o) {
  const int bh = blockIdx.y;
  const int b = bh / NH, h = bh % NH;
  const int qt = gridDim.x - 1 - blockIdx.x;
  const int q0 = qt * 64;
  const int tid = threadIdx.x;
  const int w = tid >> 6, L = tid & 63;
  const int lg = L >> 4, lc = L & 15;

  __shared__ bf16 Ks[64 * 72];
  __shared__ bf16 Vts[64 * 72];
  __shared__ bf16 Ps[4][16 * 72];

  const float QSCALE = 0.18033688011112042f;
  const size_t tokq = (size_t)(b * NS + q0 + w * 16 + lc);
  const bf16* qp = qkv + tokq * (3 * ND) + h * 64 + lg * 8;
  const bf16x8 qr0 = *(const bf16x8*)qp;
  const bf16x8 qr1 = *(const bf16x8*)(qp + 32);
  bf16x8 qf0, qf1;
#pragma unroll
  for (int j = 0; j < 8; ++j) {
    qf0[j] = (bf16)((float)qr0[j] * QSCALE);
    qf1[j] = (bf16)((float)qr1[j] * QSCALE);
  }

  f32x4 oacc[4];
#pragma unroll
  for (int nt = 0; nt < 4; ++nt) oacc[nt] = (f32x4){0.f, 0.f, 0.f, 0.f};
  float lacc[4] = {0.f, 0.f, 0.f, 0.f};

  for (int kt = 0; kt <= qt; ++kt) {
    __syncthreads();
#pragma unroll
    for (int p = 0; p < 2; ++p) {
      const int r = (p * 256 + tid) >> 3;
      const int c = (tid & 7) * 8;
      const bf16* kp =
          qkv + (size_t)(b * NS + kt * 64 + r) * (3 * ND) + ND + h * 64 + c;
      const bf16x8 k8 = *(const bf16x8*)kp;
      *(bf16x8*)&Ks[r * 72 + c] = k8;
      const bf16x8 v8 = *(const bf16x8*)(kp + ND);
#pragma unroll
      for (int j = 0; j < 8; ++j) Vts[(c + j) * 72 + r] = v8[j];
    }
    __syncthreads();

    f32x4 s[4];
#pragma unroll
    for (int nt = 0; nt < 4; ++nt) {
      const bf16x8 b0 = *(const bf16x8*)&Ks[(nt * 16 + lc) * 72 + lg * 8];
      const bf16x8 b1 = *(const bf16x8*)&Ks[(nt * 16 + lc) * 72 + 32 + lg * 8];
      f32x4 z = (f32x4){0.f, 0.f, 0.f, 0.f};
      s[nt] = mfma16(qf0, b0, z);
      s[nt] = mfma16(qf1, b1, s[nt]);
    }
    if (kt == qt) {
#pragma unroll
      for (int nt = 0; nt < 4; ++nt)
#pragma unroll
        for (int r = 0; r < 4; ++r) {
          const int qrow = w * 16 + lg * 4 + r;
          const int kcol = nt * 16 + lc;
          if (kcol > qrow) s[nt][r] = -1.0e30f;
        }
    }
#pragma unroll
    for (int nt = 0; nt < 4; ++nt)
#pragma unroll
      for (int r = 0; r < 4; ++r) {
        const float p = exp2f(fminf(s[nt][r], 20.f));
        lacc[r] += p;
        Ps[w][(lg * 4 + r) * 72 + nt * 16 + lc] = (bf16)p;
      }
    __syncthreads();

    const bf16x8 p0 = *(const bf16x8*)&Ps[w][lc * 72 + lg * 8];
    const bf16x8 p1 = *(const bf16x8*)&Ps[w][lc * 72 + 32 + lg * 8];
#pragma unroll
    for (int nt = 0; nt < 4; ++nt) {
      const bf16x8 v0 = *(const bf16x8*)&Vts[(nt * 16 + lc) * 72 + lg * 8];
      const bf16x8 v1 = *(const bf16x8*)&Vts[(nt * 16 + lc) * 72 + 32 + lg * 8];
      oacc[nt] = mfma16(p0, v0, oacc[nt]);
      oacc[nt] = mfma16(p1, v1, oacc[nt]);
    }
  }

#pragma unroll
  for (int msk = 1; msk < 16; msk <<= 1)
#pragma unroll
    for (int r = 0; r < 4; ++r) lacc[r] += __shfl_xor(lacc[r], msk);

#pragma unroll
  for (int nt = 0; nt < 4; ++nt)
#pragma unroll
    for (int r = 0; r < 4; ++r) {
      const int qrow = q0 + w * 16 + lg * 4 + r;
      const float val = oacc[nt][r] / lacc[r];
      o[(size_t)(b * NS + qrow) * ND + h * 64 + nt * 16 + lc] = (bf16)val;
    }
}

// ---------------- launcher ----------------
extern "C" void kernel_launch(void* const* d_in, const int* in_sizes, int n_in,
                              void* d_out, int out_size, void* d_ws,
                              size_t ws_size, hipStream_t stream) {
  const void* x = d_in[0];
  const void* qkv_w = d_in[2];
  const void* qkv_b = d_in[3];
  const void* out_w = d_in[4];
  const void* out_b = d_in[5];
  const void* fc1_w = d_in[6];
  const void* fc1_b = d_in[7];
  const void* fc2_w = d_in[8];
  const void* fc2_b = d_in[9];
  const void* ln1_w = d_in[10];
  const void* ln1_b = d_in[11];
  const void* ln2_w = d_in[12];
  const void* ln2_b = d_in[13];
  (void)in_sizes; (void)n_in; (void)out_size;

  char* ws = (char*)d_ws;
  int* flag = (int*)ws;

  sniff_kernel<<<dim3(1), 256, 0, stream>>>((const ushort_t*)x, flag);

  const size_t T1 = 58210048, T2 = 51918592, T3 = 45627136, T4 = 39335680;

  if (ws_size >= T2) {
    bf16* wq = (bf16*)(ws + 256);
    bf16* wo = wq + 1769472;
    bf16* w1 = wo + 589824;
    bf16* w2 = w1 + 2359296;
    bf16* bq = w2 + 2359296;
    bf16* bo = bq + 2304;
    bf16* b1 = bo + 768;
    bf16* b2 = b1 + 3072;
    bf16* slotA = b2 + 768;
    bf16* vT = slotA + (size_t)NT * ND;
    bf16* slotB = vT + (size_t)NT * ND;
    bf16* hx = slotA, *oat = slotA, *h2 = slotA;
    bf16* qkv = slotB;
    float* po = (float*)(ws + 45627136);
    float* pl = po + (size_t)24 * 15 * 2 * 4096;
    const bool sp = ws_size >= T1;

    CvtArgs ca;
    ca.s[0] = qkv_w; ca.d[0] = wq; ca.n8[0] = 1769472 / 8;
    ca.s[1] = out_w; ca.d[1] = wo; ca.n8[1] = 589824 / 8;
    ca.s[2] = fc1_w; ca.d[2] = w1; ca.n8[2] = 2359296 / 8;
    ca.s[3] = fc2_w; ca.d[3] = w2; ca.n8[3] = 2359296 / 8;
    ca.s[4] = qkv_b; ca.d[4] = bq; ca.n8[4] = 2304 / 8;
    ca.s[5] = out_b; ca.d[5] = bo; ca.n8[5] = 768 / 8;
    ca.s[6] = fc1_b; ca.d[6] = b1; ca.n8[6] = 3072 / 8;
    ca.s[7] = fc2_b; ca.d[7] = b2; ca.n8[7] = 768 / 8;
    ca.total8 = (1769472 + 589824 + 2359296 + 2359296 + 2304 + 768 + 3072 +
                 768) / 8;
    cvt_all<<<dim3(880), 256, 0, stream>>>(ca, flag);

    ln_kernel<<<dim3(NT / 4), 256, 0, stream>>>(x, ln1_w, ln1_b, hx, flag);
    gemm_qkv<<<dim3(18, 32), 256, 0, stream>>>(hx, wq, bq, qkv, vT);
    if (sp) {
      flash_attn_sp<<<dim3(47, 24), 128, 0, stream>>>(qkv, vT, oat, po, pl);
      attn_combine<<<dim3(15, 24), 256, 0, stream>>>(po, pl, oat);
    } else {
      flash_attn_v7<<<dim3(NS / 64, NB * NH), 128, 0, stream>>>(qkv, vT, oat);
    }
    gemm64<2><<<dim3(6, 64), 256, 0, stream>>>(
        oat, wo, bo, x, d_out, ND, ND, 0, flag);
    ln_kernel<<<dim3(NT / 4), 256, 0, stream>>>(d_out, ln2_w, ln2_b, h2, flag);
    if (ws_size >= T1) {
      bf16* ff1 = slotB;
      gemm64<1><<<dim3(24, 64), 256, 0, stream>>>(
          h2, w1, b1, nullptr, ff1, NF, ND, 0, flag);
      gemm64<2><<<dim3(6, 64), 256, 0, stream>>>(
          ff1, w2, b2, d_out, d_out, ND, NF, 0, flag);
    } else {
      bf16* ff1c = slotB;
      for (int c = 0; c < 2; ++c) {
        gemm64<1><<<dim3(24, 32), 256, 0, stream>>>(
            h2 + (size_t)c * 2048 * ND, w1, b1, nullptr, ff1c, NF, ND, 0, flag);
        gemm64<2><<<dim3(6, 32), 256, 0, stream>>>(
            ff1c, w2, b2, d_out, d_out, ND, NF, c * 2048, flag);
      }
    }
  } else if (ws_size >= T4) {
    bf16* wq = (bf16*)(ws + 256);
    bf16* wo = wq + 1769472;
    bf16* w1 = wo + 589824;
    bf16* w2 = w1 + 2359296;
    bf16* bq = w2 + 2359296;
    bf16* bo = bq + 2304;
    bf16* b1 = bo + 768;
    bf16* b2 = b1 + 3072;
    bf16* slotA = b2 + 768;
    bf16* slotB = slotA + (size_t)NT * ND;
    bf16* hx = slotA, *oat = slotA, *h2 = slotA;
    bf16* qkv = slotB;

    CvtArgs ca;
    ca.s[0] = qkv_w; ca.d[0] = wq; ca.n8[0] = 1769472 / 8;
    ca.s[1] = out_w; ca.d[1] = wo; ca.n8[1] = 589824 / 8;
    ca.s[2] = fc1_w; ca.d[2] = w1; ca.n8[2] = 2359296 / 8;
    ca.s[3] = fc2_w; ca.d[3] = w2; ca.n8[3] = 2359296 / 8;
    ca.s[4] = qkv_b; ca.d[4] = bq; ca.n8[4] = 2304 / 8;
    ca.s[5] = out_b; ca.d[5] = bo; ca.n8[5] = 768 / 8;
    ca.s[6] = fc1_b; ca.d[6] = b1; ca.n8[6] = 3072 / 8;
    ca.s[7] = fc2_b; ca.d[7] = b2; ca.n8[7] = 768 / 8;
    ca.total8 = (1769472 + 589824 + 2359296 + 2359296 + 2304 + 768 + 3072 +
                 768) / 8;
    cvt_all<<<dim3(880), 256, 0, stream>>>(ca, flag);

    ln_kernel<<<dim3(NT / 4), 256, 0, stream>>>(x, ln1_w, ln1_b, hx, flag);
    gemm_fast<0, 128><<<dim3(18, 32), 256, 0, stream>>>(
        hx, wq, bq, nullptr, qkv, 3 * ND, ND, 0, flag);
    flash_attn_v1<<<dim3(NS / 64, NB * NH), 256, 0, stream>>>(qkv, oat);
    gemm64<2><<<dim3(6, 64), 256, 0, stream>>>(
        oat, wo, bo, x, d_out, ND, ND, 0, flag);
    ln_kernel<<<dim3(NT / 4), 256, 0, stream>>>(d_out, ln2_w, ln2_b, h2, flag);
    if (ws_size >= T3) {
      bf16* ff1 = slotB;
      gemm64<1><<<dim3(24, 64), 256, 0, stream>>>(
          h2, w1, b1, nullptr, ff1, NF, ND, 0, flag);
      gemm64<2><<<dim3(6, 64), 256, 0, stream>>>(
          ff1, w2, b2, d_out, d_out, ND, NF, 0, flag);
    } else {
      bf16* ff1c = slotB;
      for (int c = 0; c < 2; ++c) {
        gemm64<1><<<dim3(24, 32), 256, 0, stream>>>(
            h2 + (size_t)c * 2048 * ND, w1, b1, nullptr, ff1c, NF, ND, 0, flag);
        gemm64<2><<<dim3(6, 32), 256, 0, stream>>>(
            ff1c, w2, b2, d_out, d_out, ND, NF, c * 2048, flag);
      }
    }
  } else {
    const size_t szTD = (size_t)NT * ND * sizeof(bf16);
    bf16* slotA = (bf16*)(ws + 256);
    bf16* qkv = (bf16*)(ws + 256 + szTD);
    bf16* hx = slotA, *oat = slotA, *h2 = slotA;
    bf16* ff1c = qkv;

    ln_kernel<<<dim3(NT / 4), 256, 0, stream>>>(x, ln1_w, ln1_b, hx, flag);
    gemm_bt<0><<<dim3(18, 32), 256, 0, stream>>>(
        hx, qkv_w, qkv_b, nullptr, qkv, 3 * ND, ND, 0, flag);
    flash_attn_v1<<<dim3(NS / 64, NB * NH), 256, 0, stream>>>(qkv, oat);
    gemm_bt<2><<<dim3(6, 32), 256, 0, stream>>>(
        oat, out_w, out_b, x, d_out, ND, ND, 0, flag);
    ln_kernel<<<dim3(NT / 4), 256, 0, stream>>>(d_out, ln2_w, ln2_b, h2, flag);
    for (int c = 0; c < 4; ++c) {
      gemm_bt<1><<<dim3(24, 8), 256, 0, stream>>>(
          h2 + (size_t)c * 1024 * ND, fc1_w, fc1_b, nullptr, ff1c, NF, ND, 0,
          flag);
      gemm_bt<2><<<dim3(6, 8), 256, 0, stream>>>(
          ff1c, fc2_w, fc2_b, d_out, d_out, ND, NF, c * 1024, flag);
    }
  }
}

// Round 10
// 312.348 us; speedup vs baseline: 1.0147x; 1.0147x over previous
//
#include <hip/hip_runtime.h>
#include <hip/hip_bf16.h>
#include <cstdint>
#include <cstddef>

typedef __bf16 bf16;
typedef unsigned short ushort_t;
typedef __attribute__((ext_vector_type(8))) __bf16 bf16x8;
typedef __attribute__((ext_vector_type(4))) __bf16 bf16x4;
typedef __attribute__((ext_vector_type(4))) float f32x4;

#define NB 2
#define NS 2048
#define ND 768
#define NH 12
#define NF 3072
#define NT (NB * NS)   // 4096 tokens

__device__ __forceinline__ f32x4 mfma16(bf16x8 a, bf16x8 b, f32x4 c) {
  return __builtin_amdgcn_mfma_f32_16x16x32_bf16(a, b, c, 0, 0, 0);
}

__device__ __forceinline__ void gl_lds16(const bf16* g, bf16* l) {
  __builtin_amdgcn_global_load_lds(
      (__attribute__((address_space(1))) void*)(uintptr_t)g,
      (__attribute__((address_space(3))) void*)l,
      16, 0, 0);
}

// Bijective XCD-chunked swizzle (m204).
__device__ __forceinline__ int xcd_swz(int lin, int nwg) {
  const int q = nwg >> 3, r = nwg & 7;
  const int x = lin & 7, i = lin >> 3;
  return (x < r ? x * (q + 1) : r * (q + 1) + (x - r) * q) + i;
}

// gelu(x) ~= x * sigmoid(2*0.79788456*(x + 0.044715 x^3)); |err| < ~3e-3
__device__ __forceinline__ float gelu_fast(float v) {
  const float u = v * (0.7978845608028654f + 0.03567740814f * v * v);
  const float e = exp2f(u * 2.885390081777927f);  // e^(2u)
  return v - v / (1.f + e);                       // v*e/(1+e)
}

// ---------------- dtype sniffer (flag=1 -> I/O is float32) ----------------
__global__ __launch_bounds__(256) void sniff_kernel(
    const ushort_t* __restrict__ x, int* __restrict__ flag) {
  __shared__ int s[4];
  int bad = 0;
  for (int i = threadIdx.x; i < 4096; i += 256) {
    const int e = (x[i] >> 7) & 0xFF;
    bad |= (e >= 0xC0);
  }
  bad = __any(bad) ? 1 : 0;
  if ((threadIdx.x & 63) == 0) s[threadIdx.x >> 6] = bad;
  __syncthreads();
  if (threadIdx.x == 0) *flag = s[0] | s[1] | s[2] | s[3];
}

// ---------------- merged weight/bias conversion (1 launch) ----------------
struct CvtArgs {
  const void* s[8];
  bf16* d[8];
  int n8[8];
  int total8;
};

__global__ __launch_bounds__(256) void cvt_all(CvtArgs a,
                                               const int* __restrict__ flag) {
  const int isf = *flag;
  const int stride = gridDim.x * 256;
  for (int i = blockIdx.x * 256 + threadIdx.x; i < a.total8; i += stride) {
    int seg = 0, off = i;
    while (off >= a.n8[seg]) { off -= a.n8[seg]; ++seg; }
    bf16x8 o;
    if (isf) {
      const float* s = (const float*)a.s[seg] + (size_t)off * 8;
      const f32x4 f0 = *(const f32x4*)s;
      const f32x4 f1 = *(const f32x4*)(s + 4);
#pragma unroll
      for (int j = 0; j < 4; ++j) {
        o[j] = (bf16)f0[j];
        o[4 + j] = (bf16)f1[j];
      }
    } else {
      o = *((const bf16x8*)a.s[seg] + off);
    }
    *((bf16x8*)a.d[seg] + off) = o;
  }
}

// ---------------- LayerNorm: one wave per row of 768; output bf16 ---------
__global__ __launch_bounds__(256) void ln_kernel(
    const void* __restrict__ xv, const void* __restrict__ wv,
    const void* __restrict__ bv, bf16* __restrict__ y,
    const int* __restrict__ flag) {
  const int isf = *flag;
  const int row = blockIdx.x * 4 + (threadIdx.x >> 6);
  const int L = threadIdx.x & 63;
  const float* xf = (const float*)xv;
  const bf16* xh = (const bf16*)xv;
  const float* wf = (const float*)wv;
  const bf16* wh = (const bf16*)wv;
  const float* bf_ = (const float*)bv;
  const bf16* bh = (const bf16*)bv;
  const size_t base = (size_t)row * ND;
  float v[12];
  float s = 0.f, s2 = 0.f;
#pragma unroll
  for (int i = 0; i < 12; ++i) {
    const int c = L + i * 64;
    v[i] = isf ? xf[base + c] : (float)xh[base + c];
    s += v[i];
    s2 += v[i] * v[i];
  }
#pragma unroll
  for (int off = 1; off < 64; off <<= 1) {
    s += __shfl_xor(s, off);
    s2 += __shfl_xor(s2, off);
  }
  const float mean = s * (1.f / 768.f);
  const float var = s2 * (1.f / 768.f) - mean * mean;
  const float rstd = rsqrtf(var + 1e-5f);
  bf16* yr = y + base;
#pragma unroll
  for (int i = 0; i < 12; ++i) {
    const int c = L + i * 64;
    const float ww = isf ? wf[c] : (float)wh[c];
    const float bb = isf ? bf_[c] : (float)bh[c];
    yr[c] = (bf16)((v[i] - mean) * rstd * ww + bb);
  }
}

// ---------------- V transpose kernel (fallback only) ----------------------
__global__ __launch_bounds__(256) void vt_kernel(
    const bf16* __restrict__ qkv, bf16* __restrict__ vT) {
  const int bh = blockIdx.y;
  const int b = bh / NH, h = bh % NH;
  const int st = blockIdx.x;
  __shared__ bf16 Vs[64 * 72];
  const int tid = threadIdx.x;
  {
    const int r = tid >> 2, c = (tid & 3) * 16;
    const bf16* src =
        qkv + (size_t)(b * NS + st * 64 + r) * (3 * ND) + 2 * ND + h * 64 + c;
    *(bf16x8*)&Vs[r * 72 + c] = *(const bf16x8*)src;
    *(bf16x8*)&Vs[r * 72 + c + 8] = *(const bf16x8*)(src + 8);
  }
  __syncthreads();
  {
    const int hd = tid >> 2, t0 = (tid & 3) * 16;
    bf16x8 o0, o1;
#pragma unroll
    for (int j = 0; j < 8; ++j) {
      o0[j] = Vs[(t0 + j) * 72 + hd];
      o1[j] = Vs[(t0 + 8 + j) * 72 + hd];
    }
    bf16* dst = vT + ((size_t)bh * 64 + hd) * NS + st * 64 + t0;
    *(bf16x8*)dst = o0;
    *(bf16x8*)(dst + 8) = o1;
  }
}

// ---------------- gemm64: 64x128 tile, BK=64 --------------------------------
template <int EPI>
__global__ __launch_bounds__(256) void gemm64(
    const bf16* __restrict__ A, const bf16* __restrict__ Bt,
    const bf16* __restrict__ bias, const void* resid, void* C,
    int N, int K, int row0, const int* __restrict__ flag) {
  constexpr int NBUF = 3;
  __shared__ bf16 As[NBUF][64 * 64];
  __shared__ bf16 Bs[NBUF][128 * 64];
  int isf = 0;
  if (EPI == 2) {
    isf = *flag;
    asm volatile("" ::"s"(isf));
  }
  const int tid = threadIdx.x;
  const int w = tid >> 6, L = tid & 63;
  const int lg = L >> 4, lc = L & 15;
  const int wm = (w >> 1) * 32, wn = (w & 1) * 64;
  const int nwg = gridDim.x * gridDim.y;
  const int lin = xcd_swz(blockIdx.y * gridDim.x + blockIdx.x, nwg);
  const int bm = lin / gridDim.x, bn = lin % gridDim.x;

  const bf16* Ab = A + (size_t)bm * 64 * K;
  const bf16* Bb = Bt + (size_t)bn * 128 * K;

  const int srw = tid >> 3;                      // dest row 0..31 per load
  const int scw = ((tid & 7) ^ (srw & 7)) * 8;   // pre-swizzled source col

  f32x4 acc[2][4];
#pragma unroll
  for (int i = 0; i < 2; ++i)
#pragma unroll
    for (int j = 0; j < 4; ++j) acc[i][j] = (f32x4){0.f, 0.f, 0.f, 0.f};

#define G64_STAGE(buf, kk)                                                  \
  do {                                                                      \
    gl_lds16(Ab + (size_t)srw * K + (kk) + scw, As[buf] + tid * 8);         \
    gl_lds16(Ab + (size_t)(srw + 32) * K + (kk) + scw,                      \
             As[buf] + 2048 + tid * 8);                                     \
    gl_lds16(Bb + (size_t)srw * K + (kk) + scw, Bs[buf] + tid * 8);         \
    gl_lds16(Bb + (size_t)(srw + 32) * K + (kk) + scw,                      \
             Bs[buf] + 2048 + tid * 8);                                     \
    gl_lds16(Bb + (size_t)(srw + 64) * K + (kk) + scw,                      \
             Bs[buf] + 4096 + tid * 8);                                     \
    gl_lds16(Bb + (size_t)(srw + 96) * K + (kk) + scw,                      \
             Bs[buf] + 6144 + tid * 8);                                     \
  } while (0)

#define G64_COMP(cb)                                                        \
  do {                                                                      \
    bf16x8 af[2][2], bfr[2][4];                                             \
    _Pragma("unroll") for (int kk2 = 0; kk2 < 2; ++kk2) {                   \
      _Pragma("unroll") for (int mt = 0; mt < 2; ++mt) {                    \
        const int ra = wm + mt * 16 + lc;                                   \
        af[kk2][mt] = *(const bf16x8*)&As[cb][ra * 64 +                     \
                                             (((kk2 * 4 + lg) ^ (ra & 7))   \
                                              << 3)];                       \
      }                                                                     \
      _Pragma("unroll") for (int nt = 0; nt < 4; ++nt) {                    \
        const int rb = wn + nt * 16 + lc;                                   \
        bfr[kk2][nt] = *(const bf16x8*)&Bs[cb][rb * 64 +                    \
                                              (((kk2 * 4 + lg) ^ (rb & 7))  \
                                               << 3)];                      \
      }                                                                     \
    }                                                                       \
    _Pragma("unroll") for (int kk2 = 0; kk2 < 2; ++kk2)                     \
        _Pragma("unroll") for (int mt = 0; mt < 2; ++mt)                    \
            _Pragma("unroll") for (int nt = 0; nt < 4; ++nt)                \
                acc[mt][nt] = mfma16(af[kk2][mt], bfr[kk2][nt],             \
                                     acc[mt][nt]);                          \
  } while (0)

  const int nk = K >> 6;
  G64_STAGE(0, 0);
  int cur = 0, stg = 1;
  int k = 0;
  for (; k < nk - 1; ++k) {
    G64_STAGE(stg, (k + 1) * 64);
    asm volatile("s_waitcnt vmcnt(6)" ::: "memory");
    asm volatile("s_barrier" ::: "memory");
    G64_COMP(cur);
    cur = (cur + 1 == NBUF) ? 0 : cur + 1;
    stg = (stg + 1 == NBUF) ? 0 : stg + 1;
  }
  __syncthreads();  // drain last stage (vmcnt(0) + barrier)
  G64_COMP(cur);
#undef G64_STAGE
#undef G64_COMP

  const float* rf = (const float*)resid;
  const bf16* rh = (const bf16*)resid;
  float* Cf = (float*)C;
  bf16* Ch = (bf16*)C;
#pragma unroll
  for (int mt = 0; mt < 2; ++mt) {
#pragma unroll
    for (int nt = 0; nt < 4; ++nt) {
      const int col = bn * 128 + wn + nt * 16 + lc;
      const float bv = (float)bias[col];
#pragma unroll
      for (int r = 0; r < 4; ++r) {
        const int row = bm * 64 + wm + mt * 16 + lg * 4 + r;
        float v = acc[mt][nt][r] + bv;
        if (EPI == 1) v = gelu_fast(v);
        const size_t idx = (size_t)(row0 + row) * N + col;
        if (EPI == 2) {
          v += isf ? rf[idx] : (float)rh[idx];
          if (isf) Cf[idx] = v; else Ch[idx] = (bf16)v;
        } else {
          Ch[idx] = (bf16)v;
        }
      }
    }
  }
}

// ---------------- gemm_qkv64: gemm64 structure + fused QKV epilogue -------
// r10: gemm_qkv was the last BK=32 kernel on the hot path (24 latency-
// quantum iters, 576 blocks = 2.25/CU). Same BK=64 lever as fc1/fc2:
// 64x128 tile, 12 iters, grid (18,64)=1152 blocks=4.5/CU.
__global__ __launch_bounds__(256) void gemm_qkv64(
    const bf16* __restrict__ A, const bf16* __restrict__ Bt,
    const bf16* __restrict__ bias, bf16* __restrict__ qkvout,
    bf16* __restrict__ vT) {
  const int K = ND, N = 3 * ND;
  constexpr int NBUF = 3;
  __shared__ bf16 As[NBUF][64 * 64];
  __shared__ bf16 Bs[NBUF][128 * 64];
  const int tid = threadIdx.x;
  const int w = tid >> 6, L = tid & 63;
  const int lg = L >> 4, lc = L & 15;
  const int wm = (w >> 1) * 32, wn = (w & 1) * 64;
  const int nwg = gridDim.x * gridDim.y;
  const int lin = xcd_swz(blockIdx.y * gridDim.x + blockIdx.x, nwg);
  const int bm = lin / gridDim.x, bn = lin % gridDim.x;

  const bf16* Ab = A + (size_t)bm * 64 * K;
  const bf16* Bb = Bt + (size_t)bn * 128 * K;

  const int srw = tid >> 3;
  const int scw = ((tid & 7) ^ (srw & 7)) * 8;

  f32x4 acc[2][4];
#pragma unroll
  for (int i = 0; i < 2; ++i)
#pragma unroll
    for (int j = 0; j < 4; ++j) acc[i][j] = (f32x4){0.f, 0.f, 0.f, 0.f};

#define Q64_STAGE(buf, kk)                                                  \
  do {                                                                      \
    gl_lds16(Ab + (size_t)srw * K + (kk) + scw, As[buf] + tid * 8);         \
    gl_lds16(Ab + (size_t)(srw + 32) * K + (kk) + scw,                      \
             As[buf] + 2048 + tid * 8);                                     \
    gl_lds16(Bb + (size_t)srw * K + (kk) + scw, Bs[buf] + tid * 8);         \
    gl_lds16(Bb + (size_t)(srw + 32) * K + (kk) + scw,                      \
             Bs[buf] + 2048 + tid * 8);                                     \
    gl_lds16(Bb + (size_t)(srw + 64) * K + (kk) + scw,                      \
             Bs[buf] + 4096 + tid * 8);                                     \
    gl_lds16(Bb + (size_t)(srw + 96) * K + (kk) + scw,                      \
             Bs[buf] + 6144 + tid * 8);                                     \
  } while (0)

#define Q64_COMP(cb)                                                        \
  do {                                                                      \
    bf16x8 af[2][2], bfr[2][4];                                             \
    _Pragma("unroll") for (int kk2 = 0; kk2 < 2; ++kk2) {                   \
      _Pragma("unroll") for (int mt = 0; mt < 2; ++mt) {                    \
        const int ra = wm + mt * 16 + lc;                                   \
        af[kk2][mt] = *(const bf16x8*)&As[cb][ra * 64 +                     \
                                             (((kk2 * 4 + lg) ^ (ra & 7))   \
                                              << 3)];                       \
      }                                                                     \
      _Pragma("unroll") for (int nt = 0; nt < 4; ++nt) {                    \
        const int rb = wn + nt * 16 + lc;                                   \
        bfr[kk2][nt] = *(const bf16x8*)&Bs[cb][rb * 64 +                    \
                                              (((kk2 * 4 + lg) ^ (rb & 7))  \
                                               << 3)];                      \
      }                                                                     \
    }                                                                       \
    _Pragma("unroll") for (int kk2 = 0; kk2 < 2; ++kk2)                     \
        _Pragma("unroll") for (int mt = 0; mt < 2; ++mt)                    \
            _Pragma("unroll") for (int nt = 0; nt < 4; ++nt)                \
                acc[mt][nt] = mfma16(af[kk2][mt], bfr[kk2][nt],             \
                                     acc[mt][nt]);                          \
  } while (0)

  const int nk = K >> 6;  // 12
  Q64_STAGE(0, 0);
  int cur = 0, stg = 1;
  int k = 0;
  for (; k < nk - 1; ++k) {
    Q64_STAGE(stg, (k + 1) * 64);
    asm volatile("s_waitcnt vmcnt(6)" ::: "memory");
    asm volatile("s_barrier" ::: "memory");
    Q64_COMP(cur);
    cur = (cur + 1 == NBUF) ? 0 : cur + 1;
    stg = (stg + 1 == NBUF) ? 0 : stg + 1;
  }
  __syncthreads();
  Q64_COMP(cur);
#undef Q64_STAGE
#undef Q64_COMP

#pragma unroll
  for (int mt = 0; mt < 2; ++mt) {
#pragma unroll
    for (int nt = 0; nt < 4; ++nt) {
      const int col = bn * 128 + wn + nt * 16 + lc;
      const float bv = (float)bias[col];
      if (col < 2 * ND) {  // Q or K -> qkv buffer
#pragma unroll
        for (int r = 0; r < 4; ++r) {
          const int row = bm * 64 + wm + mt * 16 + lg * 4 + r;
          qkvout[(size_t)row * N + col] = (bf16)(acc[mt][nt][r] + bv);
        }
      } else {  // V -> vT[bh][hd][token], 4 consecutive tokens per lane
        const int colv = col - 2 * ND;
        const int h_ = colv >> 6, hd = colv & 63;
        bf16x4 pk;
#pragma unroll
        for (int r = 0; r < 4; ++r) pk[r] = (bf16)(acc[mt][nt][r] + bv);
        const int tok0 = bm * 64 + wm + mt * 16 + lg * 4;
        const int b_ = tok0 >> 11, s0 = tok0 & (NS - 1);
        *(bf16x4*)&vT[((size_t)(b_ * NH + h_) * 64 + hd) * NS + s0] = pk;
      }
    }
  }
}

// ---------------- fast GEMM (TM=128): counted-vmcnt + T2 swizzle ----------
template <int EPI, int TM>
__global__ __launch_bounds__(256) void gemm_fast(
    const bf16* __restrict__ A, const bf16* __restrict__ Bt,
    const bf16* __restrict__ bias, const void* resid, void* C,
    int N, int K, int row0, const int* __restrict__ flag) {
  constexpr int NBUF = (TM == 64) ? 5 : 3;
  constexpr int LOOK = NBUF - 2;
  constexpr int MT = TM / 32;
  __shared__ bf16 As[NBUF][TM * 32];
  __shared__ bf16 Bs[NBUF][128 * 32];
  int isf = 0;
  if (EPI == 2) {
    isf = *flag;
    asm volatile("" ::"s"(isf));
  }
  const int tid = threadIdx.x;
  const int w = tid >> 6, L = tid & 63;
  const int lg = L >> 4, lc = L & 15;
  const int lgx = (lg ^ ((lc >> 1) & 3)) * 8;
  const int wm = (w >> 1) * (TM / 2), wn = (w & 1) * 64;
  const int nwg = gridDim.x * gridDim.y;
  const int lin = xcd_swz(blockIdx.y * gridDim.x + blockIdx.x, nwg);
  const int bm = lin / gridDim.x, bn = lin % gridDim.x;

  const bf16* Ab = A + (size_t)bm * TM * K;
  const bf16* Bb = Bt + (size_t)bn * 128 * K;

  const int sr = tid >> 2;
  const int sc = ((tid & 3) ^ ((tid >> 3) & 3)) * 8;

  f32x4 acc[MT][4];
#pragma unroll
  for (int i = 0; i < MT; ++i)
#pragma unroll
    for (int j = 0; j < 4; ++j) acc[i][j] = (f32x4){0.f, 0.f, 0.f, 0.f};

#define GF_STAGE(buf, kk)                                                   \
  do {                                                                      \
    gl_lds16(Ab + (size_t)sr * K + (kk) + sc, As[buf] + tid * 8);           \
    if (TM == 128)                                                          \
      gl_lds16(Ab + (size_t)(sr + 64) * K + (kk) + sc,                      \
               As[buf] + 2048 + tid * 8);                                   \
    gl_lds16(Bb + (size_t)sr * K + (kk) + sc, Bs[buf] + tid * 8);           \
    gl_lds16(Bb + (size_t)(sr + 64) * K + (kk) + sc,                        \
             Bs[buf] + 2048 + tid * 8);                                     \
  } while (0)

#define GF_COMP(cb)                                                         \
  do {                                                                      \
    bf16x8 af[MT], bfr[4];                                                  \
    _Pragma("unroll") for (int mt = 0; mt < MT; ++mt) af[mt] =              \
        *(const bf16x8*)&As[cb][(wm + mt * 16 + lc) * 32 + lgx];            \
    _Pragma("unroll") for (int nt = 0; nt < 4; ++nt) bfr[nt] =              \
        *(const bf16x8*)&Bs[cb][(wn + nt * 16 + lc) * 32 + lgx];            \
    _Pragma("unroll") for (int mt = 0; mt < MT; ++mt)                       \
        _Pragma("unroll") for (int nt = 0; nt < 4; ++nt) acc[mt][nt] =      \
            mfma16(af[mt], bfr[nt], acc[mt][nt]);                           \
  } while (0)

  const int nk = K >> 5;
#pragma unroll
  for (int s = 0; s < LOOK; ++s)
    if (s < nk) GF_STAGE(s, s * 32);
  int cur = 0, stg = LOOK;
  int k = 0;
  const int kmain = (nk > LOOK) ? nk - LOOK : 0;
  for (; k < kmain; ++k) {
    GF_STAGE(stg, (k + LOOK) * 32);
    if (TM == 64)
      asm volatile("s_waitcnt vmcnt(9)" ::: "memory");
    else
      asm volatile("s_waitcnt vmcnt(4)" ::: "memory");
    asm volatile("s_barrier" ::: "memory");
    GF_COMP(cur);
    cur = (cur + 1 == NBUF) ? 0 : cur + 1;
    stg = (stg + 1 == NBUF) ? 0 : stg + 1;
  }
  __syncthreads();
  for (; k < nk; ++k) {
    GF_COMP(cur);
    cur = (cur + 1 == NBUF) ? 0 : cur + 1;
  }
#undef GF_STAGE
#undef GF_COMP

  const float* rf = (const float*)resid;
  const bf16* rh = (const bf16*)resid;
  float* Cf = (float*)C;
  bf16* Ch = (bf16*)C;
#pragma unroll
  for (int mt = 0; mt < MT; ++mt) {
#pragma unroll
    for (int nt = 0; nt < 4; ++nt) {
      const int col = bn * 128 + wn + nt * 16 + lc;
      const float bv = (float)bias[col];
#pragma unroll
      for (int r = 0; r < 4; ++r) {
        const int row = bm * TM + wm + mt * 16 + lg * 4 + r;
        float v = acc[mt][nt][r] + bv;
        if (EPI == 1) v = gelu_fast(v);
        const size_t idx = (size_t)(row0 + row) * N + col;
        if (EPI == 2) {
          v += isf ? rf[idx] : (float)rh[idx];
          if (isf) Cf[idx] = v; else Ch[idx] = (bf16)v;
        } else {
          Ch[idx] = (bf16)v;
        }
      }
    }
  }
}

// ---------------- fallback GEMM (dtype-branch staging, round-3) -----------
template <int EPI>
__global__ __launch_bounds__(256) void gemm_bt(
    const bf16* __restrict__ A, const void* __restrict__ Bt,
    const void* __restrict__ bias, const void* resid, void* C,
    int N, int K, int row0, const int* __restrict__ flag) {
  __shared__ bf16 As[128 * 32];
  __shared__ bf16 Bs[128 * 32];
  const int isf = *flag;
  const int tid = threadIdx.x;
  const int w = tid >> 6, L = tid & 63;
  const int lg = L >> 4, lc = L & 15;
  const int wm = (w >> 1) * 64, wn = (w & 1) * 64;
  const int nwg = gridDim.x * gridDim.y;
  const int lin = xcd_swz(blockIdx.y * gridDim.x + blockIdx.x, nwg);
  const int bm = lin / gridDim.x, bn = lin % gridDim.x;

  const bf16* Ab = A + (size_t)bm * 128 * K;
  const bf16* Bth = (const bf16*)Bt + (size_t)bn * 128 * K;
  const float* Btf = (const float*)Bt + (size_t)bn * 128 * K;

  const int sr = tid >> 1;
  const int sc = (tid & 1) * 16;

  f32x4 acc[4][4];
#pragma unroll
  for (int i = 0; i < 4; ++i)
#pragma unroll
    for (int j = 0; j < 4; ++j) acc[i][j] = (f32x4){0.f, 0.f, 0.f, 0.f};

  for (int k0 = 0; k0 < K; k0 += 32) {
    const bf16* ap = Ab + (size_t)sr * K + k0 + sc;
    const bf16x8 a0 = *(const bf16x8*)ap;
    const bf16x8 a1 = *(const bf16x8*)(ap + 8);
    bf16x8 b0, b1;
    if (isf) {
      const float* bp = Btf + (size_t)sr * K + k0 + sc;
      const f32x4 f0 = *(const f32x4*)bp;
      const f32x4 f1 = *(const f32x4*)(bp + 4);
      const f32x4 f2 = *(const f32x4*)(bp + 8);
      const f32x4 f3 = *(const f32x4*)(bp + 12);
#pragma unroll
      for (int j = 0; j < 4; ++j) {
        b0[j] = (bf16)f0[j];
        b0[4 + j] = (bf16)f1[j];
        b1[j] = (bf16)f2[j];
        b1[4 + j] = (bf16)f3[j];
      }
    } else {
      const bf16* bp = Bth + (size_t)sr * K + k0 + sc;
      b0 = *(const bf16x8*)bp;
      b1 = *(const bf16x8*)(bp + 8);
    }
    __syncthreads();
    *(bf16x8*)&As[sr * 32 + sc] = a0;
    *(bf16x8*)&As[sr * 32 + sc + 8] = a1;
    *(bf16x8*)&Bs[sr * 32 + sc] = b0;
    *(bf16x8*)&Bs[sr * 32 + sc + 8] = b1;
    __syncthreads();

    bf16x8 af[4], bfr[4];
#pragma unroll
    for (int mt = 0; mt < 4; ++mt)
      af[mt] = *(const bf16x8*)&As[(wm + mt * 16 + lc) * 32 + lg * 8];
#pragma unroll
    for (int nt = 0; nt < 4; ++nt)
      bfr[nt] = *(const bf16x8*)&Bs[(wn + nt * 16 + lc) * 32 + lg * 8];
#pragma unroll
    for (int mt = 0; mt < 4; ++mt)
#pragma unroll
      for (int nt = 0; nt < 4; ++nt)
        acc[mt][nt] = mfma16(af[mt], bfr[nt], acc[mt][nt]);
  }

  const float* biasf = (const float*)bias;
  const bf16* biash = (const bf16*)bias;
  const float* rf = (const float*)resid;
  const bf16* rh = (const bf16*)resid;
  float* Cf = (float*)C;
  bf16* Ch = (bf16*)C;
#pragma unroll
  for (int mt = 0; mt < 4; ++mt) {
#pragma unroll
    for (int nt = 0; nt < 4; ++nt) {
      const int col = bn * 128 + wn + nt * 16 + lc;
      const float bv = isf ? biasf[col] : (float)biash[col];
#pragma unroll
      for (int r = 0; r < 4; ++r) {
        const int row = bm * 128 + wm + mt * 16 + lg * 4 + r;
        float v = acc[mt][nt][r] + bv;
        if (EPI == 1) v = gelu_fast(v);
        const size_t idx = (size_t)(row0 + row) * N + col;
        if (EPI == 2) {
          v += isf ? rf[idx] : (float)rh[idx];
          if (isf) Cf[idx] = v; else Ch[idx] = (bf16)v;
        } else {
          Ch[idx] = (bf16)v;
        }
      }
    }
  }
}

// ---------------- Flash attention v10b: split-KV, disjoint partials -------
// Round-8 proven version (47.2us): single tile per barrier pair, 27.6KB
// LDS (5 blocks/CU capacity), VGPR 100. Round-9's 2-tile variant REGRESSED
// (55.7us): LDS 46KB + VGPR 132 cut occupancy 13.5->7.8% -- in this
// latency-bound regime occupancy is the binding constraint, not barriers.
__global__ __launch_bounds__(128) void flash_attn_sp(
    const bf16* __restrict__ qkv, const bf16* __restrict__ vT,
    bf16* __restrict__ o, float* __restrict__ po, float* __restrict__ pl) {
  const int nwg = gridDim.x * gridDim.y;  // 1128 = 8 XCD * 141 (3 bh each)
  const int lin = xcd_swz(blockIdx.y * gridDim.x + blockIdx.x, nwg);
  const int bh = lin / 47;
  const int c = lin % 47;
  const int b = bh / NH, h = bh % NH;
  int qt, kt_lo, kt_hi, direct, cc = 0;
  if (c == 0) {
    qt = 16; kt_lo = 0; kt_hi = 16; direct = 1;
  } else if (c <= 30) {
    qt = 31 - ((c - 1) >> 1);
    const int hh = (qt + 1) >> 1;
    cc = (c - 1) & 1;
    if (cc) { kt_lo = hh; kt_hi = qt; }
    else    { kt_lo = 0;  kt_hi = hh - 1; }
    direct = 0;
  } else {
    qt = 46 - c; kt_lo = 0; kt_hi = qt; direct = 1;
  }
  const int q0 = qt * 64;
  const int tid = threadIdx.x;  // 128 threads = 2 waves
  const int w = tid >> 6, L = tid & 63;
  const int lg = L >> 4, lc = L & 15;

  __shared__ bf16 Ks[64 * 72];   // [kv][hd]
  __shared__ bf16 Vts[64 * 72];  // [hd][kv]
  __shared__ bf16 Ps[2][32 * 72];

  const float QSCALE = 0.18033688011112042f;  // (1/8) * log2(e)
  bf16x8 qf[2][2];
#pragma unroll
  for (int m = 0; m < 2; ++m) {
    const size_t tokq = (size_t)(b * NS + q0 + w * 32 + m * 16 + lc);
    const bf16* qp = qkv + tokq * (3 * ND) + h * 64 + lg * 8;
    const bf16x8 q0r = *(const bf16x8*)qp;
    const bf16x8 q1r = *(const bf16x8*)(qp + 32);
#pragma unroll
    for (int jj = 0; jj < 8; ++jj) {
      qf[m][0][jj] = (bf16)((float)q0r[jj] * QSCALE);
      qf[m][1][jj] = (bf16)((float)q1r[jj] * QSCALE);
    }
  }

  const int kr = tid >> 1, kc = (tid & 1) * 32;
  const bf16* kbase =
      qkv + (size_t)(b * NS + kr) * (3 * ND) + ND + h * 64 + kc;
  const bf16* vbase = vT + ((size_t)bh * 64 + kr) * NS + kc;

  f32x4 oacc[2][4];
#pragma unroll
  for (int m = 0; m < 2; ++m)
#pragma unroll
    for (int nt = 0; nt < 4; ++nt) oacc[m][nt] = (f32x4){0.f, 0.f, 0.f, 0.f};
  float lacc[2] = {0.f, 0.f};

  bf16x8 kreg[4], vreg[4];
  {
    const bf16* kn = kbase + (size_t)kt_lo * 64 * (3 * ND);
    const bf16* vn = vbase + (size_t)kt_lo * 64;
#pragma unroll
    for (int p = 0; p < 4; ++p) {
      kreg[p] = *(const bf16x8*)(kn + p * 8);
      vreg[p] = *(const bf16x8*)(vn + p * 8);
    }
  }

  for (int kt = kt_lo; kt <= kt_hi; ++kt) {
    __syncthreads();
#pragma unroll
    for (int p = 0; p < 4; ++p) {
      *(bf16x8*)&Ks[kr * 72 + kc + p * 8] = kreg[p];
      *(bf16x8*)&Vts[kr * 72 + kc + p * 8] = vreg[p];
    }
    __syncthreads();

    if (kt < kt_hi) {
      const bf16* kn = kbase + (size_t)(kt + 1) * 64 * (3 * ND);
      const bf16* vn = vbase + (size_t)(kt + 1) * 64;
#pragma unroll
      for (int p = 0; p < 4; ++p) {
        kreg[p] = *(const bf16x8*)(kn + p * 8);
        vreg[p] = *(const bf16x8*)(vn + p * 8);
      }
    }

    f32x4 s[2][4];
    __builtin_amdgcn_s_setprio(1);
#pragma unroll
    for (int nt = 0; nt < 4; ++nt) {
      const bf16x8 kb0 = *(const bf16x8*)&Ks[(nt * 16 + lc) * 72 + lg * 8];
      const bf16x8 kb1 =
          *(const bf16x8*)&Ks[(nt * 16 + lc) * 72 + 32 + lg * 8];
#pragma unroll
      for (int m = 0; m < 2; ++m) {
        f32x4 z = (f32x4){0.f, 0.f, 0.f, 0.f};
        s[m][nt] = mfma16(kb0, qf[m][0], z);
        s[m][nt] = mfma16(kb1, qf[m][1], s[m][nt]);
      }
    }
    __builtin_amdgcn_s_setprio(0);
    if (kt == qt) {
#pragma unroll
      for (int m = 0; m < 2; ++m)
#pragma unroll
        for (int nt = 0; nt < 4; ++nt)
#pragma unroll
          for (int r = 0; r < 4; ++r) {
            const int kv = nt * 16 + lg * 4 + r;
            const int qrow = w * 32 + m * 16 + lc;
            if (kv > qrow) s[m][nt][r] = -1.0e30f;
          }
    }
#pragma unroll
    for (int m = 0; m < 2; ++m)
#pragma unroll
      for (int nt = 0; nt < 4; ++nt) {
        bf16x4 pk;
#pragma unroll
        for (int r = 0; r < 4; ++r) {
          const float p = exp2f(fminf(s[m][nt][r], 20.f));
          lacc[m] += p;
          pk[r] = (bf16)p;
        }
        *(bf16x4*)&Ps[w][(m * 16 + lc) * 72 + nt * 16 + lg * 4] = pk;
      }
    bf16x8 pa[2][2];
#pragma unroll
    for (int m = 0; m < 2; ++m) {
      pa[m][0] = *(const bf16x8*)&Ps[w][(m * 16 + lc) * 72 + lg * 8];
      pa[m][1] = *(const bf16x8*)&Ps[w][(m * 16 + lc) * 72 + 32 + lg * 8];
    }
    __builtin_amdgcn_s_setprio(1);
#pragma unroll
    for (int nt = 0; nt < 4; ++nt) {
      const bf16x8 v0 = *(const bf16x8*)&Vts[(nt * 16 + lc) * 72 + lg * 8];
      const bf16x8 v1 =
          *(const bf16x8*)&Vts[(nt * 16 + lc) * 72 + 32 + lg * 8];
#pragma unroll
      for (int m = 0; m < 2; ++m) {
        oacc[m][nt] = mfma16(pa[m][0], v0, oacc[m][nt]);
        oacc[m][nt] = mfma16(pa[m][1], v1, oacc[m][nt]);
      }
    }
    __builtin_amdgcn_s_setprio(0);
  }

#pragma unroll
  for (int m = 0; m < 2; ++m) {
    lacc[m] += __shfl_xor(lacc[m], 16);
    lacc[m] += __shfl_xor(lacc[m], 32);
  }

  if (direct) {
    float lr[2][4];
#pragma unroll
    for (int m = 0; m < 2; ++m)
#pragma unroll
      for (int r = 0; r < 4; ++r) lr[m][r] = __shfl(lacc[m], lg * 4 + r);
#pragma unroll
    for (int m = 0; m < 2; ++m)
#pragma unroll
      for (int nt = 0; nt < 4; ++nt)
#pragma unroll
        for (int r = 0; r < 4; ++r) {
          const int qrow = q0 + w * 32 + m * 16 + lg * 4 + r;
          const float val = oacc[m][nt][r] / lr[m][r];
          o[(size_t)(b * NS + qrow) * ND + h * 64 + nt * 16 + lc] =
              (bf16)val;
        }
  } else {
    const int slot = qt - 17;  // 0..14
    float* pob = po + (((size_t)(bh * 15 + slot)) * 2 + cc) * 4096;
#pragma unroll
    for (int m = 0; m < 2; ++m)
#pragma unroll
      for (int nt = 0; nt < 4; ++nt)
#pragma unroll
        for (int r = 0; r < 4; ++r) {
          const int row = w * 32 + m * 16 + lg * 4 + r;
          const int col = nt * 16 + lc;
          pob[row * 64 + col] = oacc[m][nt][r];
        }
    if (L < 16) {
      float* plb = pl + ((bh * 15 + slot) * 2 + cc) * 64;
      plb[w * 32 + L] = lacc[0];
      plb[w * 32 + 16 + L] = lacc[1];
    }
  }
}

// ---------------- attention partial combine (qt>=17 tiles) ----------------
__global__ __launch_bounds__(256) void attn_combine(
    const float* __restrict__ po, const float* __restrict__ pl,
    bf16* __restrict__ o) {
  const int slot = blockIdx.x;  // 0..14 -> qt = slot+17
  const int bh = blockIdx.y;    // 0..23
  const int qt = slot + 17;
  const int b = bh / NH, h = bh % NH;
  const float* poA = po + ((size_t)(bh * 15 + slot)) * 2 * 4096;
  const float* poB = poA + 4096;
  const float* plA = pl + (bh * 15 + slot) * 2 * 64;
  const float* plB = plA + 64;
  for (int e = threadIdx.x; e < 4096; e += 256) {
    const int q = e >> 6, hd = e & 63;
    const float val = (poA[e] + poB[e]) / (plA[q] + plB[q]);
    o[(size_t)(b * NS + qt * 64 + q) * ND + h * 64 + hd] = (bf16)val;
  }
}

// ---------------- Flash attention v9 (T2 tier: no partial workspace) ------
__global__ __launch_bounds__(128) void flash_attn_v7(
    const bf16* __restrict__ qkv, const bf16* __restrict__ vT,
    bf16* __restrict__ o) {
  const int nwg = gridDim.x * gridDim.y;  // 768 = 8 XCD * 96
  const int lin = xcd_swz(blockIdx.y * gridDim.x + blockIdx.x, nwg);
  const int xcd = lin / 96;
  const int i96 = lin % 96;
  const int bl = i96 >> 5;
  const int j = i96 & 31;
  const int bh = xcd * 3 + bl;
  const int b = bh / NH, h = bh % NH;
  int qt;
  if (bl == 0) qt = j;
  else if (bl == 1) qt = (j + 16) & 31;
  else qt = (j < 16) ? (31 - 2 * j) : (62 - 2 * j);
  const int q0 = qt * 64;
  const int tid = threadIdx.x;
  const int w = tid >> 6, L = tid & 63;
  const int lg = L >> 4, lc = L & 15;

  __shared__ bf16 Ks[2][64 * 72];
  __shared__ bf16 Vts[2][64 * 72];
  __shared__ bf16 Ps[2][32 * 72];

  const float QSCALE = 0.18033688011112042f;
  bf16x8 qf[2][2];
#pragma unroll
  for (int m = 0; m < 2; ++m) {
    const size_t tokq = (size_t)(b * NS + q0 + w * 32 + m * 16 + lc);
    const bf16* qp = qkv + tokq * (3 * ND) + h * 64 + lg * 8;
    const bf16x8 q0r = *(const bf16x8*)qp;
    const bf16x8 q1r = *(const bf16x8*)(qp + 32);
#pragma unroll
    for (int jj = 0; jj < 8; ++jj) {
      qf[m][0][jj] = (bf16)((float)q0r[jj] * QSCALE);
      qf[m][1][jj] = (bf16)((float)q1r[jj] * QSCALE);
    }
  }

  const int kr = tid >> 1, kc = (tid & 1) * 32;
  const bf16* kbase =
      qkv + (size_t)(b * NS + kr) * (3 * ND) + ND + h * 64 + kc;
  const bf16* vbase = vT + ((size_t)bh * 64 + kr) * NS + kc;

  f32x4 oacc[2][4];
#pragma unroll
  for (int m = 0; m < 2; ++m)
#pragma unroll
    for (int nt = 0; nt < 4; ++nt) oacc[m][nt] = (f32x4){0.f, 0.f, 0.f, 0.f};
  float lacc[2] = {0.f, 0.f};

  const int nkt = qt + 1;

  bf16x8 kreg[4], vreg[4];
#pragma unroll
  for (int p = 0; p < 4; ++p) {
    kreg[p] = *(const bf16x8*)(kbase + p * 8);
    vreg[p] = *(const bf16x8*)(vbase + p * 8);
  }
#pragma unroll
  for (int p = 0; p < 4; ++p) {
    *(bf16x8*)&Ks[0][kr * 72 + kc + p * 8] = kreg[p];
    *(bf16x8*)&Vts[0][kr * 72 + kc + p * 8] = vreg[p];
  }

  for (int kt = 0; kt < nkt; ++kt) {
    __syncthreads();
    const int cur = kt & 1;

    if (kt + 1 < nkt) {
      const bf16* kn = kbase + (size_t)(kt + 1) * 64 * (3 * ND);
      const bf16* vn = vbase + (size_t)(kt + 1) * 64;
#pragma unroll
      for (int p = 0; p < 4; ++p) {
        kreg[p] = *(const bf16x8*)(kn + p * 8);
        vreg[p] = *(const bf16x8*)(vn + p * 8);
      }
    }

    f32x4 s[2][4];
    __builtin_amdgcn_s_setprio(1);
#pragma unroll
    for (int nt = 0; nt < 4; ++nt) {
      const bf16x8 kb0 =
          *(const bf16x8*)&Ks[cur][(nt * 16 + lc) * 72 + lg * 8];
      const bf16x8 kb1 =
          *(const bf16x8*)&Ks[cur][(nt * 16 + lc) * 72 + 32 + lg * 8];
#pragma unroll
      for (int m = 0; m < 2; ++m) {
        f32x4 z = (f32x4){0.f, 0.f, 0.f, 0.f};
        s[m][nt] = mfma16(kb0, qf[m][0], z);
        s[m][nt] = mfma16(kb1, qf[m][1], s[m][nt]);
      }
    }
    __builtin_amdgcn_s_setprio(0);
    if (kt == nkt - 1) {
#pragma unroll
      for (int m = 0; m < 2; ++m)
#pragma unroll
        for (int nt = 0; nt < 4; ++nt)
#pragma unroll
          for (int r = 0; r < 4; ++r) {
            const int kv = nt * 16 + lg * 4 + r;
            const int qrow = w * 32 + m * 16 + lc;
            if (kv > qrow) s[m][nt][r] = -1.0e30f;
          }
    }
#pragma unroll
    for (int m = 0; m < 2; ++m)
#pragma unroll
      for (int nt = 0; nt < 4; ++nt) {
        bf16x4 pk;
#pragma unroll
        for (int r = 0; r < 4; ++r) {
          const float p = exp2f(fminf(s[m][nt][r], 20.f));
          lacc[m] += p;
          pk[r] = (bf16)p;
        }
        *(bf16x4*)&Ps[w][(m * 16 + lc) * 72 + nt * 16 + lg * 4] = pk;
      }
    bf16x8 pa[2][2];
#pragma unroll
    for (int m = 0; m < 2; ++m) {
      pa[m][0] = *(const bf16x8*)&Ps[w][(m * 16 + lc) * 72 + lg * 8];
      pa[m][1] = *(const bf16x8*)&Ps[w][(m * 16 + lc) * 72 + 32 + lg * 8];
    }

    if (kt + 1 < nkt) {
      const int nxt = cur ^ 1;
#pragma unroll
      for (int p = 0; p < 4; ++p) {
        *(bf16x8*)&Ks[nxt][kr * 72 + kc + p * 8] = kreg[p];
        *(bf16x8*)&Vts[nxt][kr * 72 + kc + p * 8] = vreg[p];
      }
    }

    __builtin_amdgcn_s_setprio(1);
#pragma unroll
    for (int nt = 0; nt < 4; ++nt) {
      const bf16x8 v0 =
          *(const bf16x8*)&Vts[cur][(nt * 16 + lc) * 72 + lg * 8];
      const bf16x8 v1 =
          *(const bf16x8*)&Vts[cur][(nt * 16 + lc) * 72 + 32 + lg * 8];
#pragma unroll
      for (int m = 0; m < 2; ++m) {
        oacc[m][nt] = mfma16(pa[m][0], v0, oacc[m][nt]);
        oacc[m][nt] = mfma16(pa[m][1], v1, oacc[m][nt]);
      }
    }
    __builtin_amdgcn_s_setprio(0);
  }

#pragma unroll
  for (int m = 0; m < 2; ++m) {
    lacc[m] += __shfl_xor(lacc[m], 16);
    lacc[m] += __shfl_xor(lacc[m], 32);
  }
  float lr[2][4];
#pragma unroll
  for (int m = 0; m < 2; ++m)
#pragma unroll
    for (int r = 0; r < 4; ++r) lr[m][r] = __shfl(lacc[m], lg * 4 + r);

#pragma unroll
  for (int m = 0; m < 2; ++m)
#pragma unroll
    for (int nt = 0; nt < 4; ++nt)
#pragma unroll
      for (int r = 0; r < 4; ++r) {
        const int qrow = q0 + w * 32 + m * 16 + lg * 4 + r;
        const float val = oacc[m][nt][r] / lr[m][r];
        o[(size_t)(b * NS + qrow) * ND + h * 64 + nt * 16 + lc] = (bf16)val;
      }
}

// ---------------- Flash attention v1 (fallback tiers, no vT) --------------
__global__ __launch_bounds__(256) void flash_attn_v1(
    const bf16* __restrict__ qkv, bf16* __restrict__ o) {
  const int bh = blockIdx.y;
  const int b = bh / NH, h = bh % NH;
  const int qt = gridDim.x - 1 - blockIdx.x;
  const int q0 = qt * 64;
  const int tid = threadIdx.x;
  const int w = tid >> 6, L = tid & 63;
  const int lg = L >> 4, lc = L & 15;

  __shared__ bf16 Ks[64 * 72];
  __shared__ bf16 Vts[64 * 72];
  __shared__ bf16 Ps[4][16 * 72];

  const float QSCALE = 0.18033688011112042f;
  const size_t tokq = (size_t)(b * NS + q0 + w * 16 + lc);
  const bf16* qp = qkv + tokq * (3 * ND) + h * 64 + lg * 8;
  const bf16x8 qr0 = *(const bf16x8*)qp;
  const bf16x8 qr1 = *(const bf16x8*)(qp + 32);
  bf16x8 qf0, qf1;
#pragma unroll
  for (int j = 0; j < 8; ++j) {
    qf0[j] = (bf16)((float)qr0[j] * QSCALE);
    qf1[j] = (bf16)((float)qr1[j] * QSCALE);
  }

  f32x4 oacc[4];
#pragma unroll
  for (int nt = 0; nt < 4; ++nt) oacc[nt] = (f32x4){0.f, 0.f, 0.f, 0.f};
  float lacc[4] = {0.f, 0.f, 0.f, 0.f};

  for (int kt = 0; kt <= qt; ++kt) {
    __syncthreads();
#pragma unroll
    for (int p = 0; p < 2; ++p) {
      const int r = (p * 256 + tid) >> 3;
      const int c = (tid & 7) * 8;
      const bf16* kp =
          qkv + (size_t)(b * NS + kt * 64 + r) * (3 * ND) + ND + h * 64 + c;
      const bf16x8 k8 = *(const bf16x8*)kp;
      *(bf16x8*)&Ks[r * 72 + c] = k8;
      const bf16x8 v8 = *(const bf16x8*)(kp + ND);
#pragma unroll
      for (int j = 0; j < 8; ++j) Vts[(c + j) * 72 + r] = v8[j];
    }
    __syncthreads();

    f32x4 s[4];
#pragma unroll
    for (int nt = 0; nt < 4; ++nt) {
      const bf16x8 b0 = *(const bf16x8*)&Ks[(nt * 16 + lc) * 72 + lg * 8];
      const bf16x8 b1 = *(const bf16x8*)&Ks[(nt * 16 + lc) * 72 + 32 + lg * 8];
      f32x4 z = (f32x4){0.f, 0.f, 0.f, 0.f};
      s[nt] = mfma16(qf0, b0, z);
      s[nt] = mfma16(qf1, b1, s[nt]);
    }
    if (kt == qt) {
#pragma unroll
      for (int nt = 0; nt < 4; ++nt)
#pragma unroll
        for (int r = 0; r < 4; ++r) {
          const int qrow = w * 16 + lg * 4 + r;
          const int kcol = nt * 16 + lc;
          if (kcol > qrow) s[nt][r] = -1.0e30f;
        }
    }
#pragma unroll
    for (int nt = 0; nt < 4; ++nt)
#pragma unroll
      for (int r = 0; r < 4; ++r) {
        const float p = exp2f(fminf(s[nt][r], 20.f));
        lacc[r] += p;
        Ps[w][(lg * 4 + r) * 72 + nt * 16 + lc] = (bf16)p;
      }
    __syncthreads();

    const bf16x8 p0 = *(const bf16x8*)&Ps[w][lc * 72 + lg * 8];
    const bf16x8 p1 = *(const bf16x8*)&Ps[w][lc * 72 + 32 + lg * 8];
#pragma unroll
    for (int nt = 0; nt < 4; ++nt) {
      const bf16x8 v0 = *(const bf16x8*)&Vts[(nt * 16 + lc) * 72 + lg * 8];
      const bf16x8 v1 = *(const bf16x8*)&Vts[(nt * 16 + lc) * 72 + 32 + lg * 8];
      oacc[nt] = mfma16(p0, v0, oacc[nt]);
      oacc[nt] = mfma16(p1, v1, oacc[nt]);
    }
  }

#pragma unroll
  for (int msk = 1; msk < 16; msk <<= 1)
#pragma unroll
    for (int r = 0; r < 4; ++r) lacc[r] += __shfl_xor(lacc[r], msk);

#pragma unroll
  for (int nt = 0; nt < 4; ++nt)
#pragma unroll
    for (int r = 0; r < 4; ++r) {
      const int qrow = q0 + w * 16 + lg * 4 + r;
      const float val = oacc[nt][r] / lacc[r];
      o[(size_t)(b * NS + qrow) * ND + h * 64 + nt * 16 + lc] = (bf16)val;
    }
}

// ---------------- launcher ----------------
extern "C" void kernel_launch(void* const* d_in, const int* in_sizes, int n_in,
                              void* d_out, int out_size, void* d_ws,
                              size_t ws_size, hipStream_t stream) {
  const void* x = d_in[0];
  const void* qkv_w = d_in[2];
  const void* qkv_b = d_in[3];
  const void* out_w = d_in[4];
  const void* out_b = d_in[5];
  const void* fc1_w = d_in[6];
  const void* fc1_b = d_in[7];
  const void* fc2_w = d_in[8];
  const void* fc2_b = d_in[9];
  const void* ln1_w = d_in[10];
  const void* ln1_b = d_in[11];
  const void* ln2_w = d_in[12];
  const void* ln2_b = d_in[13];
  (void)in_sizes; (void)n_in; (void)out_size;

  char* ws = (char*)d_ws;
  int* flag = (int*)ws;

  sniff_kernel<<<dim3(1), 256, 0, stream>>>((const ushort_t*)x, flag);

  const size_t T1 = 58210048, T2 = 51918592, T3 = 45627136, T4 = 39335680;

  if (ws_size >= T2) {
    bf16* wq = (bf16*)(ws + 256);
    bf16* wo = wq + 1769472;
    bf16* w1 = wo + 589824;
    bf16* w2 = w1 + 2359296;
    bf16* bq = w2 + 2359296;
    bf16* bo = bq + 2304;
    bf16* b1 = bo + 768;
    bf16* b2 = b1 + 3072;
    bf16* slotA = b2 + 768;
    bf16* vT = slotA + (size_t)NT * ND;
    bf16* slotB = vT + (size_t)NT * ND;
    bf16* hx = slotA, *oat = slotA, *h2 = slotA;
    bf16* qkv = slotB;
    float* po = (float*)(ws + 45627136);
    float* pl = po + (size_t)24 * 15 * 2 * 4096;
    const bool sp = ws_size >= T1;

    CvtArgs ca;
    ca.s[0] = qkv_w; ca.d[0] = wq; ca.n8[0] = 1769472 / 8;
    ca.s[1] = out_w; ca.d[1] = wo; ca.n8[1] = 589824 / 8;
    ca.s[2] = fc1_w; ca.d[2] = w1; ca.n8[2] = 2359296 / 8;
    ca.s[3] = fc2_w; ca.d[3] = w2; ca.n8[3] = 2359296 / 8;
    ca.s[4] = qkv_b; ca.d[4] = bq; ca.n8[4] = 2304 / 8;
    ca.s[5] = out_b; ca.d[5] = bo; ca.n8[5] = 768 / 8;
    ca.s[6] = fc1_b; ca.d[6] = b1; ca.n8[6] = 3072 / 8;
    ca.s[7] = fc2_b; ca.d[7] = b2; ca.n8[7] = 768 / 8;
    ca.total8 = (1769472 + 589824 + 2359296 + 2359296 + 2304 + 768 + 3072 +
                 768) / 8;
    cvt_all<<<dim3(880), 256, 0, stream>>>(ca, flag);

    ln_kernel<<<dim3(NT / 4), 256, 0, stream>>>(x, ln1_w, ln1_b, hx, flag);
    gemm_qkv64<<<dim3(18, 64), 256, 0, stream>>>(hx, wq, bq, qkv, vT);
    if (sp) {
      flash_attn_sp<<<dim3(47, 24), 128, 0, stream>>>(qkv, vT, oat, po, pl);
      attn_combine<<<dim3(15, 24), 256, 0, stream>>>(po, pl, oat);
    } else {
      flash_attn_v7<<<dim3(NS / 64, NB * NH), 128, 0, stream>>>(qkv, vT, oat);
    }
    gemm64<2><<<dim3(6, 64), 256, 0, stream>>>(
        oat, wo, bo, x, d_out, ND, ND, 0, flag);
    ln_kernel<<<dim3(NT / 4), 256, 0, stream>>>(d_out, ln2_w, ln2_b, h2, flag);
    if (ws_size >= T1) {
      bf16* ff1 = slotB;
      gemm64<1><<<dim3(24, 64), 256, 0, stream>>>(
          h2, w1, b1, nullptr, ff1, NF, ND, 0, flag);
      gemm64<2><<<dim3(6, 64), 256, 0, stream>>>(
          ff1, w2, b2, d_out, d_out, ND, NF, 0, flag);
    } else {
      bf16* ff1c = slotB;
      for (int c = 0; c < 2; ++c) {
        gemm64<1><<<dim3(24, 32), 256, 0, stream>>>(
            h2 + (size_t)c * 2048 * ND, w1, b1, nullptr, ff1c, NF, ND, 0, flag);
        gemm64<2><<<dim3(6, 32), 256, 0, stream>>>(
            ff1c, w2, b2, d_out, d_out, ND, NF, c * 2048, flag);
      }
    }
  } else if (ws_size >= T4) {
    bf16* wq = (bf16*)(ws + 256);
    bf16* wo = wq + 1769472;
    bf16* w1 = wo + 589824;
    bf16* w2 = w1 + 2359296;
    bf16* bq = w2 + 2359296;
    bf16* bo = bq + 2304;
    bf16* b1 = bo + 768;
    bf16* b2 = b1 + 3072;
    bf16* slotA = b2 + 768;
    bf16* slotB = slotA + (size_t)NT * ND;
    bf16* hx = slotA, *oat = slotA, *h2 = slotA;
    bf16* qkv = slotB;

    CvtArgs ca;
    ca.s[0] = qkv_w; ca.d[0] = wq; ca.n8[0] = 1769472 / 8;
    ca.s[1] = out_w; ca.d[1] = wo; ca.n8[1] = 589824 / 8;
    ca.s[2] = fc1_w; ca.d[2] = w1; ca.n8[2] = 2359296 / 8;
    ca.s[3] = fc2_w; ca.d[3] = w2; ca.n8[3] = 2359296 / 8;
    ca.s[4] = qkv_b; ca.d[4] = bq; ca.n8[4] = 2304 / 8;
    ca.s[5] = out_b; ca.d[5] = bo; ca.n8[5] = 768 / 8;
    ca.s[6] = fc1_b; ca.d[6] = b1; ca.n8[6] = 3072 / 8;
    ca.s[7] = fc2_b; ca.d[7] = b2; ca.n8[7] = 768 / 8;
    ca.total8 = (1769472 + 589824 + 2359296 + 2359296 + 2304 + 768 + 3072 +
                 768) / 8;
    cvt_all<<<dim3(880), 256, 0, stream>>>(ca, flag);

    ln_kernel<<<dim3(NT / 4), 256, 0, stream>>>(x, ln1_w, ln1_b, hx, flag);
    gemm_fast<0, 128><<<dim3(18, 32), 256, 0, stream>>>(
        hx, wq, bq, nullptr, qkv, 3 * ND, ND, 0, flag);
    flash_attn_v1<<<dim3(NS / 64, NB * NH), 256, 0, stream>>>(qkv, oat);
    gemm64<2><<<dim3(6, 64), 256, 0, stream>>>(
        oat, wo, bo, x, d_out, ND, ND, 0, flag);
    ln_kernel<<<dim3(NT / 4), 256, 0, stream>>>(d_out, ln2_w, ln2_b, h2, flag);
    if (ws_size >= T3) {
      bf16* ff1 = slotB;
      gemm64<1><<<dim3(24, 64), 256, 0, stream>>>(
          h2, w1, b1, nullptr, ff1, NF, ND, 0, flag);
      gemm64<2><<<dim3(6, 64), 256, 0, stream>>>(
          ff1, w2, b2, d_out, d_out, ND, NF, 0, flag);
    } else {
      bf16* ff1c = slotB;
      for (int c = 0; c < 2; ++c) {
        gemm64<1><<<dim3(24, 32), 256, 0, stream>>>(
            h2 + (size_t)c * 2048 * ND, w1, b1, nullptr, ff1c, NF, ND, 0, flag);
        gemm64<2><<<dim3(6, 32), 256, 0, stream>>>(
            ff1c, w2, b2, d_out, d_out, ND, NF, c * 2048, flag);
      }
    }
  } else {
    const size_t szTD = (size_t)NT * ND * sizeof(bf16);
    bf16* slotA = (bf16*)(ws + 256);
    bf16* qkv = (bf16*)(ws + 256 + szTD);
    bf16* hx = slotA, *oat = slotA, *h2 = slotA;
    bf16* ff1c = qkv;

    ln_kernel<<<dim3(NT / 4), 256, 0, stream>>>(x, ln1_w, ln1_b, hx, flag);
    gemm_bt<0><<<dim3(18, 32), 256, 0, stream>>>(
        hx, qkv_w, qkv_b, nullptr, qkv, 3 * ND, ND, 0, flag);
    flash_attn_v1<<<dim3(NS / 64, NB * NH), 256, 0, stream>>>(qkv, oat);
    gemm_bt<2><<<dim3(6, 32), 256, 0, stream>>>(
        oat, out_w, out_b, x, d_out, ND, ND, 0, flag);
    ln_kernel<<<dim3(NT / 4), 256, 0, stream>>>(d_out, ln2_w, ln2_b, h2, flag);
    for (int c = 0; c < 4; ++c) {
      gemm_bt<1><<<dim3(24, 8), 256, 0, stream>>>(
          h2 + (size_t)c * 1024 * ND, fc1_w, fc1_b, nullptr, ff1c, NF, ND, 0,
          flag);
      gemm_bt<2><<<dim3(6, 8), 256, 0, stream>>>(
          ff1c, fc2_w, fc2_b, d_out, d_out, ND, NF, c * 1024, flag);
    }
  }
}

// Round 11
// 304.415 us; speedup vs baseline: 1.0411x; 1.0261x over previous
//
#include <hip/hip_runtime.h>
#include <hip/hip_bf16.h>
#include <cstdint>
#include <cstddef>

typedef __bf16 bf16;
typedef unsigned short ushort_t;
typedef __attribute__((ext_vector_type(8))) __bf16 bf16x8;
typedef __attribute__((ext_vector_type(4))) __bf16 bf16x4;
typedef __attribute__((ext_vector_type(4))) float f32x4;

#define NB 2
#define NS 2048
#define ND 768
#define NH 12
#define NF 3072
#define NT (NB * NS)   // 4096 tokens

__device__ __forceinline__ f32x4 mfma16(bf16x8 a, bf16x8 b, f32x4 c) {
  return __builtin_amdgcn_mfma_f32_16x16x32_bf16(a, b, c, 0, 0, 0);
}

__device__ __forceinline__ void gl_lds16(const bf16* g, bf16* l) {
  __builtin_amdgcn_global_load_lds(
      (__attribute__((address_space(1))) void*)(uintptr_t)g,
      (__attribute__((address_space(3))) void*)l,
      16, 0, 0);
}

// Bijective XCD-chunked swizzle (m204).
__device__ __forceinline__ int xcd_swz(int lin, int nwg) {
  const int q = nwg >> 3, r = nwg & 7;
  const int x = lin & 7, i = lin >> 3;
  return (x < r ? x * (q + 1) : r * (q + 1) + (x - r) * q) + i;
}

// gelu(x) ~= x * sigmoid(2*0.79788456*(x + 0.044715 x^3)); |err| < ~3e-3
__device__ __forceinline__ float gelu_fast(float v) {
  const float u = v * (0.7978845608028654f + 0.03567740814f * v * v);
  const float e = exp2f(u * 2.885390081777927f);  // e^(2u)
  return v - v / (1.f + e);                       // v*e/(1+e)
}

// r11: flash work units in DESCENDING length order (LPT schedule).
// entry = qt*4 + direct*2 + cc. Lengths: direct qt -> qt+1 iters;
// split lo -> (qt+1)/2, hi -> qt+1-(qt+1)/2.
__constant__ unsigned char fs_tab[47] = {
    66,                       // len17: (16,D)
    124, 125, 121, 62,        // len16: (31,lo)(31,hi)(30,hi)(15,D)
    120, 116, 117, 113, 58,   // len15
    112, 108, 109, 105, 54,   // len14
    104, 100, 101, 97, 50,    // len13
    96, 92, 93, 89, 46,       // len12
    88, 84, 85, 81, 42,       // len11
    80, 76, 77, 73, 38,       // len10
    72, 68, 69, 34,           // len9
    30, 26, 22, 18, 14, 10, 6, 2  // len8..1 directs
};

// ---------------- dtype sniffer (flag=1 -> I/O is float32) ----------------
__global__ __launch_bounds__(256) void sniff_kernel(
    const ushort_t* __restrict__ x, int* __restrict__ flag) {
  __shared__ int s[4];
  int bad = 0;
  for (int i = threadIdx.x; i < 4096; i += 256) {
    const int e = (x[i] >> 7) & 0xFF;
    bad |= (e >= 0xC0);
  }
  bad = __any(bad) ? 1 : 0;
  if ((threadIdx.x & 63) == 0) s[threadIdx.x >> 6] = bad;
  __syncthreads();
  if (threadIdx.x == 0) *flag = s[0] | s[1] | s[2] | s[3];
}

// ---------------- merged weight/bias conversion (1 launch) ----------------
struct CvtArgs {
  const void* s[8];
  bf16* d[8];
  int n8[8];
  int total8;
};

__global__ __launch_bounds__(256) void cvt_all(CvtArgs a,
                                               const int* __restrict__ flag) {
  const int isf = *flag;
  const int stride = gridDim.x * 256;
  for (int i = blockIdx.x * 256 + threadIdx.x; i < a.total8; i += stride) {
    int seg = 0, off = i;
    while (off >= a.n8[seg]) { off -= a.n8[seg]; ++seg; }
    bf16x8 o;
    if (isf) {
      const float* s = (const float*)a.s[seg] + (size_t)off * 8;
      const f32x4 f0 = *(const f32x4*)s;
      const f32x4 f1 = *(const f32x4*)(s + 4);
#pragma unroll
      for (int j = 0; j < 4; ++j) {
        o[j] = (bf16)f0[j];
        o[4 + j] = (bf16)f1[j];
      }
    } else {
      o = *((const bf16x8*)a.s[seg] + off);
    }
    *((bf16x8*)a.d[seg] + off) = o;
  }
}

// ---------------- LayerNorm: one wave per row of 768; output bf16 ---------
__global__ __launch_bounds__(256) void ln_kernel(
    const void* __restrict__ xv, const void* __restrict__ wv,
    const void* __restrict__ bv, bf16* __restrict__ y,
    const int* __restrict__ flag) {
  const int isf = *flag;
  const int row = blockIdx.x * 4 + (threadIdx.x >> 6);
  const int L = threadIdx.x & 63;
  const float* xf = (const float*)xv;
  const bf16* xh = (const bf16*)xv;
  const float* wf = (const float*)wv;
  const bf16* wh = (const bf16*)wv;
  const float* bf_ = (const float*)bv;
  const bf16* bh = (const bf16*)bv;
  const size_t base = (size_t)row * ND;
  float v[12];
  float s = 0.f, s2 = 0.f;
#pragma unroll
  for (int i = 0; i < 12; ++i) {
    const int c = L + i * 64;
    v[i] = isf ? xf[base + c] : (float)xh[base + c];
    s += v[i];
    s2 += v[i] * v[i];
  }
#pragma unroll
  for (int off = 1; off < 64; off <<= 1) {
    s += __shfl_xor(s, off);
    s2 += __shfl_xor(s2, off);
  }
  const float mean = s * (1.f / 768.f);
  const float var = s2 * (1.f / 768.f) - mean * mean;
  const float rstd = rsqrtf(var + 1e-5f);
  bf16* yr = y + base;
#pragma unroll
  for (int i = 0; i < 12; ++i) {
    const int c = L + i * 64;
    const float ww = isf ? wf[c] : (float)wh[c];
    const float bb = isf ? bf_[c] : (float)bh[c];
    yr[c] = (bf16)((v[i] - mean) * rstd * ww + bb);
  }
}

// ---------------- V transpose kernel (fallback only) ----------------------
__global__ __launch_bounds__(256) void vt_kernel(
    const bf16* __restrict__ qkv, bf16* __restrict__ vT) {
  const int bh = blockIdx.y;
  const int b = bh / NH, h = bh % NH;
  const int st = blockIdx.x;
  __shared__ bf16 Vs[64 * 72];
  const int tid = threadIdx.x;
  {
    const int r = tid >> 2, c = (tid & 3) * 16;
    const bf16* src =
        qkv + (size_t)(b * NS + st * 64 + r) * (3 * ND) + 2 * ND + h * 64 + c;
    *(bf16x8*)&Vs[r * 72 + c] = *(const bf16x8*)src;
    *(bf16x8*)&Vs[r * 72 + c + 8] = *(const bf16x8*)(src + 8);
  }
  __syncthreads();
  {
    const int hd = tid >> 2, t0 = (tid & 3) * 16;
    bf16x8 o0, o1;
#pragma unroll
    for (int j = 0; j < 8; ++j) {
      o0[j] = Vs[(t0 + j) * 72 + hd];
      o1[j] = Vs[(t0 + 8 + j) * 72 + hd];
    }
    bf16* dst = vT + ((size_t)bh * 64 + hd) * NS + st * 64 + t0;
    *(bf16x8*)dst = o0;
    *(bf16x8*)(dst + 8) = o1;
  }
}

// ---------------- gemm64: 64x128 tile, BK=64 --------------------------------
template <int EPI>
__global__ __launch_bounds__(256) void gemm64(
    const bf16* __restrict__ A, const bf16* __restrict__ Bt,
    const bf16* __restrict__ bias, const void* resid, void* C,
    int N, int K, int row0, const int* __restrict__ flag) {
  constexpr int NBUF = 3;
  __shared__ bf16 As[NBUF][64 * 64];
  __shared__ bf16 Bs[NBUF][128 * 64];
  int isf = 0;
  if (EPI == 2) {
    isf = *flag;
    asm volatile("" ::"s"(isf));
  }
  const int tid = threadIdx.x;
  const int w = tid >> 6, L = tid & 63;
  const int lg = L >> 4, lc = L & 15;
  const int wm = (w >> 1) * 32, wn = (w & 1) * 64;
  const int nwg = gridDim.x * gridDim.y;
  const int lin = xcd_swz(blockIdx.y * gridDim.x + blockIdx.x, nwg);
  const int bm = lin / gridDim.x, bn = lin % gridDim.x;

  const bf16* Ab = A + (size_t)bm * 64 * K;
  const bf16* Bb = Bt + (size_t)bn * 128 * K;

  const int srw = tid >> 3;                      // dest row 0..31 per load
  const int scw = ((tid & 7) ^ (srw & 7)) * 8;   // pre-swizzled source col

  f32x4 acc[2][4];
#pragma unroll
  for (int i = 0; i < 2; ++i)
#pragma unroll
    for (int j = 0; j < 4; ++j) acc[i][j] = (f32x4){0.f, 0.f, 0.f, 0.f};

#define G64_STAGE(buf, kk)                                                  \
  do {                                                                      \
    gl_lds16(Ab + (size_t)srw * K + (kk) + scw, As[buf] + tid * 8);         \
    gl_lds16(Ab + (size_t)(srw + 32) * K + (kk) + scw,                      \
             As[buf] + 2048 + tid * 8);                                     \
    gl_lds16(Bb + (size_t)srw * K + (kk) + scw, Bs[buf] + tid * 8);         \
    gl_lds16(Bb + (size_t)(srw + 32) * K + (kk) + scw,                      \
             Bs[buf] + 2048 + tid * 8);                                     \
    gl_lds16(Bb + (size_t)(srw + 64) * K + (kk) + scw,                      \
             Bs[buf] + 4096 + tid * 8);                                     \
    gl_lds16(Bb + (size_t)(srw + 96) * K + (kk) + scw,                      \
             Bs[buf] + 6144 + tid * 8);                                     \
  } while (0)

#define G64_COMP(cb)                                                        \
  do {                                                                      \
    bf16x8 af[2][2], bfr[2][4];                                             \
    _Pragma("unroll") for (int kk2 = 0; kk2 < 2; ++kk2) {                   \
      _Pragma("unroll") for (int mt = 0; mt < 2; ++mt) {                    \
        const int ra = wm + mt * 16 + lc;                                   \
        af[kk2][mt] = *(const bf16x8*)&As[cb][ra * 64 +                     \
                                             (((kk2 * 4 + lg) ^ (ra & 7))   \
                                              << 3)];                       \
      }                                                                     \
      _Pragma("unroll") for (int nt = 0; nt < 4; ++nt) {                    \
        const int rb = wn + nt * 16 + lc;                                   \
        bfr[kk2][nt] = *(const bf16x8*)&Bs[cb][rb * 64 +                    \
                                              (((kk2 * 4 + lg) ^ (rb & 7))  \
                                               << 3)];                      \
      }                                                                     \
    }                                                                       \
    _Pragma("unroll") for (int kk2 = 0; kk2 < 2; ++kk2)                     \
        _Pragma("unroll") for (int mt = 0; mt < 2; ++mt)                    \
            _Pragma("unroll") for (int nt = 0; nt < 4; ++nt)                \
                acc[mt][nt] = mfma16(af[kk2][mt], bfr[kk2][nt],             \
                                     acc[mt][nt]);                          \
  } while (0)

  const int nk = K >> 6;
  G64_STAGE(0, 0);
  int cur = 0, stg = 1;
  int k = 0;
  for (; k < nk - 1; ++k) {
    G64_STAGE(stg, (k + 1) * 64);
    asm volatile("s_waitcnt vmcnt(6)" ::: "memory");
    asm volatile("s_barrier" ::: "memory");
    G64_COMP(cur);
    cur = (cur + 1 == NBUF) ? 0 : cur + 1;
    stg = (stg + 1 == NBUF) ? 0 : stg + 1;
  }
  __syncthreads();  // drain last stage (vmcnt(0) + barrier)
  G64_COMP(cur);
#undef G64_STAGE
#undef G64_COMP

  const float* rf = (const float*)resid;
  const bf16* rh = (const bf16*)resid;
  float* Cf = (float*)C;
  bf16* Ch = (bf16*)C;
#pragma unroll
  for (int mt = 0; mt < 2; ++mt) {
#pragma unroll
    for (int nt = 0; nt < 4; ++nt) {
      const int col = bn * 128 + wn + nt * 16 + lc;
      const float bv = (float)bias[col];
#pragma unroll
      for (int r = 0; r < 4; ++r) {
        const int row = bm * 64 + wm + mt * 16 + lg * 4 + r;
        float v = acc[mt][nt][r] + bv;
        if (EPI == 1) v = gelu_fast(v);
        const size_t idx = (size_t)(row0 + row) * N + col;
        if (EPI == 2) {
          v += isf ? rf[idx] : (float)rh[idx];
          if (isf) Cf[idx] = v; else Ch[idx] = (bf16)v;
        } else {
          Ch[idx] = (bf16)v;
        }
      }
    }
  }
}

// ---------------- gemm_qkv64: gemm64 structure + fused QKV epilogue -------
__global__ __launch_bounds__(256) void gemm_qkv64(
    const bf16* __restrict__ A, const bf16* __restrict__ Bt,
    const bf16* __restrict__ bias, bf16* __restrict__ qkvout,
    bf16* __restrict__ vT) {
  const int K = ND, N = 3 * ND;
  constexpr int NBUF = 3;
  __shared__ bf16 As[NBUF][64 * 64];
  __shared__ bf16 Bs[NBUF][128 * 64];
  const int tid = threadIdx.x;
  const int w = tid >> 6, L = tid & 63;
  const int lg = L >> 4, lc = L & 15;
  const int wm = (w >> 1) * 32, wn = (w & 1) * 64;
  const int nwg = gridDim.x * gridDim.y;
  const int lin = xcd_swz(blockIdx.y * gridDim.x + blockIdx.x, nwg);
  const int bm = lin / gridDim.x, bn = lin % gridDim.x;

  const bf16* Ab = A + (size_t)bm * 64 * K;
  const bf16* Bb = Bt + (size_t)bn * 128 * K;

  const int srw = tid >> 3;
  const int scw = ((tid & 7) ^ (srw & 7)) * 8;

  f32x4 acc[2][4];
#pragma unroll
  for (int i = 0; i < 2; ++i)
#pragma unroll
    for (int j = 0; j < 4; ++j) acc[i][j] = (f32x4){0.f, 0.f, 0.f, 0.f};

#define Q64_STAGE(buf, kk)                                                  \
  do {                                                                      \
    gl_lds16(Ab + (size_t)srw * K + (kk) + scw, As[buf] + tid * 8);         \
    gl_lds16(Ab + (size_t)(srw + 32) * K + (kk) + scw,                      \
             As[buf] + 2048 + tid * 8);                                     \
    gl_lds16(Bb + (size_t)srw * K + (kk) + scw, Bs[buf] + tid * 8);         \
    gl_lds16(Bb + (size_t)(srw + 32) * K + (kk) + scw,                      \
             Bs[buf] + 2048 + tid * 8);                                     \
    gl_lds16(Bb + (size_t)(srw + 64) * K + (kk) + scw,                      \
             Bs[buf] + 4096 + tid * 8);                                     \
    gl_lds16(Bb + (size_t)(srw + 96) * K + (kk) + scw,                      \
             Bs[buf] + 6144 + tid * 8);                                     \
  } while (0)

#define Q64_COMP(cb)                                                        \
  do {                                                                      \
    bf16x8 af[2][2], bfr[2][4];                                             \
    _Pragma("unroll") for (int kk2 = 0; kk2 < 2; ++kk2) {                   \
      _Pragma("unroll") for (int mt = 0; mt < 2; ++mt) {                    \
        const int ra = wm + mt * 16 + lc;                                   \
        af[kk2][mt] = *(const bf16x8*)&As[cb][ra * 64 +                     \
                                             (((kk2 * 4 + lg) ^ (ra & 7))   \
                                              << 3)];                       \
      }                                                                     \
      _Pragma("unroll") for (int nt = 0; nt < 4; ++nt) {                    \
        const int rb = wn + nt * 16 + lc;                                   \
        bfr[kk2][nt] = *(const bf16x8*)&Bs[cb][rb * 64 +                    \
                                              (((kk2 * 4 + lg) ^ (rb & 7))  \
                                               << 3)];                      \
      }                                                                     \
    }                                                                       \
    _Pragma("unroll") for (int kk2 = 0; kk2 < 2; ++kk2)                     \
        _Pragma("unroll") for (int mt = 0; mt < 2; ++mt)                    \
            _Pragma("unroll") for (int nt = 0; nt < 4; ++nt)                \
                acc[mt][nt] = mfma16(af[kk2][mt], bfr[kk2][nt],             \
                                     acc[mt][nt]);                          \
  } while (0)

  const int nk = K >> 6;  // 12
  Q64_STAGE(0, 0);
  int cur = 0, stg = 1;
  int k = 0;
  for (; k < nk - 1; ++k) {
    Q64_STAGE(stg, (k + 1) * 64);
    asm volatile("s_waitcnt vmcnt(6)" ::: "memory");
    asm volatile("s_barrier" ::: "memory");
    Q64_COMP(cur);
    cur = (cur + 1 == NBUF) ? 0 : cur + 1;
    stg = (stg + 1 == NBUF) ? 0 : stg + 1;
  }
  __syncthreads();
  Q64_COMP(cur);
#undef Q64_STAGE
#undef Q64_COMP

#pragma unroll
  for (int mt = 0; mt < 2; ++mt) {
#pragma unroll
    for (int nt = 0; nt < 4; ++nt) {
      const int col = bn * 128 + wn + nt * 16 + lc;
      const float bv = (float)bias[col];
      if (col < 2 * ND) {  // Q or K -> qkv buffer
#pragma unroll
        for (int r = 0; r < 4; ++r) {
          const int row = bm * 64 + wm + mt * 16 + lg * 4 + r;
          qkvout[(size_t)row * N + col] = (bf16)(acc[mt][nt][r] + bv);
        }
      } else {  // V -> vT[bh][hd][token], 4 consecutive tokens per lane
        const int colv = col - 2 * ND;
        const int h_ = colv >> 6, hd = colv & 63;
        bf16x4 pk;
#pragma unroll
        for (int r = 0; r < 4; ++r) pk[r] = (bf16)(acc[mt][nt][r] + bv);
        const int tok0 = bm * 64 + wm + mt * 16 + lg * 4;
        const int b_ = tok0 >> 11, s0 = tok0 & (NS - 1);
        *(bf16x4*)&vT[((size_t)(b_ * NH + h_) * 64 + hd) * NS + s0] = pk;
      }
    }
  }
}

// ---------------- fast GEMM (TM=128): counted-vmcnt + T2 swizzle ----------
template <int EPI, int TM>
__global__ __launch_bounds__(256) void gemm_fast(
    const bf16* __restrict__ A, const bf16* __restrict__ Bt,
    const bf16* __restrict__ bias, const void* resid, void* C,
    int N, int K, int row0, const int* __restrict__ flag) {
  constexpr int NBUF = (TM == 64) ? 5 : 3;
  constexpr int LOOK = NBUF - 2;
  constexpr int MT = TM / 32;
  __shared__ bf16 As[NBUF][TM * 32];
  __shared__ bf16 Bs[NBUF][128 * 32];
  int isf = 0;
  if (EPI == 2) {
    isf = *flag;
    asm volatile("" ::"s"(isf));
  }
  const int tid = threadIdx.x;
  const int w = tid >> 6, L = tid & 63;
  const int lg = L >> 4, lc = L & 15;
  const int lgx = (lg ^ ((lc >> 1) & 3)) * 8;
  const int wm = (w >> 1) * (TM / 2), wn = (w & 1) * 64;
  const int nwg = gridDim.x * gridDim.y;
  const int lin = xcd_swz(blockIdx.y * gridDim.x + blockIdx.x, nwg);
  const int bm = lin / gridDim.x, bn = lin % gridDim.x;

  const bf16* Ab = A + (size_t)bm * TM * K;
  const bf16* Bb = Bt + (size_t)bn * 128 * K;

  const int sr = tid >> 2;
  const int sc = ((tid & 3) ^ ((tid >> 3) & 3)) * 8;

  f32x4 acc[MT][4];
#pragma unroll
  for (int i = 0; i < MT; ++i)
#pragma unroll
    for (int j = 0; j < 4; ++j) acc[i][j] = (f32x4){0.f, 0.f, 0.f, 0.f};

#define GF_STAGE(buf, kk)                                                   \
  do {                                                                      \
    gl_lds16(Ab + (size_t)sr * K + (kk) + sc, As[buf] + tid * 8);           \
    if (TM == 128)                                                          \
      gl_lds16(Ab + (size_t)(sr + 64) * K + (kk) + sc,                      \
               As[buf] + 2048 + tid * 8);                                   \
    gl_lds16(Bb + (size_t)sr * K + (kk) + sc, Bs[buf] + tid * 8);           \
    gl_lds16(Bb + (size_t)(sr + 64) * K + (kk) + sc,                        \
             Bs[buf] + 2048 + tid * 8);                                     \
  } while (0)

#define GF_COMP(cb)                                                         \
  do {                                                                      \
    bf16x8 af[MT], bfr[4];                                                  \
    _Pragma("unroll") for (int mt = 0; mt < MT; ++mt) af[mt] =              \
        *(const bf16x8*)&As[cb][(wm + mt * 16 + lc) * 32 + lgx];            \
    _Pragma("unroll") for (int nt = 0; nt < 4; ++nt) bfr[nt] =              \
        *(const bf16x8*)&Bs[cb][(wn + nt * 16 + lc) * 32 + lgx];            \
    _Pragma("unroll") for (int mt = 0; mt < MT; ++mt)                       \
        _Pragma("unroll") for (int nt = 0; nt < 4; ++nt) acc[mt][nt] =      \
            mfma16(af[mt], bfr[nt], acc[mt][nt]);                           \
  } while (0)

  const int nk = K >> 5;
#pragma unroll
  for (int s = 0; s < LOOK; ++s)
    if (s < nk) GF_STAGE(s, s * 32);
  int cur = 0, stg = LOOK;
  int k = 0;
  const int kmain = (nk > LOOK) ? nk - LOOK : 0;
  for (; k < kmain; ++k) {
    GF_STAGE(stg, (k + LOOK) * 32);
    if (TM == 64)
      asm volatile("s_waitcnt vmcnt(9)" ::: "memory");
    else
      asm volatile("s_waitcnt vmcnt(4)" ::: "memory");
    asm volatile("s_barrier" ::: "memory");
    GF_COMP(cur);
    cur = (cur + 1 == NBUF) ? 0 : cur + 1;
    stg = (stg + 1 == NBUF) ? 0 : stg + 1;
  }
  __syncthreads();
  for (; k < nk; ++k) {
    GF_COMP(cur);
    cur = (cur + 1 == NBUF) ? 0 : cur + 1;
  }
#undef GF_STAGE
#undef GF_COMP

  const float* rf = (const float*)resid;
  const bf16* rh = (const bf16*)resid;
  float* Cf = (float*)C;
  bf16* Ch = (bf16*)C;
#pragma unroll
  for (int mt = 0; mt < MT; ++mt) {
#pragma unroll
    for (int nt = 0; nt < 4; ++nt) {
      const int col = bn * 128 + wn + nt * 16 + lc;
      const float bv = (float)bias[col];
#pragma unroll
      for (int r = 0; r < 4; ++r) {
        const int row = bm * TM + wm + mt * 16 + lg * 4 + r;
        float v = acc[mt][nt][r] + bv;
        if (EPI == 1) v = gelu_fast(v);
        const size_t idx = (size_t)(row0 + row) * N + col;
        if (EPI == 2) {
          v += isf ? rf[idx] : (float)rh[idx];
          if (isf) Cf[idx] = v; else Ch[idx] = (bf16)v;
        } else {
          Ch[idx] = (bf16)v;
        }
      }
    }
  }
}

// ---------------- fallback GEMM (dtype-branch staging, round-3) -----------
template <int EPI>
__global__ __launch_bounds__(256) void gemm_bt(
    const bf16* __restrict__ A, const void* __restrict__ Bt,
    const void* __restrict__ bias, const void* resid, void* C,
    int N, int K, int row0, const int* __restrict__ flag) {
  __shared__ bf16 As[128 * 32];
  __shared__ bf16 Bs[128 * 32];
  const int isf = *flag;
  const int tid = threadIdx.x;
  const int w = tid >> 6, L = tid & 63;
  const int lg = L >> 4, lc = L & 15;
  const int wm = (w >> 1) * 64, wn = (w & 1) * 64;
  const int nwg = gridDim.x * gridDim.y;
  const int lin = xcd_swz(blockIdx.y * gridDim.x + blockIdx.x, nwg);
  const int bm = lin / gridDim.x, bn = lin % gridDim.x;

  const bf16* Ab = A + (size_t)bm * 128 * K;
  const bf16* Bth = (const bf16*)Bt + (size_t)bn * 128 * K;
  const float* Btf = (const float*)Bt + (size_t)bn * 128 * K;

  const int sr = tid >> 1;
  const int sc = (tid & 1) * 16;

  f32x4 acc[4][4];
#pragma unroll
  for (int i = 0; i < 4; ++i)
#pragma unroll
    for (int j = 0; j < 4; ++j) acc[i][j] = (f32x4){0.f, 0.f, 0.f, 0.f};

  for (int k0 = 0; k0 < K; k0 += 32) {
    const bf16* ap = Ab + (size_t)sr * K + k0 + sc;
    const bf16x8 a0 = *(const bf16x8*)ap;
    const bf16x8 a1 = *(const bf16x8*)(ap + 8);
    bf16x8 b0, b1;
    if (isf) {
      const float* bp = Btf + (size_t)sr * K + k0 + sc;
      const f32x4 f0 = *(const f32x4*)bp;
      const f32x4 f1 = *(const f32x4*)(bp + 4);
      const f32x4 f2 = *(const f32x4*)(bp + 8);
      const f32x4 f3 = *(const f32x4*)(bp + 12);
#pragma unroll
      for (int j = 0; j < 4; ++j) {
        b0[j] = (bf16)f0[j];
        b0[4 + j] = (bf16)f1[j];
        b1[j] = (bf16)f2[j];
        b1[4 + j] = (bf16)f3[j];
      }
    } else {
      const bf16* bp = Bth + (size_t)sr * K + k0 + sc;
      b0 = *(const bf16x8*)bp;
      b1 = *(const bf16x8*)(bp + 8);
    }
    __syncthreads();
    *(bf16x8*)&As[sr * 32 + sc] = a0;
    *(bf16x8*)&As[sr * 32 + sc + 8] = a1;
    *(bf16x8*)&Bs[sr * 32 + sc] = b0;
    *(bf16x8*)&Bs[sr * 32 + sc + 8] = b1;
    __syncthreads();

    bf16x8 af[4], bfr[4];
#pragma unroll
    for (int mt = 0; mt < 4; ++mt)
      af[mt] = *(const bf16x8*)&As[(wm + mt * 16 + lc) * 32 + lg * 8];
#pragma unroll
    for (int nt = 0; nt < 4; ++nt)
      bfr[nt] = *(const bf16x8*)&Bs[(wn + nt * 16 + lc) * 32 + lg * 8];
#pragma unroll
    for (int mt = 0; mt < 4; ++mt)
#pragma unroll
      for (int nt = 0; nt < 4; ++nt)
        acc[mt][nt] = mfma16(af[mt], bfr[nt], acc[mt][nt]);
  }

  const float* biasf = (const float*)bias;
  const bf16* biash = (const bf16*)bias;
  const float* rf = (const float*)resid;
  const bf16* rh = (const bf16*)resid;
  float* Cf = (float*)C;
  bf16* Ch = (bf16*)C;
#pragma unroll
  for (int mt = 0; mt < 4; ++mt) {
#pragma unroll
    for (int nt = 0; nt < 4; ++nt) {
      const int col = bn * 128 + wn + nt * 16 + lc;
      const float bv = isf ? biasf[col] : (float)biash[col];
#pragma unroll
      for (int r = 0; r < 4; ++r) {
        const int row = bm * 128 + wm + mt * 16 + lg * 4 + r;
        float v = acc[mt][nt][r] + bv;
        if (EPI == 1) v = gelu_fast(v);
        const size_t idx = (size_t)(row0 + row) * N + col;
        if (EPI == 2) {
          v += isf ? rf[idx] : (float)rh[idx];
          if (isf) Cf[idx] = v; else Ch[idx] = (bf16)v;
        } else {
          Ch[idx] = (bf16)v;
        }
      }
    }
  }
}

// ---------------- Flash attention v12: split-KV + LPT dispatch order ------
// r10 structure (proven 47.2us) with ONE change: block c decodes through
// fs_tab (descending-length LPT order, bh interleaved) so the hardware's
// sequential workgroup dispatch starts long blocks FIRST. Old order put
// 16-iter direct tiles after the 9-iter splits -> late-start x length tail.
__global__ __launch_bounds__(128) void flash_attn_sp(
    const bf16* __restrict__ qkv, const bf16* __restrict__ vT,
    bf16* __restrict__ o, float* __restrict__ po, float* __restrict__ pl) {
  const int nwg = gridDim.x * gridDim.y;  // 1128 = 8 XCD * 141
  const int lin = xcd_swz(blockIdx.y * gridDim.x + blockIdx.x, nwg);
  const int i141 = lin % 141;
  const int t = i141 / 3, bl = i141 % 3;       // LPT index, bh interleave
  const int bh = (lin / 141) * 3 + bl;
  const int b = bh / NH, h = bh % NH;
  const unsigned v_ = fs_tab[t];
  const int qt = v_ >> 2;
  const int direct = (v_ >> 1) & 1;
  const int cc = v_ & 1;
  int kt_lo, kt_hi;
  if (direct) {
    kt_lo = 0; kt_hi = qt;
  } else {
    const int hh = (qt + 1) >> 1;
    if (cc) { kt_lo = hh; kt_hi = qt; }
    else    { kt_lo = 0;  kt_hi = hh - 1; }
  }
  const int q0 = qt * 64;
  const int tid = threadIdx.x;  // 128 threads = 2 waves
  const int w = tid >> 6, L = tid & 63;
  const int lg = L >> 4, lc = L & 15;

  __shared__ bf16 Ks[64 * 72];   // [kv][hd]
  __shared__ bf16 Vts[64 * 72];  // [hd][kv]
  __shared__ bf16 Ps[2][32 * 72];

  const float QSCALE = 0.18033688011112042f;  // (1/8) * log2(e)
  bf16x8 qf[2][2];
#pragma unroll
  for (int m = 0; m < 2; ++m) {
    const size_t tokq = (size_t)(b * NS + q0 + w * 32 + m * 16 + lc);
    const bf16* qp = qkv + tokq * (3 * ND) + h * 64 + lg * 8;
    const bf16x8 q0r = *(const bf16x8*)qp;
    const bf16x8 q1r = *(const bf16x8*)(qp + 32);
#pragma unroll
    for (int jj = 0; jj < 8; ++jj) {
      qf[m][0][jj] = (bf16)((float)q0r[jj] * QSCALE);
      qf[m][1][jj] = (bf16)((float)q1r[jj] * QSCALE);
    }
  }

  const int kr = tid >> 1, kc = (tid & 1) * 32;
  const bf16* kbase =
      qkv + (size_t)(b * NS + kr) * (3 * ND) + ND + h * 64 + kc;
  const bf16* vbase = vT + ((size_t)bh * 64 + kr) * NS + kc;

  f32x4 oacc[2][4];
#pragma unroll
  for (int m = 0; m < 2; ++m)
#pragma unroll
    for (int nt = 0; nt < 4; ++nt) oacc[m][nt] = (f32x4){0.f, 0.f, 0.f, 0.f};
  float lacc[2] = {0.f, 0.f};

  bf16x8 kreg[4], vreg[4];
  {
    const bf16* kn = kbase + (size_t)kt_lo * 64 * (3 * ND);
    const bf16* vn = vbase + (size_t)kt_lo * 64;
#pragma unroll
    for (int p = 0; p < 4; ++p) {
      kreg[p] = *(const bf16x8*)(kn + p * 8);
      vreg[p] = *(const bf16x8*)(vn + p * 8);
    }
  }

  for (int kt = kt_lo; kt <= kt_hi; ++kt) {
    __syncthreads();
#pragma unroll
    for (int p = 0; p < 4; ++p) {
      *(bf16x8*)&Ks[kr * 72 + kc + p * 8] = kreg[p];
      *(bf16x8*)&Vts[kr * 72 + kc + p * 8] = vreg[p];
    }
    __syncthreads();

    if (kt < kt_hi) {
      const bf16* kn = kbase + (size_t)(kt + 1) * 64 * (3 * ND);
      const bf16* vn = vbase + (size_t)(kt + 1) * 64;
#pragma unroll
      for (int p = 0; p < 4; ++p) {
        kreg[p] = *(const bf16x8*)(kn + p * 8);
        vreg[p] = *(const bf16x8*)(vn + p * 8);
      }
    }

    f32x4 s[2][4];
    __builtin_amdgcn_s_setprio(1);
#pragma unroll
    for (int nt = 0; nt < 4; ++nt) {
      const bf16x8 kb0 = *(const bf16x8*)&Ks[(nt * 16 + lc) * 72 + lg * 8];
      const bf16x8 kb1 =
          *(const bf16x8*)&Ks[(nt * 16 + lc) * 72 + 32 + lg * 8];
#pragma unroll
      for (int m = 0; m < 2; ++m) {
        f32x4 z = (f32x4){0.f, 0.f, 0.f, 0.f};
        s[m][nt] = mfma16(kb0, qf[m][0], z);
        s[m][nt] = mfma16(kb1, qf[m][1], s[m][nt]);
      }
    }
    __builtin_amdgcn_s_setprio(0);
    if (kt == qt) {
#pragma unroll
      for (int m = 0; m < 2; ++m)
#pragma unroll
        for (int nt = 0; nt < 4; ++nt)
#pragma unroll
          for (int r = 0; r < 4; ++r) {
            const int kv = nt * 16 + lg * 4 + r;
            const int qrow = w * 32 + m * 16 + lc;
            if (kv > qrow) s[m][nt][r] = -1.0e30f;
          }
    }
#pragma unroll
    for (int m = 0; m < 2; ++m)
#pragma unroll
      for (int nt = 0; nt < 4; ++nt) {
        bf16x4 pk;
#pragma unroll
        for (int r = 0; r < 4; ++r) {
          const float p = exp2f(fminf(s[m][nt][r], 20.f));
          lacc[m] += p;
          pk[r] = (bf16)p;
        }
        *(bf16x4*)&Ps[w][(m * 16 + lc) * 72 + nt * 16 + lg * 4] = pk;
      }
    bf16x8 pa[2][2];
#pragma unroll
    for (int m = 0; m < 2; ++m) {
      pa[m][0] = *(const bf16x8*)&Ps[w][(m * 16 + lc) * 72 + lg * 8];
      pa[m][1] = *(const bf16x8*)&Ps[w][(m * 16 + lc) * 72 + 32 + lg * 8];
    }
    __builtin_amdgcn_s_setprio(1);
#pragma unroll
    for (int nt = 0; nt < 4; ++nt) {
      const bf16x8 v0 = *(const bf16x8*)&Vts[(nt * 16 + lc) * 72 + lg * 8];
      const bf16x8 v1 =
          *(const bf16x8*)&Vts[(nt * 16 + lc) * 72 + 32 + lg * 8];
#pragma unroll
      for (int m = 0; m < 2; ++m) {
        oacc[m][nt] = mfma16(pa[m][0], v0, oacc[m][nt]);
        oacc[m][nt] = mfma16(pa[m][1], v1, oacc[m][nt]);
      }
    }
    __builtin_amdgcn_s_setprio(0);
  }

#pragma unroll
  for (int m = 0; m < 2; ++m) {
    lacc[m] += __shfl_xor(lacc[m], 16);
    lacc[m] += __shfl_xor(lacc[m], 32);
  }

  if (direct) {
    float lr[2][4];
#pragma unroll
    for (int m = 0; m < 2; ++m)
#pragma unroll
      for (int r = 0; r < 4; ++r) lr[m][r] = __shfl(lacc[m], lg * 4 + r);
#pragma unroll
    for (int m = 0; m < 2; ++m)
#pragma unroll
      for (int nt = 0; nt < 4; ++nt)
#pragma unroll
        for (int r = 0; r < 4; ++r) {
          const int qrow = q0 + w * 32 + m * 16 + lg * 4 + r;
          const float val = oacc[m][nt][r] / lr[m][r];
          o[(size_t)(b * NS + qrow) * ND + h * 64 + nt * 16 + lc] =
              (bf16)val;
        }
  } else {
    const int slot = qt - 17;  // 0..14
    float* pob = po + (((size_t)(bh * 15 + slot)) * 2 + cc) * 4096;
#pragma unroll
    for (int m = 0; m < 2; ++m)
#pragma unroll
      for (int nt = 0; nt < 4; ++nt)
#pragma unroll
        for (int r = 0; r < 4; ++r) {
          const int row = w * 32 + m * 16 + lg * 4 + r;
          const int col = nt * 16 + lc;
          pob[row * 64 + col] = oacc[m][nt][r];
        }
    if (L < 16) {
      float* plb = pl + ((bh * 15 + slot) * 2 + cc) * 64;
      plb[w * 32 + L] = lacc[0];
      plb[w * 32 + 16 + L] = lacc[1];
    }
  }
}

// ---------------- attention partial combine (qt>=17 tiles) ----------------
__global__ __launch_bounds__(256) void attn_combine(
    const float* __restrict__ po, const float* __restrict__ pl,
    bf16* __restrict__ o) {
  const int slot = blockIdx.x;  // 0..14 -> qt = slot+17
  const int bh = blockIdx.y;    // 0..23
  const int qt = slot + 17;
  const int b = bh / NH, h = bh % NH;
  const float* poA = po + ((size_t)(bh * 15 + slot)) * 2 * 4096;
  const float* poB = poA + 4096;
  const float* plA = pl + (bh * 15 + slot) * 2 * 64;
  const float* plB = plA + 64;
  for (int e = threadIdx.x; e < 4096; e += 256) {
    const int q = e >> 6, hd = e & 63;
    const float val = (poA[e] + poB[e]) / (plA[q] + plB[q]);
    o[(size_t)(b * NS + qt * 64 + q) * ND + h * 64 + hd] = (bf16)val;
  }
}

// ---------------- Flash attention v9 (T2 tier: no partial workspace) ------
__global__ __launch_bounds__(128) void flash_attn_v7(
    const bf16* __restrict__ qkv, const bf16* __restrict__ vT,
    bf16* __restrict__ o) {
  const int nwg = gridDim.x * gridDim.y;  // 768 = 8 XCD * 96
  const int lin = xcd_swz(blockIdx.y * gridDim.x + blockIdx.x, nwg);
  const int xcd = lin / 96;
  const int i96 = lin % 96;
  const int bl = i96 >> 5;
  const int j = i96 & 31;
  const int bh = xcd * 3 + bl;
  const int b = bh / NH, h = bh % NH;
  int qt;
  if (bl == 0) qt = j;
  else if (bl == 1) qt = (j + 16) & 31;
  else qt = (j < 16) ? (31 - 2 * j) : (62 - 2 * j);
  const int q0 = qt * 64;
  const int tid = threadIdx.x;
  const int w = tid >> 6, L = tid & 63;
  const int lg = L >> 4, lc = L & 15;

  __shared__ bf16 Ks[2][64 * 72];
  __shared__ bf16 Vts[2][64 * 72];
  __shared__ bf16 Ps[2][32 * 72];

  const float QSCALE = 0.18033688011112042f;
  bf16x8 qf[2][2];
#pragma unroll
  for (int m = 0; m < 2; ++m) {
    const size_t tokq = (size_t)(b * NS + q0 + w * 32 + m * 16 + lc);
    const bf16* qp = qkv + tokq * (3 * ND) + h * 64 + lg * 8;
    const bf16x8 q0r = *(const bf16x8*)qp;
    const bf16x8 q1r = *(const bf16x8*)(qp + 32);
#pragma unroll
    for (int jj = 0; jj < 8; ++jj) {
      qf[m][0][jj] = (bf16)((float)q0r[jj] * QSCALE);
      qf[m][1][jj] = (bf16)((float)q1r[jj] * QSCALE);
    }
  }

  const int kr = tid >> 1, kc = (tid & 1) * 32;
  const bf16* kbase =
      qkv + (size_t)(b * NS + kr) * (3 * ND) + ND + h * 64 + kc;
  const bf16* vbase = vT + ((size_t)bh * 64 + kr) * NS + kc;

  f32x4 oacc[2][4];
#pragma unroll
  for (int m = 0; m < 2; ++m)
#pragma unroll
    for (int nt = 0; nt < 4; ++nt) oacc[m][nt] = (f32x4){0.f, 0.f, 0.f, 0.f};
  float lacc[2] = {0.f, 0.f};

  const int nkt = qt + 1;

  bf16x8 kreg[4], vreg[4];
#pragma unroll
  for (int p = 0; p < 4; ++p) {
    kreg[p] = *(const bf16x8*)(kbase + p * 8);
    vreg[p] = *(const bf16x8*)(vbase + p * 8);
  }
#pragma unroll
  for (int p = 0; p < 4; ++p) {
    *(bf16x8*)&Ks[0][kr * 72 + kc + p * 8] = kreg[p];
    *(bf16x8*)&Vts[0][kr * 72 + kc + p * 8] = vreg[p];
  }

  for (int kt = 0; kt < nkt; ++kt) {
    __syncthreads();
    const int cur = kt & 1;

    if (kt + 1 < nkt) {
      const bf16* kn = kbase + (size_t)(kt + 1) * 64 * (3 * ND);
      const bf16* vn = vbase + (size_t)(kt + 1) * 64;
#pragma unroll
      for (int p = 0; p < 4; ++p) {
        kreg[p] = *(const bf16x8*)(kn + p * 8);
        vreg[p] = *(const bf16x8*)(vn + p * 8);
      }
    }

    f32x4 s[2][4];
    __builtin_amdgcn_s_setprio(1);
#pragma unroll
    for (int nt = 0; nt < 4; ++nt) {
      const bf16x8 kb0 =
          *(const bf16x8*)&Ks[cur][(nt * 16 + lc) * 72 + lg * 8];
      const bf16x8 kb1 =
          *(const bf16x8*)&Ks[cur][(nt * 16 + lc) * 72 + 32 + lg * 8];
#pragma unroll
      for (int m = 0; m < 2; ++m) {
        f32x4 z = (f32x4){0.f, 0.f, 0.f, 0.f};
        s[m][nt] = mfma16(kb0, qf[m][0], z);
        s[m][nt] = mfma16(kb1, qf[m][1], s[m][nt]);
      }
    }
    __builtin_amdgcn_s_setprio(0);
    if (kt == nkt - 1) {
#pragma unroll
      for (int m = 0; m < 2; ++m)
#pragma unroll
        for (int nt = 0; nt < 4; ++nt)
#pragma unroll
          for (int r = 0; r < 4; ++r) {
            const int kv = nt * 16 + lg * 4 + r;
            const int qrow = w * 32 + m * 16 + lc;
            if (kv > qrow) s[m][nt][r] = -1.0e30f;
          }
    }
#pragma unroll
    for (int m = 0; m < 2; ++m)
#pragma unroll
      for (int nt = 0; nt < 4; ++nt) {
        bf16x4 pk;
#pragma unroll
        for (int r = 0; r < 4; ++r) {
          const float p = exp2f(fminf(s[m][nt][r], 20.f));
          lacc[m] += p;
          pk[r] = (bf16)p;
        }
        *(bf16x4*)&Ps[w][(m * 16 + lc) * 72 + nt * 16 + lg * 4] = pk;
      }
    bf16x8 pa[2][2];
#pragma unroll
    for (int m = 0; m < 2; ++m) {
      pa[m][0] = *(const bf16x8*)&Ps[w][(m * 16 + lc) * 72 + lg * 8];
      pa[m][1] = *(const bf16x8*)&Ps[w][(m * 16 + lc) * 72 + 32 + lg * 8];
    }

    if (kt + 1 < nkt) {
      const int nxt = cur ^ 1;
#pragma unroll
      for (int p = 0; p < 4; ++p) {
        *(bf16x8*)&Ks[nxt][kr * 72 + kc + p * 8] = kreg[p];
        *(bf16x8*)&Vts[nxt][kr * 72 + kc + p * 8] = vreg[p];
      }
    }

    __builtin_amdgcn_s_setprio(1);
#pragma unroll
    for (int nt = 0; nt < 4; ++nt) {
      const bf16x8 v0 =
          *(const bf16x8*)&Vts[cur][(nt * 16 + lc) * 72 + lg * 8];
      const bf16x8 v1 =
          *(const bf16x8*)&Vts[cur][(nt * 16 + lc) * 72 + 32 + lg * 8];
#pragma unroll
      for (int m = 0; m < 2; ++m) {
        oacc[m][nt] = mfma16(pa[m][0], v0, oacc[m][nt]);
        oacc[m][nt] = mfma16(pa[m][1], v1, oacc[m][nt]);
      }
    }
    __builtin_amdgcn_s_setprio(0);
  }

#pragma unroll
  for (int m = 0; m < 2; ++m) {
    lacc[m] += __shfl_xor(lacc[m], 16);
    lacc[m] += __shfl_xor(lacc[m], 32);
  }
  float lr[2][4];
#pragma unroll
  for (int m = 0; m < 2; ++m)
#pragma unroll
    for (int r = 0; r < 4; ++r) lr[m][r] = __shfl(lacc[m], lg * 4 + r);

#pragma unroll
  for (int m = 0; m < 2; ++m)
#pragma unroll
    for (int nt = 0; nt < 4; ++nt)
#pragma unroll
      for (int r = 0; r < 4; ++r) {
        const int qrow = q0 + w * 32 + m * 16 + lg * 4 + r;
        const float val = oacc[m][nt][r] / lr[m][r];
        o[(size_t)(b * NS + qrow) * ND + h * 64 + nt * 16 + lc] = (bf16)val;
      }
}

// ---------------- Flash attention v1 (fallback tiers, no vT) --------------
__global__ __launch_bounds__(256) void flash_attn_v1(
    const bf16* __restrict__ qkv, bf16* __restrict__ o) {
  const int bh = blockIdx.y;
  const int b = bh / NH, h = bh % NH;
  const int qt = gridDim.x - 1 - blockIdx.x;
  const int q0 = qt * 64;
  const int tid = threadIdx.x;
  const int w = tid >> 6, L = tid & 63;
  const int lg = L >> 4, lc = L & 15;

  __shared__ bf16 Ks[64 * 72];
  __shared__ bf16 Vts[64 * 72];
  __shared__ bf16 Ps[4][16 * 72];

  const float QSCALE = 0.18033688011112042f;
  const size_t tokq = (size_t)(b * NS + q0 + w * 16 + lc);
  const bf16* qp = qkv + tokq * (3 * ND) + h * 64 + lg * 8;
  const bf16x8 qr0 = *(const bf16x8*)qp;
  const bf16x8 qr1 = *(const bf16x8*)(qp + 32);
  bf16x8 qf0, qf1;
#pragma unroll
  for (int j = 0; j < 8; ++j) {
    qf0[j] = (bf16)((float)qr0[j] * QSCALE);
    qf1[j] = (bf16)((float)qr1[j] * QSCALE);
  }

  f32x4 oacc[4];
#pragma unroll
  for (int nt = 0; nt < 4; ++nt) oacc[nt] = (f32x4){0.f, 0.f, 0.f, 0.f};
  float lacc[4] = {0.f, 0.f, 0.f, 0.f};

  for (int kt = 0; kt <= qt; ++kt) {
    __syncthreads();
#pragma unroll
    for (int p = 0; p < 2; ++p) {
      const int r = (p * 256 + tid) >> 3;
      const int c = (tid & 7) * 8;
      const bf16* kp =
          qkv + (size_t)(b * NS + kt * 64 + r) * (3 * ND) + ND + h * 64 + c;
      const bf16x8 k8 = *(const bf16x8*)kp;
      *(bf16x8*)&Ks[r * 72 + c] = k8;
      const bf16x8 v8 = *(const bf16x8*)(kp + ND);
#pragma unroll
      for (int j = 0; j < 8; ++j) Vts[(c + j) * 72 + r] = v8[j];
    }
    __syncthreads();

    f32x4 s[4];
#pragma unroll
    for (int nt = 0; nt < 4; ++nt) {
      const bf16x8 b0 = *(const bf16x8*)&Ks[(nt * 16 + lc) * 72 + lg * 8];
      const bf16x8 b1 = *(const bf16x8*)&Ks[(nt * 16 + lc) * 72 + 32 + lg * 8];
      f32x4 z = (f32x4){0.f, 0.f, 0.f, 0.f};
      s[nt] = mfma16(qf0, b0, z);
      s[nt] = mfma16(qf1, b1, s[nt]);
    }
    if (kt == qt) {
#pragma unroll
      for (int nt = 0; nt < 4; ++nt)
#pragma unroll
        for (int r = 0; r < 4; ++r) {
          const int qrow = w * 16 + lg * 4 + r;
          const int kcol = nt * 16 + lc;
          if (kcol > qrow) s[nt][r] = -1.0e30f;
        }
    }
#pragma unroll
    for (int nt = 0; nt < 4; ++nt)
#pragma unroll
      for (int r = 0; r < 4; ++r) {
        const float p = exp2f(fminf(s[nt][r], 20.f));
        lacc[r] += p;
        Ps[w][(lg * 4 + r) * 72 + nt * 16 + lc] = (bf16)p;
      }
    __syncthreads();

    const bf16x8 p0 = *(const bf16x8*)&Ps[w][lc * 72 + lg * 8];
    const bf16x8 p1 = *(const bf16x8*)&Ps[w][lc * 72 + 32 + lg * 8];
#pragma unroll
    for (int nt = 0; nt < 4; ++nt) {
      const bf16x8 v0 = *(const bf16x8*)&Vts[(nt * 16 + lc) * 72 + lg * 8];
      const bf16x8 v1 = *(const bf16x8*)&Vts[(nt * 16 + lc) * 72 + 32 + lg * 8];
      oacc[nt] = mfma16(p0, v0, oacc[nt]);
      oacc[nt] = mfma16(p1, v1, oacc[nt]);
    }
  }

#pragma unroll
  for (int msk = 1; msk < 16; msk <<= 1)
#pragma unroll
    for (int r = 0; r < 4; ++r) lacc[r] += __shfl_xor(lacc[r], msk);

#pragma unroll
  for (int nt = 0; nt < 4; ++nt)
#pragma unroll
    for (int r = 0; r < 4; ++r) {
      const int qrow = q0 + w * 16 + lg * 4 + r;
      const float val = oacc[nt][r] / lacc[r];
      o[(size_t)(b * NS + qrow) * ND + h * 64 + nt * 16 + lc] = (bf16)val;
    }
}

// ---------------- launcher ----------------
extern "C" void kernel_launch(void* const* d_in, const int* in_sizes, int n_in,
                              void* d_out, int out_size, void* d_ws,
                              size_t ws_size, hipStream_t stream) {
  const void* x = d_in[0];
  const void* qkv_w = d_in[2];
  const void* qkv_b = d_in[3];
  const void* out_w = d_in[4];
  const void* out_b = d_in[5];
  const void* fc1_w = d_in[6];
  const void* fc1_b = d_in[7];
  const void* fc2_w = d_in[8];
  const void* fc2_b = d_in[9];
  const void* ln1_w = d_in[10];
  const void* ln1_b = d_in[11];
  const void* ln2_w = d_in[12];
  const void* ln2_b = d_in[13];
  (void)in_sizes; (void)n_in; (void)out_size;

  char* ws = (char*)d_ws;
  int* flag = (int*)ws;

  sniff_kernel<<<dim3(1), 256, 0, stream>>>((const ushort_t*)x, flag);

  const size_t T1 = 58210048, T2 = 51918592, T3 = 45627136, T4 = 39335680;

  if (ws_size >= T2) {
    bf16* wq = (bf16*)(ws + 256);
    bf16* wo = wq + 1769472;
    bf16* w1 = wo + 589824;
    bf16* w2 = w1 + 2359296;
    bf16* bq = w2 + 2359296;
    bf16* bo = bq + 2304;
    bf16* b1 = bo + 768;
    bf16* b2 = b1 + 3072;
    bf16* slotA = b2 + 768;
    bf16* vT = slotA + (size_t)NT * ND;
    bf16* slotB = vT + (size_t)NT * ND;
    bf16* hx = slotA, *oat = slotA, *h2 = slotA;
    bf16* qkv = slotB;
    float* po = (float*)(ws + 45627136);
    float* pl = po + (size_t)24 * 15 * 2 * 4096;
    const bool sp = ws_size >= T1;

    CvtArgs ca;
    ca.s[0] = qkv_w; ca.d[0] = wq; ca.n8[0] = 1769472 / 8;
    ca.s[1] = out_w; ca.d[1] = wo; ca.n8[1] = 589824 / 8;
    ca.s[2] = fc1_w; ca.d[2] = w1; ca.n8[2] = 2359296 / 8;
    ca.s[3] = fc2_w; ca.d[3] = w2; ca.n8[3] = 2359296 / 8;
    ca.s[4] = qkv_b; ca.d[4] = bq; ca.n8[4] = 2304 / 8;
    ca.s[5] = out_b; ca.d[5] = bo; ca.n8[5] = 768 / 8;
    ca.s[6] = fc1_b; ca.d[6] = b1; ca.n8[6] = 3072 / 8;
    ca.s[7] = fc2_b; ca.d[7] = b2; ca.n8[7] = 768 / 8;
    ca.total8 = (1769472 + 589824 + 2359296 + 2359296 + 2304 + 768 + 3072 +
                 768) / 8;
    cvt_all<<<dim3(880), 256, 0, stream>>>(ca, flag);

    ln_kernel<<<dim3(NT / 4), 256, 0, stream>>>(x, ln1_w, ln1_b, hx, flag);
    gemm_qkv64<<<dim3(18, 64), 256, 0, stream>>>(hx, wq, bq, qkv, vT);
    if (sp) {
      flash_attn_sp<<<dim3(47, 24), 128, 0, stream>>>(qkv, vT, oat, po, pl);
      attn_combine<<<dim3(15, 24), 256, 0, stream>>>(po, pl, oat);
    } else {
      flash_attn_v7<<<dim3(NS / 64, NB * NH), 128, 0, stream>>>(qkv, vT, oat);
    }
    gemm64<2><<<dim3(6, 64), 256, 0, stream>>>(
        oat, wo, bo, x, d_out, ND, ND, 0, flag);
    ln_kernel<<<dim3(NT / 4), 256, 0, stream>>>(d_out, ln2_w, ln2_b, h2, flag);
    if (ws_size >= T1) {
      bf16* ff1 = slotB;
      gemm64<1><<<dim3(24, 64), 256, 0, stream>>>(
          h2, w1, b1, nullptr, ff1, NF, ND, 0, flag);
      gemm64<2><<<dim3(6, 64), 256, 0, stream>>>(
          ff1, w2, b2, d_out, d_out, ND, NF, 0, flag);
    } else {
      bf16* ff1c = slotB;
      for (int c = 0; c < 2; ++c) {
        gemm64<1><<<dim3(24, 32), 256, 0, stream>>>(
            h2 + (size_t)c * 2048 * ND, w1, b1, nullptr, ff1c, NF, ND, 0, flag);
        gemm64<2><<<dim3(6, 32), 256, 0, stream>>>(
            ff1c, w2, b2, d_out, d_out, ND, NF, c * 2048, flag);
      }
    }
  } else if (ws_size >= T4) {
    bf16* wq = (bf16*)(ws + 256);
    bf16* wo = wq + 1769472;
    bf16* w1 = wo + 589824;
    bf16* w2 = w1 + 2359296;
    bf16* bq = w2 + 2359296;
    bf16* bo = bq + 2304;
    bf16* b1 = bo + 768;
    bf16* b2 = b1 + 3072;
    bf16* slotA = b2 + 768;
    bf16* slotB = slotA + (size_t)NT * ND;
    bf16* hx = slotA, *oat = slotA, *h2 = slotA;
    bf16* qkv = slotB;

    CvtArgs ca;
    ca.s[0] = qkv_w; ca.d[0] = wq; ca.n8[0] = 1769472 / 8;
    ca.s[1] = out_w; ca.d[1] = wo; ca.n8[1] = 589824 / 8;
    ca.s[2] = fc1_w; ca.d[2] = w1; ca.n8[2] = 2359296 / 8;
    ca.s[3] = fc2_w; ca.d[3] = w2; ca.n8[3] = 2359296 / 8;
    ca.s[4] = qkv_b; ca.d[4] = bq; ca.n8[4] = 2304 / 8;
    ca.s[5] = out_b; ca.d[5] = bo; ca.n8[5] = 768 / 8;
    ca.s[6] = fc1_b; ca.d[6] = b1; ca.n8[6] = 3072 / 8;
    ca.s[7] = fc2_b; ca.d[7] = b2; ca.n8[7] = 768 / 8;
    ca.total8 = (1769472 + 589824 + 2359296 + 2359296 + 2304 + 768 + 3072 +
                 768) / 8;
    cvt_all<<<dim3(880), 256, 0, stream>>>(ca, flag);

    ln_kernel<<<dim3(NT / 4), 256, 0, stream>>>(x, ln1_w, ln1_b, hx, flag);
    gemm_fast<0, 128><<<dim3(18, 32), 256, 0, stream>>>(
        hx, wq, bq, nullptr, qkv, 3 * ND, ND, 0, flag);
    flash_attn_v1<<<dim3(NS / 64, NB * NH), 256, 0, stream>>>(qkv, oat);
    gemm64<2><<<dim3(6, 64), 256, 0, stream>>>(
        oat, wo, bo, x, d_out, ND, ND, 0, flag);
    ln_kernel<<<dim3(NT / 4), 256, 0, stream>>>(d_out, ln2_w, ln2_b, h2, flag);
    if (ws_size >= T3) {
      bf16* ff1 = slotB;
      gemm64<1><<<dim3(24, 64), 256, 0, stream>>>(
          h2, w1, b1, nullptr, ff1, NF, ND, 0, flag);
      gemm64<2><<<dim3(6, 64), 256, 0, stream>>>(
          ff1, w2, b2, d_out, d_out, ND, NF, 0, flag);
    } else {
      bf16* ff1c = slotB;
      for (int c = 0; c < 2; ++c) {
        gemm64<1><<<dim3(24, 32), 256, 0, stream>>>(
            h2 + (size_t)c * 2048 * ND, w1, b1, nullptr, ff1c, NF, ND, 0, flag);
        gemm64<2><<<dim3(6, 32), 256, 0, stream>>>(
            ff1c, w2, b2, d_out, d_out, ND, NF, c * 2048, flag);
      }
    }
  } else {
    const size_t szTD = (size_t)NT * ND * sizeof(bf16);
    bf16* slotA = (bf16*)(ws + 256);
    bf16* qkv = (bf16*)(ws + 256 + szTD);
    bf16* hx = slotA, *oat = slotA, *h2 = slotA;
    bf16* ff1c = qkv;

    ln_kernel<<<dim3(NT / 4), 256, 0, stream>>>(x, ln1_w, ln1_b, hx, flag);
    gemm_bt<0><<<dim3(18, 32), 256, 0, stream>>>(
        hx, qkv_w, qkv_b, nullptr, qkv, 3 * ND, ND, 0, flag);
    flash_attn_v1<<<dim3(NS / 64, NB * NH), 256, 0, stream>>>(qkv, oat);
    gemm_bt<2><<<dim3(6, 32), 256, 0, stream>>>(
        oat, out_w, out_b, x, d_out, ND, ND, 0, flag);
    ln_kernel<<<dim3(NT / 4), 256, 0, stream>>>(d_out, ln2_w, ln2_b, h2, flag);
    for (int c = 0; c < 4; ++c) {
      gemm_bt<1><<<dim3(24, 8), 256, 0, stream>>>(
          h2 + (size_t)c * 1024 * ND, fc1_w, fc1_b, nullptr, ff1c, NF, ND, 0,
          flag);
      gemm_bt<2><<<dim3(6, 8), 256, 0, stream>>>(
          ff1c, fc2_w, fc2_b, d_out, d_out, ND, NF, c * 1024, flag);
    }
  }
}

// Round 12
// 296.278 us; speedup vs baseline: 1.0697x; 1.0275x over previous
//
#include <hip/hip_runtime.h>
#include <hip/hip_bf16.h>
#include <cstdint>
#include <cstddef>

typedef __bf16 bf16;
typedef unsigned short ushort_t;
typedef __attribute__((ext_vector_type(8))) __bf16 bf16x8;
typedef __attribute__((ext_vector_type(4))) __bf16 bf16x4;
typedef __attribute__((ext_vector_type(4))) float f32x4;

#define NB 2
#define NS 2048
#define ND 768
#define NH 12
#define NF 3072
#define NT (NB * NS)   // 4096 tokens

__device__ __forceinline__ f32x4 mfma16(bf16x8 a, bf16x8 b, f32x4 c) {
  return __builtin_amdgcn_mfma_f32_16x16x32_bf16(a, b, c, 0, 0, 0);
}

__device__ __forceinline__ void gl_lds16(const bf16* g, bf16* l) {
  __builtin_amdgcn_global_load_lds(
      (__attribute__((address_space(1))) void*)(uintptr_t)g,
      (__attribute__((address_space(3))) void*)l,
      16, 0, 0);
}

// Bijective XCD-chunked swizzle (m204).
__device__ __forceinline__ int xcd_swz(int lin, int nwg) {
  const int q = nwg >> 3, r = nwg & 7;
  const int x = lin & 7, i = lin >> 3;
  return (x < r ? x * (q + 1) : r * (q + 1) + (x - r) * q) + i;
}

// gelu(x) ~= x * sigmoid(2*0.79788456*(x + 0.044715 x^3)); |err| < ~3e-3
__device__ __forceinline__ float gelu_fast(float v) {
  const float u = v * (0.7978845608028654f + 0.03567740814f * v * v);
  const float e = exp2f(u * 2.885390081777927f);  // e^(2u)
  return v - v / (1.f + e);                       // v*e/(1+e)
}

// r11: flash work units in DESCENDING length order (LPT schedule).
// entry = qt*4 + direct*2 + cc.
__constant__ unsigned char fs_tab[47] = {
    66,                       // len17: (16,D)
    124, 125, 121, 62,        // len16
    120, 116, 117, 113, 58,   // len15
    112, 108, 109, 105, 54,   // len14
    104, 100, 101, 97, 50,    // len13
    96, 92, 93, 89, 46,       // len12
    88, 84, 85, 81, 42,       // len11
    80, 76, 77, 73, 38,       // len10
    72, 68, 69, 34,           // len9
    30, 26, 22, 18, 14, 10, 6, 2  // len8..1 directs
};

// ---------------- dtype sniffer (flag=1 -> I/O is float32) ----------------
__global__ __launch_bounds__(256) void sniff_kernel(
    const ushort_t* __restrict__ x, int* __restrict__ flag) {
  __shared__ int s[4];
  int bad = 0;
  for (int i = threadIdx.x; i < 4096; i += 256) {
    const int e = (x[i] >> 7) & 0xFF;
    bad |= (e >= 0xC0);
  }
  bad = __any(bad) ? 1 : 0;
  if ((threadIdx.x & 63) == 0) s[threadIdx.x >> 6] = bad;
  __syncthreads();
  if (threadIdx.x == 0) *flag = s[0] | s[1] | s[2] | s[3];
}

// ---------------- merged weight/bias conversion (1 launch) ----------------
struct CvtArgs {
  const void* s[8];
  bf16* d[8];
  int n8[8];
  int total8;
};

__global__ __launch_bounds__(256) void cvt_all(CvtArgs a,
                                               const int* __restrict__ flag) {
  const int isf = *flag;
  const int stride = gridDim.x * 256;
  for (int i = blockIdx.x * 256 + threadIdx.x; i < a.total8; i += stride) {
    int seg = 0, off = i;
    while (off >= a.n8[seg]) { off -= a.n8[seg]; ++seg; }
    bf16x8 o;
    if (isf) {
      const float* s = (const float*)a.s[seg] + (size_t)off * 8;
      const f32x4 f0 = *(const f32x4*)s;
      const f32x4 f1 = *(const f32x4*)(s + 4);
#pragma unroll
      for (int j = 0; j < 4; ++j) {
        o[j] = (bf16)f0[j];
        o[4 + j] = (bf16)f1[j];
      }
    } else {
      o = *((const bf16x8*)a.s[seg] + off);
    }
    *((bf16x8*)a.d[seg] + off) = o;
  }
}

// ---------------- LayerNorm: one wave per row of 768; output bf16 ---------
__global__ __launch_bounds__(256) void ln_kernel(
    const void* __restrict__ xv, const void* __restrict__ wv,
    const void* __restrict__ bv, bf16* __restrict__ y,
    const int* __restrict__ flag) {
  const int isf = *flag;
  const int row = blockIdx.x * 4 + (threadIdx.x >> 6);
  const int L = threadIdx.x & 63;
  const float* xf = (const float*)xv;
  const bf16* xh = (const bf16*)xv;
  const float* wf = (const float*)wv;
  const bf16* wh = (const bf16*)wv;
  const float* bf_ = (const float*)bv;
  const bf16* bh = (const bf16*)bv;
  const size_t base = (size_t)row * ND;
  float v[12];
  float s = 0.f, s2 = 0.f;
#pragma unroll
  for (int i = 0; i < 12; ++i) {
    const int c = L + i * 64;
    v[i] = isf ? xf[base + c] : (float)xh[base + c];
    s += v[i];
    s2 += v[i] * v[i];
  }
#pragma unroll
  for (int off = 1; off < 64; off <<= 1) {
    s += __shfl_xor(s, off);
    s2 += __shfl_xor(s2, off);
  }
  const float mean = s * (1.f / 768.f);
  const float var = s2 * (1.f / 768.f) - mean * mean;
  const float rstd = rsqrtf(var + 1e-5f);
  bf16* yr = y + base;
#pragma unroll
  for (int i = 0; i < 12; ++i) {
    const int c = L + i * 64;
    const float ww = isf ? wf[c] : (float)wh[c];
    const float bb = isf ? bf_[c] : (float)bh[c];
    yr[c] = (bf16)((v[i] - mean) * rstd * ww + bb);
  }
}

// ---------------- V transpose kernel (fallback only) ----------------------
__global__ __launch_bounds__(256) void vt_kernel(
    const bf16* __restrict__ qkv, bf16* __restrict__ vT) {
  const int bh = blockIdx.y;
  const int b = bh / NH, h = bh % NH;
  const int st = blockIdx.x;
  __shared__ bf16 Vs[64 * 72];
  const int tid = threadIdx.x;
  {
    const int r = tid >> 2, c = (tid & 3) * 16;
    const bf16* src =
        qkv + (size_t)(b * NS + st * 64 + r) * (3 * ND) + 2 * ND + h * 64 + c;
    *(bf16x8*)&Vs[r * 72 + c] = *(const bf16x8*)src;
    *(bf16x8*)&Vs[r * 72 + c + 8] = *(const bf16x8*)(src + 8);
  }
  __syncthreads();
  {
    const int hd = tid >> 2, t0 = (tid & 3) * 16;
    bf16x8 o0, o1;
#pragma unroll
    for (int j = 0; j < 8; ++j) {
      o0[j] = Vs[(t0 + j) * 72 + hd];
      o1[j] = Vs[(t0 + 8 + j) * 72 + hd];
    }
    bf16* dst = vT + ((size_t)bh * 64 + hd) * NS + st * 64 + t0;
    *(bf16x8*)dst = o0;
    *(bf16x8*)(dst + 8) = o1;
  }
}

// ---------------- gemm64: 64xTN tile, BK=64 ---------------------------------
// r12: TN templated. TN=64 for the N=768 GEMMs (fc2, attn-out): LDS 48KB
// -> 3 blocks/CU and grid (12,64)=768 blocks=3/CU supplied (was 6x64=384
// = 1.5/CU, grid-starved: fc2 45us at 1500cy/block-iter). TN=128 for fc1.
template <int EPI, int TN>
__global__ __launch_bounds__(256) void gemm64(
    const bf16* __restrict__ A, const bf16* __restrict__ Bt,
    const bf16* __restrict__ bias, const void* resid, void* C,
    int N, int K, int row0, const int* __restrict__ flag) {
  constexpr int NBUF = 3;
  constexpr int NTF = TN / 32;  // 16-col frags per wave (= B loads/stage)
  __shared__ bf16 As[NBUF][64 * 64];
  __shared__ bf16 Bs[NBUF][TN * 64];
  int isf = 0;
  if (EPI == 2) {
    isf = *flag;
    asm volatile("" ::"s"(isf));
  }
  const int tid = threadIdx.x;
  const int w = tid >> 6, L = tid & 63;
  const int lg = L >> 4, lc = L & 15;
  const int wm = (w >> 1) * 32, wn = (w & 1) * (TN / 2);
  const int nwg = gridDim.x * gridDim.y;
  const int lin = xcd_swz(blockIdx.y * gridDim.x + blockIdx.x, nwg);
  const int bm = lin / gridDim.x, bn = lin % gridDim.x;

  const bf16* Ab = A + (size_t)bm * 64 * K;
  const bf16* Bb = Bt + (size_t)bn * TN * K;

  const int srw = tid >> 3;                      // dest row 0..31 per load
  const int scw = ((tid & 7) ^ (srw & 7)) * 8;   // pre-swizzled source col

  f32x4 acc[2][NTF];
#pragma unroll
  for (int i = 0; i < 2; ++i)
#pragma unroll
    for (int j = 0; j < NTF; ++j) acc[i][j] = (f32x4){0.f, 0.f, 0.f, 0.f};

#define G64_STAGE(buf, kk)                                                  \
  do {                                                                      \
    gl_lds16(Ab + (size_t)srw * K + (kk) + scw, As[buf] + tid * 8);         \
    gl_lds16(Ab + (size_t)(srw + 32) * K + (kk) + scw,                      \
             As[buf] + 2048 + tid * 8);                                     \
    _Pragma("unroll") for (int bi = 0; bi < NTF; ++bi)                      \
        gl_lds16(Bb + (size_t)(srw + 32 * bi) * K + (kk) + scw,             \
                 Bs[buf] + bi * 2048 + tid * 8);                            \
  } while (0)

#define G64_COMP(cb)                                                        \
  do {                                                                      \
    bf16x8 af[2][2], bfr[2][NTF];                                           \
    _Pragma("unroll") for (int kk2 = 0; kk2 < 2; ++kk2) {                   \
      _Pragma("unroll") for (int mt = 0; mt < 2; ++mt) {                    \
        const int ra = wm + mt * 16 + lc;                                   \
        af[kk2][mt] = *(const bf16x8*)&As[cb][ra * 64 +                     \
                                             (((kk2 * 4 + lg) ^ (ra & 7))   \
                                              << 3)];                       \
      }                                                                     \
      _Pragma("unroll") for (int nt = 0; nt < NTF; ++nt) {                  \
        const int rb = wn + nt * 16 + lc;                                   \
        bfr[kk2][nt] = *(const bf16x8*)&Bs[cb][rb * 64 +                    \
                                              (((kk2 * 4 + lg) ^ (rb & 7))  \
                                               << 3)];                      \
      }                                                                     \
    }                                                                       \
    _Pragma("unroll") for (int kk2 = 0; kk2 < 2; ++kk2)                     \
        _Pragma("unroll") for (int mt = 0; mt < 2; ++mt)                    \
            _Pragma("unroll") for (int nt = 0; nt < NTF; ++nt)              \
                acc[mt][nt] = mfma16(af[kk2][mt], bfr[kk2][nt],             \
                                     acc[mt][nt]);                          \
  } while (0)

  const int nk = K >> 6;
  G64_STAGE(0, 0);
  int cur = 0, stg = 1;
  int k = 0;
  for (; k < nk - 1; ++k) {
    G64_STAGE(stg, (k + 1) * 64);
    if (TN == 128)
      asm volatile("s_waitcnt vmcnt(6)" ::: "memory");
    else
      asm volatile("s_waitcnt vmcnt(4)" ::: "memory");
    asm volatile("s_barrier" ::: "memory");
    G64_COMP(cur);
    cur = (cur + 1 == NBUF) ? 0 : cur + 1;
    stg = (stg + 1 == NBUF) ? 0 : stg + 1;
  }
  __syncthreads();  // drain last stage (vmcnt(0) + barrier)
  G64_COMP(cur);
#undef G64_STAGE
#undef G64_COMP

  const float* rf = (const float*)resid;
  const bf16* rh = (const bf16*)resid;
  float* Cf = (float*)C;
  bf16* Ch = (bf16*)C;
#pragma unroll
  for (int mt = 0; mt < 2; ++mt) {
#pragma unroll
    for (int nt = 0; nt < NTF; ++nt) {
      const int col = bn * TN + wn + nt * 16 + lc;
      const float bv = (float)bias[col];
#pragma unroll
      for (int r = 0; r < 4; ++r) {
        const int row = bm * 64 + wm + mt * 16 + lg * 4 + r;
        float v = acc[mt][nt][r] + bv;
        if (EPI == 1) v = gelu_fast(v);
        const size_t idx = (size_t)(row0 + row) * N + col;
        if (EPI == 2) {
          v += isf ? rf[idx] : (float)rh[idx];
          if (isf) Cf[idx] = v; else Ch[idx] = (bf16)v;
        } else {
          Ch[idx] = (bf16)v;
        }
      }
    }
  }
}

// ---------------- gemm_qkv64: gemm64 structure + fused QKV epilogue -------
__global__ __launch_bounds__(256) void gemm_qkv64(
    const bf16* __restrict__ A, const bf16* __restrict__ Bt,
    const bf16* __restrict__ bias, bf16* __restrict__ qkvout,
    bf16* __restrict__ vT) {
  const int K = ND, N = 3 * ND;
  constexpr int NBUF = 3;
  __shared__ bf16 As[NBUF][64 * 64];
  __shared__ bf16 Bs[NBUF][128 * 64];
  const int tid = threadIdx.x;
  const int w = tid >> 6, L = tid & 63;
  const int lg = L >> 4, lc = L & 15;
  const int wm = (w >> 1) * 32, wn = (w & 1) * 64;
  const int nwg = gridDim.x * gridDim.y;
  const int lin = xcd_swz(blockIdx.y * gridDim.x + blockIdx.x, nwg);
  const int bm = lin / gridDim.x, bn = lin % gridDim.x;

  const bf16* Ab = A + (size_t)bm * 64 * K;
  const bf16* Bb = Bt + (size_t)bn * 128 * K;

  const int srw = tid >> 3;
  const int scw = ((tid & 7) ^ (srw & 7)) * 8;

  f32x4 acc[2][4];
#pragma unroll
  for (int i = 0; i < 2; ++i)
#pragma unroll
    for (int j = 0; j < 4; ++j) acc[i][j] = (f32x4){0.f, 0.f, 0.f, 0.f};

#define Q64_STAGE(buf, kk)                                                  \
  do {                                                                      \
    gl_lds16(Ab + (size_t)srw * K + (kk) + scw, As[buf] + tid * 8);         \
    gl_lds16(Ab + (size_t)(srw + 32) * K + (kk) + scw,                      \
             As[buf] + 2048 + tid * 8);                                     \
    gl_lds16(Bb + (size_t)srw * K + (kk) + scw, Bs[buf] + tid * 8);         \
    gl_lds16(Bb + (size_t)(srw + 32) * K + (kk) + scw,                      \
             Bs[buf] + 2048 + tid * 8);                                     \
    gl_lds16(Bb + (size_t)(srw + 64) * K + (kk) + scw,                      \
             Bs[buf] + 4096 + tid * 8);                                     \
    gl_lds16(Bb + (size_t)(srw + 96) * K + (kk) + scw,                      \
             Bs[buf] + 6144 + tid * 8);                                     \
  } while (0)

#define Q64_COMP(cb)                                                        \
  do {                                                                      \
    bf16x8 af[2][2], bfr[2][4];                                             \
    _Pragma("unroll") for (int kk2 = 0; kk2 < 2; ++kk2) {                   \
      _Pragma("unroll") for (int mt = 0; mt < 2; ++mt) {                    \
        const int ra = wm + mt * 16 + lc;                                   \
        af[kk2][mt] = *(const bf16x8*)&As[cb][ra * 64 +                     \
                                             (((kk2 * 4 + lg) ^ (ra & 7))   \
                                              << 3)];                       \
      }                                                                     \
      _Pragma("unroll") for (int nt = 0; nt < 4; ++nt) {                    \
        const int rb = wn + nt * 16 + lc;                                   \
        bfr[kk2][nt] = *(const bf16x8*)&Bs[cb][rb * 64 +                    \
                                              (((kk2 * 4 + lg) ^ (rb & 7))  \
                                               << 3)];                      \
      }                                                                     \
    }                                                                       \
    _Pragma("unroll") for (int kk2 = 0; kk2 < 2; ++kk2)                     \
        _Pragma("unroll") for (int mt = 0; mt < 2; ++mt)                    \
            _Pragma("unroll") for (int nt = 0; nt < 4; ++nt)                \
                acc[mt][nt] = mfma16(af[kk2][mt], bfr[kk2][nt],             \
                                     acc[mt][nt]);                          \
  } while (0)

  const int nk = K >> 6;  // 12
  Q64_STAGE(0, 0);
  int cur = 0, stg = 1;
  int k = 0;
  for (; k < nk - 1; ++k) {
    Q64_STAGE(stg, (k + 1) * 64);
    asm volatile("s_waitcnt vmcnt(6)" ::: "memory");
    asm volatile("s_barrier" ::: "memory");
    Q64_COMP(cur);
    cur = (cur + 1 == NBUF) ? 0 : cur + 1;
    stg = (stg + 1 == NBUF) ? 0 : stg + 1;
  }
  __syncthreads();
  Q64_COMP(cur);
#undef Q64_STAGE
#undef Q64_COMP

#pragma unroll
  for (int mt = 0; mt < 2; ++mt) {
#pragma unroll
    for (int nt = 0; nt < 4; ++nt) {
      const int col = bn * 128 + wn + nt * 16 + lc;
      const float bv = (float)bias[col];
      if (col < 2 * ND) {  // Q or K -> qkv buffer
#pragma unroll
        for (int r = 0; r < 4; ++r) {
          const int row = bm * 64 + wm + mt * 16 + lg * 4 + r;
          qkvout[(size_t)row * N + col] = (bf16)(acc[mt][nt][r] + bv);
        }
      } else {  // V -> vT[bh][hd][token], 4 consecutive tokens per lane
        const int colv = col - 2 * ND;
        const int h_ = colv >> 6, hd = colv & 63;
        bf16x4 pk;
#pragma unroll
        for (int r = 0; r < 4; ++r) pk[r] = (bf16)(acc[mt][nt][r] + bv);
        const int tok0 = bm * 64 + wm + mt * 16 + lg * 4;
        const int b_ = tok0 >> 11, s0 = tok0 & (NS - 1);
        *(bf16x4*)&vT[((size_t)(b_ * NH + h_) * 64 + hd) * NS + s0] = pk;
      }
    }
  }
}

// ---------------- fast GEMM (TM=128): counted-vmcnt + T2 swizzle ----------
template <int EPI, int TM>
__global__ __launch_bounds__(256) void gemm_fast(
    const bf16* __restrict__ A, const bf16* __restrict__ Bt,
    const bf16* __restrict__ bias, const void* resid, void* C,
    int N, int K, int row0, const int* __restrict__ flag) {
  constexpr int NBUF = (TM == 64) ? 5 : 3;
  constexpr int LOOK = NBUF - 2;
  constexpr int MT = TM / 32;
  __shared__ bf16 As[NBUF][TM * 32];
  __shared__ bf16 Bs[NBUF][128 * 32];
  int isf = 0;
  if (EPI == 2) {
    isf = *flag;
    asm volatile("" ::"s"(isf));
  }
  const int tid = threadIdx.x;
  const int w = tid >> 6, L = tid & 63;
  const int lg = L >> 4, lc = L & 15;
  const int lgx = (lg ^ ((lc >> 1) & 3)) * 8;
  const int wm = (w >> 1) * (TM / 2), wn = (w & 1) * 64;
  const int nwg = gridDim.x * gridDim.y;
  const int lin = xcd_swz(blockIdx.y * gridDim.x + blockIdx.x, nwg);
  const int bm = lin / gridDim.x, bn = lin % gridDim.x;

  const bf16* Ab = A + (size_t)bm * TM * K;
  const bf16* Bb = Bt + (size_t)bn * 128 * K;

  const int sr = tid >> 2;
  const int sc = ((tid & 3) ^ ((tid >> 3) & 3)) * 8;

  f32x4 acc[MT][4];
#pragma unroll
  for (int i = 0; i < MT; ++i)
#pragma unroll
    for (int j = 0; j < 4; ++j) acc[i][j] = (f32x4){0.f, 0.f, 0.f, 0.f};

#define GF_STAGE(buf, kk)                                                   \
  do {                                                                      \
    gl_lds16(Ab + (size_t)sr * K + (kk) + sc, As[buf] + tid * 8);           \
    if (TM == 128)                                                          \
      gl_lds16(Ab + (size_t)(sr + 64) * K + (kk) + sc,                      \
               As[buf] + 2048 + tid * 8);                                   \
    gl_lds16(Bb + (size_t)sr * K + (kk) + sc, Bs[buf] + tid * 8);           \
    gl_lds16(Bb + (size_t)(sr + 64) * K + (kk) + sc,                        \
             Bs[buf] + 2048 + tid * 8);                                     \
  } while (0)

#define GF_COMP(cb)                                                         \
  do {                                                                      \
    bf16x8 af[MT], bfr[4];                                                  \
    _Pragma("unroll") for (int mt = 0; mt < MT; ++mt) af[mt] =              \
        *(const bf16x8*)&As[cb][(wm + mt * 16 + lc) * 32 + lgx];            \
    _Pragma("unroll") for (int nt = 0; nt < 4; ++nt) bfr[nt] =              \
        *(const bf16x8*)&Bs[cb][(wn + nt * 16 + lc) * 32 + lgx];            \
    _Pragma("unroll") for (int mt = 0; mt < MT; ++mt)                       \
        _Pragma("unroll") for (int nt = 0; nt < 4; ++nt) acc[mt][nt] =      \
            mfma16(af[mt], bfr[nt], acc[mt][nt]);                           \
  } while (0)

  const int nk = K >> 5;
#pragma unroll
  for (int s = 0; s < LOOK; ++s)
    if (s < nk) GF_STAGE(s, s * 32);
  int cur = 0, stg = LOOK;
  int k = 0;
  const int kmain = (nk > LOOK) ? nk - LOOK : 0;
  for (; k < kmain; ++k) {
    GF_STAGE(stg, (k + LOOK) * 32);
    if (TM == 64)
      asm volatile("s_waitcnt vmcnt(9)" ::: "memory");
    else
      asm volatile("s_waitcnt vmcnt(4)" ::: "memory");
    asm volatile("s_barrier" ::: "memory");
    GF_COMP(cur);
    cur = (cur + 1 == NBUF) ? 0 : cur + 1;
    stg = (stg + 1 == NBUF) ? 0 : stg + 1;
  }
  __syncthreads();
  for (; k < nk; ++k) {
    GF_COMP(cur);
    cur = (cur + 1 == NBUF) ? 0 : cur + 1;
  }
#undef GF_STAGE
#undef GF_COMP

  const float* rf = (const float*)resid;
  const bf16* rh = (const bf16*)resid;
  float* Cf = (float*)C;
  bf16* Ch = (bf16*)C;
#pragma unroll
  for (int mt = 0; mt < MT; ++mt) {
#pragma unroll
    for (int nt = 0; nt < 4; ++nt) {
      const int col = bn * 128 + wn + nt * 16 + lc;
      const float bv = (float)bias[col];
#pragma unroll
      for (int r = 0; r < 4; ++r) {
        const int row = bm * TM + wm + mt * 16 + lg * 4 + r;
        float v = acc[mt][nt][r] + bv;
        if (EPI == 1) v = gelu_fast(v);
        const size_t idx = (size_t)(row0 + row) * N + col;
        if (EPI == 2) {
          v += isf ? rf[idx] : (float)rh[idx];
          if (isf) Cf[idx] = v; else Ch[idx] = (bf16)v;
        } else {
          Ch[idx] = (bf16)v;
        }
      }
    }
  }
}

// ---------------- fallback GEMM (dtype-branch staging, round-3) -----------
template <int EPI>
__global__ __launch_bounds__(256) void gemm_bt(
    const bf16* __restrict__ A, const void* __restrict__ Bt,
    const void* __restrict__ bias, const void* resid, void* C,
    int N, int K, int row0, const int* __restrict__ flag) {
  __shared__ bf16 As[128 * 32];
  __shared__ bf16 Bs[128 * 32];
  const int isf = *flag;
  const int tid = threadIdx.x;
  const int w = tid >> 6, L = tid & 63;
  const int lg = L >> 4, lc = L & 15;
  const int wm = (w >> 1) * 64, wn = (w & 1) * 64;
  const int nwg = gridDim.x * gridDim.y;
  const int lin = xcd_swz(blockIdx.y * gridDim.x + blockIdx.x, nwg);
  const int bm = lin / gridDim.x, bn = lin % gridDim.x;

  const bf16* Ab = A + (size_t)bm * 128 * K;
  const bf16* Bth = (const bf16*)Bt + (size_t)bn * 128 * K;
  const float* Btf = (const float*)Bt + (size_t)bn * 128 * K;

  const int sr = tid >> 1;
  const int sc = (tid & 1) * 16;

  f32x4 acc[4][4];
#pragma unroll
  for (int i = 0; i < 4; ++i)
#pragma unroll
    for (int j = 0; j < 4; ++j) acc[i][j] = (f32x4){0.f, 0.f, 0.f, 0.f};

  for (int k0 = 0; k0 < K; k0 += 32) {
    const bf16* ap = Ab + (size_t)sr * K + k0 + sc;
    const bf16x8 a0 = *(const bf16x8*)ap;
    const bf16x8 a1 = *(const bf16x8*)(ap + 8);
    bf16x8 b0, b1;
    if (isf) {
      const float* bp = Btf + (size_t)sr * K + k0 + sc;
      const f32x4 f0 = *(const f32x4*)bp;
      const f32x4 f1 = *(const f32x4*)(bp + 4);
      const f32x4 f2 = *(const f32x4*)(bp + 8);
      const f32x4 f3 = *(const f32x4*)(bp + 12);
#pragma unroll
      for (int j = 0; j < 4; ++j) {
        b0[j] = (bf16)f0[j];
        b0[4 + j] = (bf16)f1[j];
        b1[j] = (bf16)f2[j];
        b1[4 + j] = (bf16)f3[j];
      }
    } else {
      const bf16* bp = Bth + (size_t)sr * K + k0 + sc;
      b0 = *(const bf16x8*)bp;
      b1 = *(const bf16x8*)(bp + 8);
    }
    __syncthreads();
    *(bf16x8*)&As[sr * 32 + sc] = a0;
    *(bf16x8*)&As[sr * 32 + sc + 8] = a1;
    *(bf16x8*)&Bs[sr * 32 + sc] = b0;
    *(bf16x8*)&Bs[sr * 32 + sc + 8] = b1;
    __syncthreads();

    bf16x8 af[4], bfr[4];
#pragma unroll
    for (int mt = 0; mt < 4; ++mt)
      af[mt] = *(const bf16x8*)&As[(wm + mt * 16 + lc) * 32 + lg * 8];
#pragma unroll
    for (int nt = 0; nt < 4; ++nt)
      bfr[nt] = *(const bf16x8*)&Bs[(wn + nt * 16 + lc) * 32 + lg * 8];
#pragma unroll
    for (int mt = 0; mt < 4; ++mt)
#pragma unroll
      for (int nt = 0; nt < 4; ++nt)
        acc[mt][nt] = mfma16(af[mt], bfr[nt], acc[mt][nt]);
  }

  const float* biasf = (const float*)bias;
  const bf16* biash = (const bf16*)bias;
  const float* rf = (const float*)resid;
  const bf16* rh = (const bf16*)resid;
  float* Cf = (float*)C;
  bf16* Ch = (bf16*)C;
#pragma unroll
  for (int mt = 0; mt < 4; ++mt) {
#pragma unroll
    for (int nt = 0; nt < 4; ++nt) {
      const int col = bn * 128 + wn + nt * 16 + lc;
      const float bv = isf ? biasf[col] : (float)biash[col];
#pragma unroll
      for (int r = 0; r < 4; ++r) {
        const int row = bm * 128 + wm + mt * 16 + lg * 4 + r;
        float v = acc[mt][nt][r] + bv;
        if (EPI == 1) v = gelu_fast(v);
        const size_t idx = (size_t)(row0 + row) * N + col;
        if (EPI == 2) {
          v += isf ? rf[idx] : (float)rh[idx];
          if (isf) Cf[idx] = v; else Ch[idx] = (bf16)v;
        } else {
          Ch[idx] = (bf16)v;
        }
      }
    }
  }
}

// ---------------- Flash attention v12: split-KV + LPT dispatch order ------
__global__ __launch_bounds__(128) void flash_attn_sp(
    const bf16* __restrict__ qkv, const bf16* __restrict__ vT,
    bf16* __restrict__ o, float* __restrict__ po, float* __restrict__ pl) {
  const int nwg = gridDim.x * gridDim.y;  // 1128 = 8 XCD * 141
  const int lin = xcd_swz(blockIdx.y * gridDim.x + blockIdx.x, nwg);
  const int i141 = lin % 141;
  const int t = i141 / 3, bl = i141 % 3;       // LPT index, bh interleave
  const int bh = (lin / 141) * 3 + bl;
  const int b = bh / NH, h = bh % NH;
  const unsigned v_ = fs_tab[t];
  const int qt = v_ >> 2;
  const int direct = (v_ >> 1) & 1;
  const int cc = v_ & 1;
  int kt_lo, kt_hi;
  if (direct) {
    kt_lo = 0; kt_hi = qt;
  } else {
    const int hh = (qt + 1) >> 1;
    if (cc) { kt_lo = hh; kt_hi = qt; }
    else    { kt_lo = 0;  kt_hi = hh - 1; }
  }
  const int q0 = qt * 64;
  const int tid = threadIdx.x;  // 128 threads = 2 waves
  const int w = tid >> 6, L = tid & 63;
  const int lg = L >> 4, lc = L & 15;

  __shared__ bf16 Ks[64 * 72];   // [kv][hd]
  __shared__ bf16 Vts[64 * 72];  // [hd][kv]
  __shared__ bf16 Ps[2][32 * 72];

  const float QSCALE = 0.18033688011112042f;  // (1/8) * log2(e)
  bf16x8 qf[2][2];
#pragma unroll
  for (int m = 0; m < 2; ++m) {
    const size_t tokq = (size_t)(b * NS + q0 + w * 32 + m * 16 + lc);
    const bf16* qp = qkv + tokq * (3 * ND) + h * 64 + lg * 8;
    const bf16x8 q0r = *(const bf16x8*)qp;
    const bf16x8 q1r = *(const bf16x8*)(qp + 32);
#pragma unroll
    for (int jj = 0; jj < 8; ++jj) {
      qf[m][0][jj] = (bf16)((float)q0r[jj] * QSCALE);
      qf[m][1][jj] = (bf16)((float)q1r[jj] * QSCALE);
    }
  }

  const int kr = tid >> 1, kc = (tid & 1) * 32;
  const bf16* kbase =
      qkv + (size_t)(b * NS + kr) * (3 * ND) + ND + h * 64 + kc;
  const bf16* vbase = vT + ((size_t)bh * 64 + kr) * NS + kc;

  f32x4 oacc[2][4];
#pragma unroll
  for (int m = 0; m < 2; ++m)
#pragma unroll
    for (int nt = 0; nt < 4; ++nt) oacc[m][nt] = (f32x4){0.f, 0.f, 0.f, 0.f};
  float lacc[2] = {0.f, 0.f};

  bf16x8 kreg[4], vreg[4];
  {
    const bf16* kn = kbase + (size_t)kt_lo * 64 * (3 * ND);
    const bf16* vn = vbase + (size_t)kt_lo * 64;
#pragma unroll
    for (int p = 0; p < 4; ++p) {
      kreg[p] = *(const bf16x8*)(kn + p * 8);
      vreg[p] = *(const bf16x8*)(vn + p * 8);
    }
  }

  for (int kt = kt_lo; kt <= kt_hi; ++kt) {
    __syncthreads();
#pragma unroll
    for (int p = 0; p < 4; ++p) {
      *(bf16x8*)&Ks[kr * 72 + kc + p * 8] = kreg[p];
      *(bf16x8*)&Vts[kr * 72 + kc + p * 8] = vreg[p];
    }
    __syncthreads();

    if (kt < kt_hi) {
      const bf16* kn = kbase + (size_t)(kt + 1) * 64 * (3 * ND);
      const bf16* vn = vbase + (size_t)(kt + 1) * 64;
#pragma unroll
      for (int p = 0; p < 4; ++p) {
        kreg[p] = *(const bf16x8*)(kn + p * 8);
        vreg[p] = *(const bf16x8*)(vn + p * 8);
      }
    }

    f32x4 s[2][4];
    __builtin_amdgcn_s_setprio(1);
#pragma unroll
    for (int nt = 0; nt < 4; ++nt) {
      const bf16x8 kb0 = *(const bf16x8*)&Ks[(nt * 16 + lc) * 72 + lg * 8];
      const bf16x8 kb1 =
          *(const bf16x8*)&Ks[(nt * 16 + lc) * 72 + 32 + lg * 8];
#pragma unroll
      for (int m = 0; m < 2; ++m) {
        f32x4 z = (f32x4){0.f, 0.f, 0.f, 0.f};
        s[m][nt] = mfma16(kb0, qf[m][0], z);
        s[m][nt] = mfma16(kb1, qf[m][1], s[m][nt]);
      }
    }
    __builtin_amdgcn_s_setprio(0);
    if (kt == qt) {
#pragma unroll
      for (int m = 0; m < 2; ++m)
#pragma unroll
        for (int nt = 0; nt < 4; ++nt)
#pragma unroll
          for (int r = 0; r < 4; ++r) {
            const int kv = nt * 16 + lg * 4 + r;
            const int qrow = w * 32 + m * 16 + lc;
            if (kv > qrow) s[m][nt][r] = -1.0e30f;
          }
    }
#pragma unroll
    for (int m = 0; m < 2; ++m)
#pragma unroll
      for (int nt = 0; nt < 4; ++nt) {
        bf16x4 pk;
#pragma unroll
        for (int r = 0; r < 4; ++r) {
          const float p = exp2f(fminf(s[m][nt][r], 20.f));
          lacc[m] += p;
          pk[r] = (bf16)p;
        }
        *(bf16x4*)&Ps[w][(m * 16 + lc) * 72 + nt * 16 + lg * 4] = pk;
      }
    bf16x8 pa[2][2];
#pragma unroll
    for (int m = 0; m < 2; ++m) {
      pa[m][0] = *(const bf16x8*)&Ps[w][(m * 16 + lc) * 72 + lg * 8];
      pa[m][1] = *(const bf16x8*)&Ps[w][(m * 16 + lc) * 72 + 32 + lg * 8];
    }
    __builtin_amdgcn_s_setprio(1);
#pragma unroll
    for (int nt = 0; nt < 4; ++nt) {
      const bf16x8 v0 = *(const bf16x8*)&Vts[(nt * 16 + lc) * 72 + lg * 8];
      const bf16x8 v1 =
          *(const bf16x8*)&Vts[(nt * 16 + lc) * 72 + 32 + lg * 8];
#pragma unroll
      for (int m = 0; m < 2; ++m) {
        oacc[m][nt] = mfma16(pa[m][0], v0, oacc[m][nt]);
        oacc[m][nt] = mfma16(pa[m][1], v1, oacc[m][nt]);
      }
    }
    __builtin_amdgcn_s_setprio(0);
  }

#pragma unroll
  for (int m = 0; m < 2; ++m) {
    lacc[m] += __shfl_xor(lacc[m], 16);
    lacc[m] += __shfl_xor(lacc[m], 32);
  }

  if (direct) {
    float lr[2][4];
#pragma unroll
    for (int m = 0; m < 2; ++m)
#pragma unroll
      for (int r = 0; r < 4; ++r) lr[m][r] = __shfl(lacc[m], lg * 4 + r);
#pragma unroll
    for (int m = 0; m < 2; ++m)
#pragma unroll
      for (int nt = 0; nt < 4; ++nt)
#pragma unroll
        for (int r = 0; r < 4; ++r) {
          const int qrow = q0 + w * 32 + m * 16 + lg * 4 + r;
          const float val = oacc[m][nt][r] / lr[m][r];
          o[(size_t)(b * NS + qrow) * ND + h * 64 + nt * 16 + lc] =
              (bf16)val;
        }
  } else {
    const int slot = qt - 17;  // 0..14
    float* pob = po + (((size_t)(bh * 15 + slot)) * 2 + cc) * 4096;
#pragma unroll
    for (int m = 0; m < 2; ++m)
#pragma unroll
      for (int nt = 0; nt < 4; ++nt)
#pragma unroll
        for (int r = 0; r < 4; ++r) {
          const int row = w * 32 + m * 16 + lg * 4 + r;
          const int col = nt * 16 + lc;
          pob[row * 64 + col] = oacc[m][nt][r];
        }
    if (L < 16) {
      float* plb = pl + ((bh * 15 + slot) * 2 + cc) * 64;
      plb[w * 32 + L] = lacc[0];
      plb[w * 32 + 16 + L] = lacc[1];
    }
  }
}

// ---------------- attention partial combine (qt>=17 tiles) ----------------
__global__ __launch_bounds__(256) void attn_combine(
    const float* __restrict__ po, const float* __restrict__ pl,
    bf16* __restrict__ o) {
  const int slot = blockIdx.x;  // 0..14 -> qt = slot+17
  const int bh = blockIdx.y;    // 0..23
  const int qt = slot + 17;
  const int b = bh / NH, h = bh % NH;
  const float* poA = po + ((size_t)(bh * 15 + slot)) * 2 * 4096;
  const float* poB = poA + 4096;
  const float* plA = pl + (bh * 15 + slot) * 2 * 64;
  const float* plB = plA + 64;
  for (int e = threadIdx.x; e < 4096; e += 256) {
    const int q = e >> 6, hd = e & 63;
    const float val = (poA[e] + poB[e]) / (plA[q] + plB[q]);
    o[(size_t)(b * NS + qt * 64 + q) * ND + h * 64 + hd] = (bf16)val;
  }
}

// ---------------- Flash attention v9 (T2 tier: no partial workspace) ------
__global__ __launch_bounds__(128) void flash_attn_v7(
    const bf16* __restrict__ qkv, const bf16* __restrict__ vT,
    bf16* __restrict__ o) {
  const int nwg = gridDim.x * gridDim.y;  // 768 = 8 XCD * 96
  const int lin = xcd_swz(blockIdx.y * gridDim.x + blockIdx.x, nwg);
  const int xcd = lin / 96;
  const int i96 = lin % 96;
  const int bl = i96 >> 5;
  const int j = i96 & 31;
  const int bh = xcd * 3 + bl;
  const int b = bh / NH, h = bh % NH;
  int qt;
  if (bl == 0) qt = j;
  else if (bl == 1) qt = (j + 16) & 31;
  else qt = (j < 16) ? (31 - 2 * j) : (62 - 2 * j);
  const int q0 = qt * 64;
  const int tid = threadIdx.x;
  const int w = tid >> 6, L = tid & 63;
  const int lg = L >> 4, lc = L & 15;

  __shared__ bf16 Ks[2][64 * 72];
  __shared__ bf16 Vts[2][64 * 72];
  __shared__ bf16 Ps[2][32 * 72];

  const float QSCALE = 0.18033688011112042f;
  bf16x8 qf[2][2];
#pragma unroll
  for (int m = 0; m < 2; ++m) {
    const size_t tokq = (size_t)(b * NS + q0 + w * 32 + m * 16 + lc);
    const bf16* qp = qkv + tokq * (3 * ND) + h * 64 + lg * 8;
    const bf16x8 q0r = *(const bf16x8*)qp;
    const bf16x8 q1r = *(const bf16x8*)(qp + 32);
#pragma unroll
    for (int jj = 0; jj < 8; ++jj) {
      qf[m][0][jj] = (bf16)((float)q0r[jj] * QSCALE);
      qf[m][1][jj] = (bf16)((float)q1r[jj] * QSCALE);
    }
  }

  const int kr = tid >> 1, kc = (tid & 1) * 32;
  const bf16* kbase =
      qkv + (size_t)(b * NS + kr) * (3 * ND) + ND + h * 64 + kc;
  const bf16* vbase = vT + ((size_t)bh * 64 + kr) * NS + kc;

  f32x4 oacc[2][4];
#pragma unroll
  for (int m = 0; m < 2; ++m)
#pragma unroll
    for (int nt = 0; nt < 4; ++nt) oacc[m][nt] = (f32x4){0.f, 0.f, 0.f, 0.f};
  float lacc[2] = {0.f, 0.f};

  const int nkt = qt + 1;

  bf16x8 kreg[4], vreg[4];
#pragma unroll
  for (int p = 0; p < 4; ++p) {
    kreg[p] = *(const bf16x8*)(kbase + p * 8);
    vreg[p] = *(const bf16x8*)(vbase + p * 8);
  }
#pragma unroll
  for (int p = 0; p < 4; ++p) {
    *(bf16x8*)&Ks[0][kr * 72 + kc + p * 8] = kreg[p];
    *(bf16x8*)&Vts[0][kr * 72 + kc + p * 8] = vreg[p];
  }

  for (int kt = 0; kt < nkt; ++kt) {
    __syncthreads();
    const int cur = kt & 1;

    if (kt + 1 < nkt) {
      const bf16* kn = kbase + (size_t)(kt + 1) * 64 * (3 * ND);
      const bf16* vn = vbase + (size_t)(kt + 1) * 64;
#pragma unroll
      for (int p = 0; p < 4; ++p) {
        kreg[p] = *(const bf16x8*)(kn + p * 8);
        vreg[p] = *(const bf16x8*)(vn + p * 8);
      }
    }

    f32x4 s[2][4];
    __builtin_amdgcn_s_setprio(1);
#pragma unroll
    for (int nt = 0; nt < 4; ++nt) {
      const bf16x8 kb0 =
          *(const bf16x8*)&Ks[cur][(nt * 16 + lc) * 72 + lg * 8];
      const bf16x8 kb1 =
          *(const bf16x8*)&Ks[cur][(nt * 16 + lc) * 72 + 32 + lg * 8];
#pragma unroll
      for (int m = 0; m < 2; ++m) {
        f32x4 z = (f32x4){0.f, 0.f, 0.f, 0.f};
        s[m][nt] = mfma16(kb0, qf[m][0], z);
        s[m][nt] = mfma16(kb1, qf[m][1], s[m][nt]);
      }
    }
    __builtin_amdgcn_s_setprio(0);
    if (kt == nkt - 1) {
#pragma unroll
      for (int m = 0; m < 2; ++m)
#pragma unroll
        for (int nt = 0; nt < 4; ++nt)
#pragma unroll
          for (int r = 0; r < 4; ++r) {
            const int kv = nt * 16 + lg * 4 + r;
            const int qrow = w * 32 + m * 16 + lc;
            if (kv > qrow) s[m][nt][r] = -1.0e30f;
          }
    }
#pragma unroll
    for (int m = 0; m < 2; ++m)
#pragma unroll
      for (int nt = 0; nt < 4; ++nt) {
        bf16x4 pk;
#pragma unroll
        for (int r = 0; r < 4; ++r) {
          const float p = exp2f(fminf(s[m][nt][r], 20.f));
          lacc[m] += p;
          pk[r] = (bf16)p;
        }
        *(bf16x4*)&Ps[w][(m * 16 + lc) * 72 + nt * 16 + lg * 4] = pk;
      }
    bf16x8 pa[2][2];
#pragma unroll
    for (int m = 0; m < 2; ++m) {
      pa[m][0] = *(const bf16x8*)&Ps[w][(m * 16 + lc) * 72 + lg * 8];
      pa[m][1] = *(const bf16x8*)&Ps[w][(m * 16 + lc) * 72 + 32 + lg * 8];
    }

    if (kt + 1 < nkt) {
      const int nxt = cur ^ 1;
#pragma unroll
      for (int p = 0; p < 4; ++p) {
        *(bf16x8*)&Ks[nxt][kr * 72 + kc + p * 8] = kreg[p];
        *(bf16x8*)&Vts[nxt][kr * 72 + kc + p * 8] = vreg[p];
      }
    }

    __builtin_amdgcn_s_setprio(1);
#pragma unroll
    for (int nt = 0; nt < 4; ++nt) {
      const bf16x8 v0 =
          *(const bf16x8*)&Vts[cur][(nt * 16 + lc) * 72 + lg * 8];
      const bf16x8 v1 =
          *(const bf16x8*)&Vts[cur][(nt * 16 + lc) * 72 + 32 + lg * 8];
#pragma unroll
      for (int m = 0; m < 2; ++m) {
        oacc[m][nt] = mfma16(pa[m][0], v0, oacc[m][nt]);
        oacc[m][nt] = mfma16(pa[m][1], v1, oacc[m][nt]);
      }
    }
    __builtin_amdgcn_s_setprio(0);
  }

#pragma unroll
  for (int m = 0; m < 2; ++m) {
    lacc[m] += __shfl_xor(lacc[m], 16);
    lacc[m] += __shfl_xor(lacc[m], 32);
  }
  float lr[2][4];
#pragma unroll
  for (int m = 0; m < 2; ++m)
#pragma unroll
    for (int r = 0; r < 4; ++r) lr[m][r] = __shfl(lacc[m], lg * 4 + r);

#pragma unroll
  for (int m = 0; m < 2; ++m)
#pragma unroll
    for (int nt = 0; nt < 4; ++nt)
#pragma unroll
      for (int r = 0; r < 4; ++r) {
        const int qrow = q0 + w * 32 + m * 16 + lg * 4 + r;
        const float val = oacc[m][nt][r] / lr[m][r];
        o[(size_t)(b * NS + qrow) * ND + h * 64 + nt * 16 + lc] = (bf16)val;
      }
}

// ---------------- Flash attention v1 (fallback tiers, no vT) --------------
__global__ __launch_bounds__(256) void flash_attn_v1(
    const bf16* __restrict__ qkv, bf16* __restrict__ o) {
  const int bh = blockIdx.y;
  const int b = bh / NH, h = bh % NH;
  const int qt = gridDim.x - 1 - blockIdx.x;
  const int q0 = qt * 64;
  const int tid = threadIdx.x;
  const int w = tid >> 6, L = tid & 63;
  const int lg = L >> 4, lc = L & 15;

  __shared__ bf16 Ks[64 * 72];
  __shared__ bf16 Vts[64 * 72];
  __shared__ bf16 Ps[4][16 * 72];

  const float QSCALE = 0.18033688011112042f;
  const size_t tokq = (size_t)(b * NS + q0 + w * 16 + lc);
  const bf16* qp = qkv + tokq * (3 * ND) + h * 64 + lg * 8;
  const bf16x8 qr0 = *(const bf16x8*)qp;
  const bf16x8 qr1 = *(const bf16x8*)(qp + 32);
  bf16x8 qf0, qf1;
#pragma unroll
  for (int j = 0; j < 8; ++j) {
    qf0[j] = (bf16)((float)qr0[j] * QSCALE);
    qf1[j] = (bf16)((float)qr1[j] * QSCALE);
  }

  f32x4 oacc[4];
#pragma unroll
  for (int nt = 0; nt < 4; ++nt) oacc[nt] = (f32x4){0.f, 0.f, 0.f, 0.f};
  float lacc[4] = {0.f, 0.f, 0.f, 0.f};

  for (int kt = 0; kt <= qt; ++kt) {
    __syncthreads();
#pragma unroll
    for (int p = 0; p < 2; ++p) {
      const int r = (p * 256 + tid) >> 3;
      const int c = (tid & 7) * 8;
      const bf16* kp =
          qkv + (size_t)(b * NS + kt * 64 + r) * (3 * ND) + ND + h * 64 + c;
      const bf16x8 k8 = *(const bf16x8*)kp;
      *(bf16x8*)&Ks[r * 72 + c] = k8;
      const bf16x8 v8 = *(const bf16x8*)(kp + ND);
#pragma unroll
      for (int j = 0; j < 8; ++j) Vts[(c + j) * 72 + r] = v8[j];
    }
    __syncthreads();

    f32x4 s[4];
#pragma unroll
    for (int nt = 0; nt < 4; ++nt) {
      const bf16x8 b0 = *(const bf16x8*)&Ks[(nt * 16 + lc) * 72 + lg * 8];
      const bf16x8 b1 = *(const bf16x8*)&Ks[(nt * 16 + lc) * 72 + 32 + lg * 8];
      f32x4 z = (f32x4){0.f, 0.f, 0.f, 0.f};
      s[nt] = mfma16(qf0, b0, z);
      s[nt] = mfma16(qf1, b1, s[nt]);
    }
    if (kt == qt) {
#pragma unroll
      for (int nt = 0; nt < 4; ++nt)
#pragma unroll
        for (int r = 0; r < 4; ++r) {
          const int qrow = w * 16 + lg * 4 + r;
          const int kcol = nt * 16 + lc;
          if (kcol > qrow) s[nt][r] = -1.0e30f;
        }
    }
#pragma unroll
    for (int nt = 0; nt < 4; ++nt)
#pragma unroll
      for (int r = 0; r < 4; ++r) {
        const float p = exp2f(fminf(s[nt][r], 20.f));
        lacc[r] += p;
        Ps[w][(lg * 4 + r) * 72 + nt * 16 + lc] = (bf16)p;
      }
    __syncthreads();

    const bf16x8 p0 = *(const bf16x8*)&Ps[w][lc * 72 + lg * 8];
    const bf16x8 p1 = *(const bf16x8*)&Ps[w][lc * 72 + 32 + lg * 8];
#pragma unroll
    for (int nt = 0; nt < 4; ++nt) {
      const bf16x8 v0 = *(const bf16x8*)&Vts[(nt * 16 + lc) * 72 + lg * 8];
      const bf16x8 v1 = *(const bf16x8*)&Vts[(nt * 16 + lc) * 72 + 32 + lg * 8];
      oacc[nt] = mfma16(p0, v0, oacc[nt]);
      oacc[nt] = mfma16(p1, v1, oacc[nt]);
    }
  }

#pragma unroll
  for (int msk = 1; msk < 16; msk <<= 1)
#pragma unroll
    for (int r = 0; r < 4; ++r) lacc[r] += __shfl_xor(lacc[r], msk);

#pragma unroll
  for (int nt = 0; nt < 4; ++nt)
#pragma unroll
    for (int r = 0; r < 4; ++r) {
      const int qrow = q0 + w * 16 + lg * 4 + r;
      const float val = oacc[nt][r] / lacc[r];
      o[(size_t)(b * NS + qrow) * ND + h * 64 + nt * 16 + lc] = (bf16)val;
    }
}

// ---------------- launcher ----------------
extern "C" void kernel_launch(void* const* d_in, const int* in_sizes, int n_in,
                              void* d_out, int out_size, void* d_ws,
                              size_t ws_size, hipStream_t stream) {
  const void* x = d_in[0];
  const void* qkv_w = d_in[2];
  const void* qkv_b = d_in[3];
  const void* out_w = d_in[4];
  const void* out_b = d_in[5];
  const void* fc1_w = d_in[6];
  const void* fc1_b = d_in[7];
  const void* fc2_w = d_in[8];
  const void* fc2_b = d_in[9];
  const void* ln1_w = d_in[10];
  const void* ln1_b = d_in[11];
  const void* ln2_w = d_in[12];
  const void* ln2_b = d_in[13];
  (void)in_sizes; (void)n_in; (void)out_size;

  char* ws = (char*)d_ws;
  int* flag = (int*)ws;

  sniff_kernel<<<dim3(1), 256, 0, stream>>>((const ushort_t*)x, flag);

  const size_t T1 = 58210048, T2 = 51918592, T3 = 45627136, T4 = 39335680;

  if (ws_size >= T2) {
    bf16* wq = (bf16*)(ws + 256);
    bf16* wo = wq + 1769472;
    bf16* w1 = wo + 589824;
    bf16* w2 = w1 + 2359296;
    bf16* bq = w2 + 2359296;
    bf16* bo = bq + 2304;
    bf16* b1 = bo + 768;
    bf16* b2 = b1 + 3072;
    bf16* slotA = b2 + 768;
    bf16* vT = slotA + (size_t)NT * ND;
    bf16* slotB = vT + (size_t)NT * ND;
    bf16* hx = slotA, *oat = slotA, *h2 = slotA;
    bf16* qkv = slotB;
    float* po = (float*)(ws + 45627136);
    float* pl = po + (size_t)24 * 15 * 2 * 4096;
    const bool sp = ws_size >= T1;

    CvtArgs ca;
    ca.s[0] = qkv_w; ca.d[0] = wq; ca.n8[0] = 1769472 / 8;
    ca.s[1] = out_w; ca.d[1] = wo; ca.n8[1] = 589824 / 8;
    ca.s[2] = fc1_w; ca.d[2] = w1; ca.n8[2] = 2359296 / 8;
    ca.s[3] = fc2_w; ca.d[3] = w2; ca.n8[3] = 2359296 / 8;
    ca.s[4] = qkv_b; ca.d[4] = bq; ca.n8[4] = 2304 / 8;
    ca.s[5] = out_b; ca.d[5] = bo; ca.n8[5] = 768 / 8;
    ca.s[6] = fc1_b; ca.d[6] = b1; ca.n8[6] = 3072 / 8;
    ca.s[7] = fc2_b; ca.d[7] = b2; ca.n8[7] = 768 / 8;
    ca.total8 = (1769472 + 589824 + 2359296 + 2359296 + 2304 + 768 + 3072 +
                 768) / 8;
    cvt_all<<<dim3(880), 256, 0, stream>>>(ca, flag);

    ln_kernel<<<dim3(NT / 4), 256, 0, stream>>>(x, ln1_w, ln1_b, hx, flag);
    gemm_qkv64<<<dim3(18, 64), 256, 0, stream>>>(hx, wq, bq, qkv, vT);
    if (sp) {
      flash_attn_sp<<<dim3(47, 24), 128, 0, stream>>>(qkv, vT, oat, po, pl);
      attn_combine<<<dim3(15, 24), 256, 0, stream>>>(po, pl, oat);
    } else {
      flash_attn_v7<<<dim3(NS / 64, NB * NH), 128, 0, stream>>>(qkv, vT, oat);
    }
    gemm64<2, 64><<<dim3(12, 64), 256, 0, stream>>>(
        oat, wo, bo, x, d_out, ND, ND, 0, flag);
    ln_kernel<<<dim3(NT / 4), 256, 0, stream>>>(d_out, ln2_w, ln2_b, h2, flag);
    if (ws_size >= T1) {
      bf16* ff1 = slotB;
      gemm64<1, 128><<<dim3(24, 64), 256, 0, stream>>>(
          h2, w1, b1, nullptr, ff1, NF, ND, 0, flag);
      gemm64<2, 64><<<dim3(12, 64), 256, 0, stream>>>(
          ff1, w2, b2, d_out, d_out, ND, NF, 0, flag);
    } else {
      bf16* ff1c = slotB;
      for (int c = 0; c < 2; ++c) {
        gemm64<1, 128><<<dim3(24, 32), 256, 0, stream>>>(
            h2 + (size_t)c * 2048 * ND, w1, b1, nullptr, ff1c, NF, ND, 0, flag);
        gemm64<2, 64><<<dim3(12, 32), 256, 0, stream>>>(
            ff1c, w2, b2, d_out, d_out, ND, NF, c * 2048, flag);
      }
    }
  } else if (ws_size >= T4) {
    bf16* wq = (bf16*)(ws + 256);
    bf16* wo = wq + 1769472;
    bf16* w1 = wo + 589824;
    bf16* w2 = w1 + 2359296;
    bf16* bq = w2 + 2359296;
    bf16* bo = bq + 2304;
    bf16* b1 = bo + 768;
    bf16* b2 = b1 + 3072;
    bf16* slotA = b2 + 768;
    bf16* slotB = slotA + (size_t)NT * ND;
    bf16* hx = slotA, *oat = slotA, *h2 = slotA;
    bf16* qkv = slotB;

    CvtArgs ca;
    ca.s[0] = qkv_w; ca.d[0] = wq; ca.n8[0] = 1769472 / 8;
    ca.s[1] = out_w; ca.d[1] = wo; ca.n8[1] = 589824 / 8;
    ca.s[2] = fc1_w; ca.d[2] = w1; ca.n8[2] = 2359296 / 8;
    ca.s[3] = fc2_w; ca.d[3] = w2; ca.n8[3] = 2359296 / 8;
    ca.s[4] = qkv_b; ca.d[4] = bq; ca.n8[4] = 2304 / 8;
    ca.s[5] = out_b; ca.d[5] = bo; ca.n8[5] = 768 / 8;
    ca.s[6] = fc1_b; ca.d[6] = b1; ca.n8[6] = 3072 / 8;
    ca.s[7] = fc2_b; ca.d[7] = b2; ca.n8[7] = 768 / 8;
    ca.total8 = (1769472 + 589824 + 2359296 + 2359296 + 2304 + 768 + 3072 +
                 768) / 8;
    cvt_all<<<dim3(880), 256, 0, stream>>>(ca, flag);

    ln_kernel<<<dim3(NT / 4), 256, 0, stream>>>(x, ln1_w, ln1_b, hx, flag);
    gemm_fast<0, 128><<<dim3(18, 32), 256, 0, stream>>>(
        hx, wq, bq, nullptr, qkv, 3 * ND, ND, 0, flag);
    flash_attn_v1<<<dim3(NS / 64, NB * NH), 256, 0, stream>>>(qkv, oat);
    gemm64<2, 64><<<dim3(12, 64), 256, 0, stream>>>(
        oat, wo, bo, x, d_out, ND, ND, 0, flag);
    ln_kernel<<<dim3(NT / 4), 256, 0, stream>>>(d_out, ln2_w, ln2_b, h2, flag);
    if (ws_size >= T3) {
      bf16* ff1 = slotB;
      gemm64<1, 128><<<dim3(24, 64), 256, 0, stream>>>(
          h2, w1, b1, nullptr, ff1, NF, ND, 0, flag);
      gemm64<2, 64><<<dim3(12, 64), 256, 0, stream>>>(
          ff1, w2, b2, d_out, d_out, ND, NF, 0, flag);
    } else {
      bf16* ff1c = slotB;
      for (int c = 0; c < 2; ++c) {
        gemm64<1, 128><<<dim3(24, 32), 256, 0, stream>>>(
            h2 + (size_t)c * 2048 * ND, w1, b1, nullptr, ff1c, NF, ND, 0, flag);
        gemm64<2, 64><<<dim3(12, 32), 256, 0, stream>>>(
            ff1c, w2, b2, d_out, d_out, ND, NF, c * 2048, flag);
      }
    }
  } else {
    const size_t szTD = (size_t)NT * ND * sizeof(bf16);
    bf16* slotA = (bf16*)(ws + 256);
    bf16* qkv = (bf16*)(ws + 256 + szTD);
    bf16* hx = slotA, *oat = slotA, *h2 = slotA;
    bf16* ff1c = qkv;

    ln_kernel<<<dim3(NT / 4), 256, 0, stream>>>(x, ln1_w, ln1_b, hx, flag);
    gemm_bt<0><<<dim3(18, 32), 256, 0, stream>>>(
        hx, qkv_w, qkv_b, nullptr, qkv, 3 * ND, ND, 0, flag);
    flash_attn_v1<<<dim3(NS / 64, NB * NH), 256, 0, stream>>>(qkv, oat);
    gemm_bt<2><<<dim3(6, 32), 256, 0, stream>>>(
        oat, out_w, out_b, x, d_out, ND, ND, 0, flag);
    ln_kernel<<<dim3(NT / 4), 256, 0, stream>>>(d_out, ln2_w, ln2_b, h2, flag);
    for (int c = 0; c < 4; ++c) {
      gemm_bt<1><<<dim3(24, 8), 256, 0, stream>>>(
          h2 + (size_t)c * 1024 * ND, fc1_w, fc1_b, nullptr, ff1c, NF, ND, 0,
          flag);
      gemm_bt<2><<<dim3(6, 8), 256, 0, stream>>>(
          ff1c, fc2_w, fc2_b, d_out, d_out, ND, NF, c * 1024, flag);
    }
  }
}

// Round 13
// 293.759 us; speedup vs baseline: 1.0789x; 1.0086x over previous
//
#include <hip/hip_runtime.h>
#include <hip/hip_bf16.h>
#include <cstdint>
#include <cstddef>

typedef __bf16 bf16;
typedef unsigned short ushort_t;
typedef __attribute__((ext_vector_type(8))) __bf16 bf16x8;
typedef __attribute__((ext_vector_type(4))) __bf16 bf16x4;
typedef __attribute__((ext_vector_type(4))) float f32x4;

#define NB 2
#define NS 2048
#define ND 768
#define NH 12
#define NF 3072
#define NT (NB * NS)   // 4096 tokens

__device__ __forceinline__ f32x4 mfma16(bf16x8 a, bf16x8 b, f32x4 c) {
  return __builtin_amdgcn_mfma_f32_16x16x32_bf16(a, b, c, 0, 0, 0);
}

__device__ __forceinline__ void gl_lds16(const bf16* g, bf16* l) {
  __builtin_amdgcn_global_load_lds(
      (__attribute__((address_space(1))) void*)(uintptr_t)g,
      (__attribute__((address_space(3))) void*)l,
      16, 0, 0);
}

// Bijective XCD-chunked swizzle (m204).
__device__ __forceinline__ int xcd_swz(int lin, int nwg) {
  const int q = nwg >> 3, r = nwg & 7;
  const int x = lin & 7, i = lin >> 3;
  return (x < r ? x * (q + 1) : r * (q + 1) + (x - r) * q) + i;
}

// gelu(x) ~= x * sigmoid(2*0.79788456*(x + 0.044715 x^3)); |err| < ~3e-3
__device__ __forceinline__ float gelu_fast(float v) {
  const float u = v * (0.7978845608028654f + 0.03567740814f * v * v);
  const float e = exp2f(u * 2.885390081777927f);  // e^(2u)
  return v - v / (1.f + e);                       // v*e/(1+e)
}

// r11: flash work units in DESCENDING length order (LPT schedule).
// entry = qt*4 + direct*2 + cc.
__constant__ unsigned char fs_tab[47] = {
    66,                       // len17: (16,D)
    124, 125, 121, 62,        // len16
    120, 116, 117, 113, 58,   // len15
    112, 108, 109, 105, 54,   // len14
    104, 100, 101, 97, 50,    // len13
    96, 92, 93, 89, 46,       // len12
    88, 84, 85, 81, 42,       // len11
    80, 76, 77, 73, 38,       // len10
    72, 68, 69, 34,           // len9
    30, 26, 22, 18, 14, 10, 6, 2  // len8..1 directs
};

// ---------------- dtype sniffer (flag=1 -> I/O is float32) ----------------
__global__ __launch_bounds__(256) void sniff_kernel(
    const ushort_t* __restrict__ x, int* __restrict__ flag) {
  __shared__ int s[4];
  int bad = 0;
  for (int i = threadIdx.x; i < 4096; i += 256) {
    const int e = (x[i] >> 7) & 0xFF;
    bad |= (e >= 0xC0);
  }
  bad = __any(bad) ? 1 : 0;
  if ((threadIdx.x & 63) == 0) s[threadIdx.x >> 6] = bad;
  __syncthreads();
  if (threadIdx.x == 0) *flag = s[0] | s[1] | s[2] | s[3];
}

// ---------------- merged weight/bias conversion (1 launch) ----------------
struct CvtArgs {
  const void* s[8];
  bf16* d[8];
  int n8[8];
  int total8;
};

__global__ __launch_bounds__(256) void cvt_all(CvtArgs a,
                                               const int* __restrict__ flag) {
  const int isf = *flag;
  const int stride = gridDim.x * 256;
  for (int i = blockIdx.x * 256 + threadIdx.x; i < a.total8; i += stride) {
    int seg = 0, off = i;
    while (off >= a.n8[seg]) { off -= a.n8[seg]; ++seg; }
    bf16x8 o;
    if (isf) {
      const float* s = (const float*)a.s[seg] + (size_t)off * 8;
      const f32x4 f0 = *(const f32x4*)s;
      const f32x4 f1 = *(const f32x4*)(s + 4);
#pragma unroll
      for (int j = 0; j < 4; ++j) {
        o[j] = (bf16)f0[j];
        o[4 + j] = (bf16)f1[j];
      }
    } else {
      o = *((const bf16x8*)a.s[seg] + off);
    }
    *((bf16x8*)a.d[seg] + off) = o;
  }
}

// ---------------- LayerNorm: one wave per row of 768; output bf16 ---------
__global__ __launch_bounds__(256) void ln_kernel(
    const void* __restrict__ xv, const void* __restrict__ wv,
    const void* __restrict__ bv, bf16* __restrict__ y,
    const int* __restrict__ flag) {
  const int isf = *flag;
  const int row = blockIdx.x * 4 + (threadIdx.x >> 6);
  const int L = threadIdx.x & 63;
  const float* xf = (const float*)xv;
  const bf16* xh = (const bf16*)xv;
  const float* wf = (const float*)wv;
  const bf16* wh = (const bf16*)wv;
  const float* bf_ = (const float*)bv;
  const bf16* bh = (const bf16*)bv;
  const size_t base = (size_t)row * ND;
  float v[12];
  float s = 0.f, s2 = 0.f;
#pragma unroll
  for (int i = 0; i < 12; ++i) {
    const int c = L + i * 64;
    v[i] = isf ? xf[base + c] : (float)xh[base + c];
    s += v[i];
    s2 += v[i] * v[i];
  }
#pragma unroll
  for (int off = 1; off < 64; off <<= 1) {
    s += __shfl_xor(s, off);
    s2 += __shfl_xor(s2, off);
  }
  const float mean = s * (1.f / 768.f);
  const float var = s2 * (1.f / 768.f) - mean * mean;
  const float rstd = rsqrtf(var + 1e-5f);
  bf16* yr = y + base;
#pragma unroll
  for (int i = 0; i < 12; ++i) {
    const int c = L + i * 64;
    const float ww = isf ? wf[c] : (float)wh[c];
    const float bb = isf ? bf_[c] : (float)bh[c];
    yr[c] = (bf16)((v[i] - mean) * rstd * ww + bb);
  }
}

// ---------------- V transpose kernel (fallback only) ----------------------
__global__ __launch_bounds__(256) void vt_kernel(
    const bf16* __restrict__ qkv, bf16* __restrict__ vT) {
  const int bh = blockIdx.y;
  const int b = bh / NH, h = bh % NH;
  const int st = blockIdx.x;
  __shared__ bf16 Vs[64 * 72];
  const int tid = threadIdx.x;
  {
    const int r = tid >> 2, c = (tid & 3) * 16;
    const bf16* src =
        qkv + (size_t)(b * NS + st * 64 + r) * (3 * ND) + 2 * ND + h * 64 + c;
    *(bf16x8*)&Vs[r * 72 + c] = *(const bf16x8*)src;
    *(bf16x8*)&Vs[r * 72 + c + 8] = *(const bf16x8*)(src + 8);
  }
  __syncthreads();
  {
    const int hd = tid >> 2, t0 = (tid & 3) * 16;
    bf16x8 o0, o1;
#pragma unroll
    for (int j = 0; j < 8; ++j) {
      o0[j] = Vs[(t0 + j) * 72 + hd];
      o1[j] = Vs[(t0 + 8 + j) * 72 + hd];
    }
    bf16* dst = vT + ((size_t)bh * 64 + hd) * NS + st * 64 + t0;
    *(bf16x8*)dst = o0;
    *(bf16x8*)(dst + 8) = o1;
  }
}

// ---------------- gemm64: 64xTN tile, BK=64 ---------------------------------
// r12: TN=64 for fc2/attn-out (proven: fc2 45->off-list). r13: fc1 too --
// fc1 at TN=128 was the last 2-resident kernel (72KB LDS, 56.5us, occ 20%);
// TN=64 gives 48KB LDS -> 3 resident and grid (48,64)=3072 blocks=12/CU.
template <int EPI, int TN>
__global__ __launch_bounds__(256) void gemm64(
    const bf16* __restrict__ A, const bf16* __restrict__ Bt,
    const bf16* __restrict__ bias, const void* resid, void* C,
    int N, int K, int row0, const int* __restrict__ flag) {
  constexpr int NBUF = 3;
  constexpr int NTF = TN / 32;  // 16-col frags per wave (= B loads/stage)
  __shared__ bf16 As[NBUF][64 * 64];
  __shared__ bf16 Bs[NBUF][TN * 64];
  int isf = 0;
  if (EPI == 2) {
    isf = *flag;
    asm volatile("" ::"s"(isf));
  }
  const int tid = threadIdx.x;
  const int w = tid >> 6, L = tid & 63;
  const int lg = L >> 4, lc = L & 15;
  const int wm = (w >> 1) * 32, wn = (w & 1) * (TN / 2);
  const int nwg = gridDim.x * gridDim.y;
  const int lin = xcd_swz(blockIdx.y * gridDim.x + blockIdx.x, nwg);
  const int bm = lin / gridDim.x, bn = lin % gridDim.x;

  const bf16* Ab = A + (size_t)bm * 64 * K;
  const bf16* Bb = Bt + (size_t)bn * TN * K;

  const int srw = tid >> 3;                      // dest row 0..31 per load
  const int scw = ((tid & 7) ^ (srw & 7)) * 8;   // pre-swizzled source col

  f32x4 acc[2][NTF];
#pragma unroll
  for (int i = 0; i < 2; ++i)
#pragma unroll
    for (int j = 0; j < NTF; ++j) acc[i][j] = (f32x4){0.f, 0.f, 0.f, 0.f};

#define G64_STAGE(buf, kk)                                                  \
  do {                                                                      \
    gl_lds16(Ab + (size_t)srw * K + (kk) + scw, As[buf] + tid * 8);         \
    gl_lds16(Ab + (size_t)(srw + 32) * K + (kk) + scw,                      \
             As[buf] + 2048 + tid * 8);                                     \
    _Pragma("unroll") for (int bi = 0; bi < NTF; ++bi)                      \
        gl_lds16(Bb + (size_t)(srw + 32 * bi) * K + (kk) + scw,             \
                 Bs[buf] + bi * 2048 + tid * 8);                            \
  } while (0)

#define G64_COMP(cb)                                                        \
  do {                                                                      \
    bf16x8 af[2][2], bfr[2][NTF];                                           \
    _Pragma("unroll") for (int kk2 = 0; kk2 < 2; ++kk2) {                   \
      _Pragma("unroll") for (int mt = 0; mt < 2; ++mt) {                    \
        const int ra = wm + mt * 16 + lc;                                   \
        af[kk2][mt] = *(const bf16x8*)&As[cb][ra * 64 +                     \
                                             (((kk2 * 4 + lg) ^ (ra & 7))   \
                                              << 3)];                       \
      }                                                                     \
      _Pragma("unroll") for (int nt = 0; nt < NTF; ++nt) {                  \
        const int rb = wn + nt * 16 + lc;                                   \
        bfr[kk2][nt] = *(const bf16x8*)&Bs[cb][rb * 64 +                    \
                                              (((kk2 * 4 + lg) ^ (rb & 7))  \
                                               << 3)];                      \
      }                                                                     \
    }                                                                       \
    _Pragma("unroll") for (int kk2 = 0; kk2 < 2; ++kk2)                     \
        _Pragma("unroll") for (int mt = 0; mt < 2; ++mt)                    \
            _Pragma("unroll") for (int nt = 0; nt < NTF; ++nt)              \
                acc[mt][nt] = mfma16(af[kk2][mt], bfr[kk2][nt],             \
                                     acc[mt][nt]);                          \
  } while (0)

  const int nk = K >> 6;
  G64_STAGE(0, 0);
  int cur = 0, stg = 1;
  int k = 0;
  for (; k < nk - 1; ++k) {
    G64_STAGE(stg, (k + 1) * 64);
    if (TN == 128)
      asm volatile("s_waitcnt vmcnt(6)" ::: "memory");
    else
      asm volatile("s_waitcnt vmcnt(4)" ::: "memory");
    asm volatile("s_barrier" ::: "memory");
    G64_COMP(cur);
    cur = (cur + 1 == NBUF) ? 0 : cur + 1;
    stg = (stg + 1 == NBUF) ? 0 : stg + 1;
  }
  __syncthreads();  // drain last stage (vmcnt(0) + barrier)
  G64_COMP(cur);
#undef G64_STAGE
#undef G64_COMP

  const float* rf = (const float*)resid;
  const bf16* rh = (const bf16*)resid;
  float* Cf = (float*)C;
  bf16* Ch = (bf16*)C;
#pragma unroll
  for (int mt = 0; mt < 2; ++mt) {
#pragma unroll
    for (int nt = 0; nt < NTF; ++nt) {
      const int col = bn * TN + wn + nt * 16 + lc;
      const float bv = (float)bias[col];
#pragma unroll
      for (int r = 0; r < 4; ++r) {
        const int row = bm * 64 + wm + mt * 16 + lg * 4 + r;
        float v = acc[mt][nt][r] + bv;
        if (EPI == 1) v = gelu_fast(v);
        const size_t idx = (size_t)(row0 + row) * N + col;
        if (EPI == 2) {
          v += isf ? rf[idx] : (float)rh[idx];
          if (isf) Cf[idx] = v; else Ch[idx] = (bf16)v;
        } else {
          Ch[idx] = (bf16)v;
        }
      }
    }
  }
}

// ---------------- gemm_qkv64: gemm64 structure + fused QKV epilogue -------
__global__ __launch_bounds__(256) void gemm_qkv64(
    const bf16* __restrict__ A, const bf16* __restrict__ Bt,
    const bf16* __restrict__ bias, bf16* __restrict__ qkvout,
    bf16* __restrict__ vT) {
  const int K = ND, N = 3 * ND;
  constexpr int NBUF = 3;
  __shared__ bf16 As[NBUF][64 * 64];
  __shared__ bf16 Bs[NBUF][128 * 64];
  const int tid = threadIdx.x;
  const int w = tid >> 6, L = tid & 63;
  const int lg = L >> 4, lc = L & 15;
  const int wm = (w >> 1) * 32, wn = (w & 1) * 64;
  const int nwg = gridDim.x * gridDim.y;
  const int lin = xcd_swz(blockIdx.y * gridDim.x + blockIdx.x, nwg);
  const int bm = lin / gridDim.x, bn = lin % gridDim.x;

  const bf16* Ab = A + (size_t)bm * 64 * K;
  const bf16* Bb = Bt + (size_t)bn * 128 * K;

  const int srw = tid >> 3;
  const int scw = ((tid & 7) ^ (srw & 7)) * 8;

  f32x4 acc[2][4];
#pragma unroll
  for (int i = 0; i < 2; ++i)
#pragma unroll
    for (int j = 0; j < 4; ++j) acc[i][j] = (f32x4){0.f, 0.f, 0.f, 0.f};

#define Q64_STAGE(buf, kk)                                                  \
  do {                                                                      \
    gl_lds16(Ab + (size_t)srw * K + (kk) + scw, As[buf] + tid * 8);         \
    gl_lds16(Ab + (size_t)(srw + 32) * K + (kk) + scw,                      \
             As[buf] + 2048 + tid * 8);                                     \
    gl_lds16(Bb + (size_t)srw * K + (kk) + scw, Bs[buf] + tid * 8);         \
    gl_lds16(Bb + (size_t)(srw + 32) * K + (kk) + scw,                      \
             Bs[buf] + 2048 + tid * 8);                                     \
    gl_lds16(Bb + (size_t)(srw + 64) * K + (kk) + scw,                      \
             Bs[buf] + 4096 + tid * 8);                                     \
    gl_lds16(Bb + (size_t)(srw + 96) * K + (kk) + scw,                      \
             Bs[buf] + 6144 + tid * 8);                                     \
  } while (0)

#define Q64_COMP(cb)                                                        \
  do {                                                                      \
    bf16x8 af[2][2], bfr[2][4];                                             \
    _Pragma("unroll") for (int kk2 = 0; kk2 < 2; ++kk2) {                   \
      _Pragma("unroll") for (int mt = 0; mt < 2; ++mt) {                    \
        const int ra = wm + mt * 16 + lc;                                   \
        af[kk2][mt] = *(const bf16x8*)&As[cb][ra * 64 +                     \
                                             (((kk2 * 4 + lg) ^ (ra & 7))   \
                                              << 3)];                       \
      }                                                                     \
      _Pragma("unroll") for (int nt = 0; nt < 4; ++nt) {                    \
        const int rb = wn + nt * 16 + lc;                                   \
        bfr[kk2][nt] = *(const bf16x8*)&Bs[cb][rb * 64 +                    \
                                              (((kk2 * 4 + lg) ^ (rb & 7))  \
                                               << 3)];                      \
      }                                                                     \
    }                                                                       \
    _Pragma("unroll") for (int kk2 = 0; kk2 < 2; ++kk2)                     \
        _Pragma("unroll") for (int mt = 0; mt < 2; ++mt)                    \
            _Pragma("unroll") for (int nt = 0; nt < 4; ++nt)                \
                acc[mt][nt] = mfma16(af[kk2][mt], bfr[kk2][nt],             \
                                     acc[mt][nt]);                          \
  } while (0)

  const int nk = K >> 6;  // 12
  Q64_STAGE(0, 0);
  int cur = 0, stg = 1;
  int k = 0;
  for (; k < nk - 1; ++k) {
    Q64_STAGE(stg, (k + 1) * 64);
    asm volatile("s_waitcnt vmcnt(6)" ::: "memory");
    asm volatile("s_barrier" ::: "memory");
    Q64_COMP(cur);
    cur = (cur + 1 == NBUF) ? 0 : cur + 1;
    stg = (stg + 1 == NBUF) ? 0 : stg + 1;
  }
  __syncthreads();
  Q64_COMP(cur);
#undef Q64_STAGE
#undef Q64_COMP

#pragma unroll
  for (int mt = 0; mt < 2; ++mt) {
#pragma unroll
    for (int nt = 0; nt < 4; ++nt) {
      const int col = bn * 128 + wn + nt * 16 + lc;
      const float bv = (float)bias[col];
      if (col < 2 * ND) {  // Q or K -> qkv buffer
#pragma unroll
        for (int r = 0; r < 4; ++r) {
          const int row = bm * 64 + wm + mt * 16 + lg * 4 + r;
          qkvout[(size_t)row * N + col] = (bf16)(acc[mt][nt][r] + bv);
        }
      } else {  // V -> vT[bh][hd][token], 4 consecutive tokens per lane
        const int colv = col - 2 * ND;
        const int h_ = colv >> 6, hd = colv & 63;
        bf16x4 pk;
#pragma unroll
        for (int r = 0; r < 4; ++r) pk[r] = (bf16)(acc[mt][nt][r] + bv);
        const int tok0 = bm * 64 + wm + mt * 16 + lg * 4;
        const int b_ = tok0 >> 11, s0 = tok0 & (NS - 1);
        *(bf16x4*)&vT[((size_t)(b_ * NH + h_) * 64 + hd) * NS + s0] = pk;
      }
    }
  }
}

// ---------------- fast GEMM (TM=128): counted-vmcnt + T2 swizzle ----------
template <int EPI, int TM>
__global__ __launch_bounds__(256) void gemm_fast(
    const bf16* __restrict__ A, const bf16* __restrict__ Bt,
    const bf16* __restrict__ bias, const void* resid, void* C,
    int N, int K, int row0, const int* __restrict__ flag) {
  constexpr int NBUF = (TM == 64) ? 5 : 3;
  constexpr int LOOK = NBUF - 2;
  constexpr int MT = TM / 32;
  __shared__ bf16 As[NBUF][TM * 32];
  __shared__ bf16 Bs[NBUF][128 * 32];
  int isf = 0;
  if (EPI == 2) {
    isf = *flag;
    asm volatile("" ::"s"(isf));
  }
  const int tid = threadIdx.x;
  const int w = tid >> 6, L = tid & 63;
  const int lg = L >> 4, lc = L & 15;
  const int lgx = (lg ^ ((lc >> 1) & 3)) * 8;
  const int wm = (w >> 1) * (TM / 2), wn = (w & 1) * 64;
  const int nwg = gridDim.x * gridDim.y;
  const int lin = xcd_swz(blockIdx.y * gridDim.x + blockIdx.x, nwg);
  const int bm = lin / gridDim.x, bn = lin % gridDim.x;

  const bf16* Ab = A + (size_t)bm * TM * K;
  const bf16* Bb = Bt + (size_t)bn * 128 * K;

  const int sr = tid >> 2;
  const int sc = ((tid & 3) ^ ((tid >> 3) & 3)) * 8;

  f32x4 acc[MT][4];
#pragma unroll
  for (int i = 0; i < MT; ++i)
#pragma unroll
    for (int j = 0; j < 4; ++j) acc[i][j] = (f32x4){0.f, 0.f, 0.f, 0.f};

#define GF_STAGE(buf, kk)                                                   \
  do {                                                                      \
    gl_lds16(Ab + (size_t)sr * K + (kk) + sc, As[buf] + tid * 8);           \
    if (TM == 128)                                                          \
      gl_lds16(Ab + (size_t)(sr + 64) * K + (kk) + sc,                      \
               As[buf] + 2048 + tid * 8);                                   \
    gl_lds16(Bb + (size_t)sr * K + (kk) + sc, Bs[buf] + tid * 8);           \
    gl_lds16(Bb + (size_t)(sr + 64) * K + (kk) + sc,                        \
             Bs[buf] + 2048 + tid * 8);                                     \
  } while (0)

#define GF_COMP(cb)                                                         \
  do {                                                                      \
    bf16x8 af[MT], bfr[4];                                                  \
    _Pragma("unroll") for (int mt = 0; mt < MT; ++mt) af[mt] =              \
        *(const bf16x8*)&As[cb][(wm + mt * 16 + lc) * 32 + lgx];            \
    _Pragma("unroll") for (int nt = 0; nt < 4; ++nt) bfr[nt] =              \
        *(const bf16x8*)&Bs[cb][(wn + nt * 16 + lc) * 32 + lgx];            \
    _Pragma("unroll") for (int mt = 0; mt < MT; ++mt)                       \
        _Pragma("unroll") for (int nt = 0; nt < 4; ++nt) acc[mt][nt] =      \
            mfma16(af[mt], bfr[nt], acc[mt][nt]);                           \
  } while (0)

  const int nk = K >> 5;
#pragma unroll
  for (int s = 0; s < LOOK; ++s)
    if (s < nk) GF_STAGE(s, s * 32);
  int cur = 0, stg = LOOK;
  int k = 0;
  const int kmain = (nk > LOOK) ? nk - LOOK : 0;
  for (; k < kmain; ++k) {
    GF_STAGE(stg, (k + LOOK) * 32);
    if (TM == 64)
      asm volatile("s_waitcnt vmcnt(9)" ::: "memory");
    else
      asm volatile("s_waitcnt vmcnt(4)" ::: "memory");
    asm volatile("s_barrier" ::: "memory");
    GF_COMP(cur);
    cur = (cur + 1 == NBUF) ? 0 : cur + 1;
    stg = (stg + 1 == NBUF) ? 0 : stg + 1;
  }
  __syncthreads();
  for (; k < nk; ++k) {
    GF_COMP(cur);
    cur = (cur + 1 == NBUF) ? 0 : cur + 1;
  }
#undef GF_STAGE
#undef GF_COMP

  const float* rf = (const float*)resid;
  const bf16* rh = (const bf16*)resid;
  float* Cf = (float*)C;
  bf16* Ch = (bf16*)C;
#pragma unroll
  for (int mt = 0; mt < MT; ++mt) {
#pragma unroll
    for (int nt = 0; nt < 4; ++nt) {
      const int col = bn * 128 + wn + nt * 16 + lc;
      const float bv = (float)bias[col];
#pragma unroll
      for (int r = 0; r < 4; ++r) {
        const int row = bm * TM + wm + mt * 16 + lg * 4 + r;
        float v = acc[mt][nt][r] + bv;
        if (EPI == 1) v = gelu_fast(v);
        const size_t idx = (size_t)(row0 + row) * N + col;
        if (EPI == 2) {
          v += isf ? rf[idx] : (float)rh[idx];
          if (isf) Cf[idx] = v; else Ch[idx] = (bf16)v;
        } else {
          Ch[idx] = (bf16)v;
        }
      }
    }
  }
}

// ---------------- fallback GEMM (dtype-branch staging, round-3) -----------
template <int EPI>
__global__ __launch_bounds__(256) void gemm_bt(
    const bf16* __restrict__ A, const void* __restrict__ Bt,
    const void* __restrict__ bias, const void* resid, void* C,
    int N, int K, int row0, const int* __restrict__ flag) {
  __shared__ bf16 As[128 * 32];
  __shared__ bf16 Bs[128 * 32];
  const int isf = *flag;
  const int tid = threadIdx.x;
  const int w = tid >> 6, L = tid & 63;
  const int lg = L >> 4, lc = L & 15;
  const int wm = (w >> 1) * 64, wn = (w & 1) * 64;
  const int nwg = gridDim.x * gridDim.y;
  const int lin = xcd_swz(blockIdx.y * gridDim.x + blockIdx.x, nwg);
  const int bm = lin / gridDim.x, bn = lin % gridDim.x;

  const bf16* Ab = A + (size_t)bm * 128 * K;
  const bf16* Bth = (const bf16*)Bt + (size_t)bn * 128 * K;
  const float* Btf = (const float*)Bt + (size_t)bn * 128 * K;

  const int sr = tid >> 1;
  const int sc = (tid & 1) * 16;

  f32x4 acc[4][4];
#pragma unroll
  for (int i = 0; i < 4; ++i)
#pragma unroll
    for (int j = 0; j < 4; ++j) acc[i][j] = (f32x4){0.f, 0.f, 0.f, 0.f};

  for (int k0 = 0; k0 < K; k0 += 32) {
    const bf16* ap = Ab + (size_t)sr * K + k0 + sc;
    const bf16x8 a0 = *(const bf16x8*)ap;
    const bf16x8 a1 = *(const bf16x8*)(ap + 8);
    bf16x8 b0, b1;
    if (isf) {
      const float* bp = Btf + (size_t)sr * K + k0 + sc;
      const f32x4 f0 = *(const f32x4*)bp;
      const f32x4 f1 = *(const f32x4*)(bp + 4);
      const f32x4 f2 = *(const f32x4*)(bp + 8);
      const f32x4 f3 = *(const f32x4*)(bp + 12);
#pragma unroll
      for (int j = 0; j < 4; ++j) {
        b0[j] = (bf16)f0[j];
        b0[4 + j] = (bf16)f1[j];
        b1[j] = (bf16)f2[j];
        b1[4 + j] = (bf16)f3[j];
      }
    } else {
      const bf16* bp = Bth + (size_t)sr * K + k0 + sc;
      b0 = *(const bf16x8*)bp;
      b1 = *(const bf16x8*)(bp + 8);
    }
    __syncthreads();
    *(bf16x8*)&As[sr * 32 + sc] = a0;
    *(bf16x8*)&As[sr * 32 + sc + 8] = a1;
    *(bf16x8*)&Bs[sr * 32 + sc] = b0;
    *(bf16x8*)&Bs[sr * 32 + sc + 8] = b1;
    __syncthreads();

    bf16x8 af[4], bfr[4];
#pragma unroll
    for (int mt = 0; mt < 4; ++mt)
      af[mt] = *(const bf16x8*)&As[(wm + mt * 16 + lc) * 32 + lg * 8];
#pragma unroll
    for (int nt = 0; nt < 4; ++nt)
      bfr[nt] = *(const bf16x8*)&Bs[(wn + nt * 16 + lc) * 32 + lg * 8];
#pragma unroll
    for (int mt = 0; mt < 4; ++mt)
#pragma unroll
      for (int nt = 0; nt < 4; ++nt)
        acc[mt][nt] = mfma16(af[mt], bfr[nt], acc[mt][nt]);
  }

  const float* biasf = (const float*)bias;
  const bf16* biash = (const bf16*)bias;
  const float* rf = (const float*)resid;
  const bf16* rh = (const bf16*)resid;
  float* Cf = (float*)C;
  bf16* Ch = (bf16*)C;
#pragma unroll
  for (int mt = 0; mt < 4; ++mt) {
#pragma unroll
    for (int nt = 0; nt < 4; ++nt) {
      const int col = bn * 128 + wn + nt * 16 + lc;
      const float bv = isf ? biasf[col] : (float)biash[col];
#pragma unroll
      for (int r = 0; r < 4; ++r) {
        const int row = bm * 128 + wm + mt * 16 + lg * 4 + r;
        float v = acc[mt][nt][r] + bv;
        if (EPI == 1) v = gelu_fast(v);
        const size_t idx = (size_t)(row0 + row) * N + col;
        if (EPI == 2) {
          v += isf ? rf[idx] : (float)rh[idx];
          if (isf) Cf[idx] = v; else Ch[idx] = (bf16)v;
        } else {
          Ch[idx] = (bf16)v;
        }
      }
    }
  }
}

// ---------------- Flash attention v12: split-KV + LPT dispatch order ------
__global__ __launch_bounds__(128) void flash_attn_sp(
    const bf16* __restrict__ qkv, const bf16* __restrict__ vT,
    bf16* __restrict__ o, float* __restrict__ po, float* __restrict__ pl) {
  const int nwg = gridDim.x * gridDim.y;  // 1128 = 8 XCD * 141
  const int lin = xcd_swz(blockIdx.y * gridDim.x + blockIdx.x, nwg);
  const int i141 = lin % 141;
  const int t = i141 / 3, bl = i141 % 3;       // LPT index, bh interleave
  const int bh = (lin / 141) * 3 + bl;
  const int b = bh / NH, h = bh % NH;
  const unsigned v_ = fs_tab[t];
  const int qt = v_ >> 2;
  const int direct = (v_ >> 1) & 1;
  const int cc = v_ & 1;
  int kt_lo, kt_hi;
  if (direct) {
    kt_lo = 0; kt_hi = qt;
  } else {
    const int hh = (qt + 1) >> 1;
    if (cc) { kt_lo = hh; kt_hi = qt; }
    else    { kt_lo = 0;  kt_hi = hh - 1; }
  }
  const int q0 = qt * 64;
  const int tid = threadIdx.x;  // 128 threads = 2 waves
  const int w = tid >> 6, L = tid & 63;
  const int lg = L >> 4, lc = L & 15;

  __shared__ bf16 Ks[64 * 72];   // [kv][hd]
  __shared__ bf16 Vts[64 * 72];  // [hd][kv]
  __shared__ bf16 Ps[2][32 * 72];

  const float QSCALE = 0.18033688011112042f;  // (1/8) * log2(e)
  bf16x8 qf[2][2];
#pragma unroll
  for (int m = 0; m < 2; ++m) {
    const size_t tokq = (size_t)(b * NS + q0 + w * 32 + m * 16 + lc);
    const bf16* qp = qkv + tokq * (3 * ND) + h * 64 + lg * 8;
    const bf16x8 q0r = *(const bf16x8*)qp;
    const bf16x8 q1r = *(const bf16x8*)(qp + 32);
#pragma unroll
    for (int jj = 0; jj < 8; ++jj) {
      qf[m][0][jj] = (bf16)((float)q0r[jj] * QSCALE);
      qf[m][1][jj] = (bf16)((float)q1r[jj] * QSCALE);
    }
  }

  const int kr = tid >> 1, kc = (tid & 1) * 32;
  const bf16* kbase =
      qkv + (size_t)(b * NS + kr) * (3 * ND) + ND + h * 64 + kc;
  const bf16* vbase = vT + ((size_t)bh * 64 + kr) * NS + kc;

  f32x4 oacc[2][4];
#pragma unroll
  for (int m = 0; m < 2; ++m)
#pragma unroll
    for (int nt = 0; nt < 4; ++nt) oacc[m][nt] = (f32x4){0.f, 0.f, 0.f, 0.f};
  float lacc[2] = {0.f, 0.f};

  bf16x8 kreg[4], vreg[4];
  {
    const bf16* kn = kbase + (size_t)kt_lo * 64 * (3 * ND);
    const bf16* vn = vbase + (size_t)kt_lo * 64;
#pragma unroll
    for (int p = 0; p < 4; ++p) {
      kreg[p] = *(const bf16x8*)(kn + p * 8);
      vreg[p] = *(const bf16x8*)(vn + p * 8);
    }
  }

  for (int kt = kt_lo; kt <= kt_hi; ++kt) {
    __syncthreads();
#pragma unroll
    for (int p = 0; p < 4; ++p) {
      *(bf16x8*)&Ks[kr * 72 + kc + p * 8] = kreg[p];
      *(bf16x8*)&Vts[kr * 72 + kc + p * 8] = vreg[p];
    }
    __syncthreads();

    if (kt < kt_hi) {
      const bf16* kn = kbase + (size_t)(kt + 1) * 64 * (3 * ND);
      const bf16* vn = vbase + (size_t)(kt + 1) * 64;
#pragma unroll
      for (int p = 0; p < 4; ++p) {
        kreg[p] = *(const bf16x8*)(kn + p * 8);
        vreg[p] = *(const bf16x8*)(vn + p * 8);
      }
    }

    f32x4 s[2][4];
    __builtin_amdgcn_s_setprio(1);
#pragma unroll
    for (int nt = 0; nt < 4; ++nt) {
      const bf16x8 kb0 = *(const bf16x8*)&Ks[(nt * 16 + lc) * 72 + lg * 8];
      const bf16x8 kb1 =
          *(const bf16x8*)&Ks[(nt * 16 + lc) * 72 + 32 + lg * 8];
#pragma unroll
      for (int m = 0; m < 2; ++m) {
        f32x4 z = (f32x4){0.f, 0.f, 0.f, 0.f};
        s[m][nt] = mfma16(kb0, qf[m][0], z);
        s[m][nt] = mfma16(kb1, qf[m][1], s[m][nt]);
      }
    }
    __builtin_amdgcn_s_setprio(0);
    if (kt == qt) {
#pragma unroll
      for (int m = 0; m < 2; ++m)
#pragma unroll
        for (int nt = 0; nt < 4; ++nt)
#pragma unroll
          for (int r = 0; r < 4; ++r) {
            const int kv = nt * 16 + lg * 4 + r;
            const int qrow = w * 32 + m * 16 + lc;
            if (kv > qrow) s[m][nt][r] = -1.0e30f;
          }
    }
#pragma unroll
    for (int m = 0; m < 2; ++m)
#pragma unroll
      for (int nt = 0; nt < 4; ++nt) {
        bf16x4 pk;
#pragma unroll
        for (int r = 0; r < 4; ++r) {
          const float p = exp2f(fminf(s[m][nt][r], 20.f));
          lacc[m] += p;
          pk[r] = (bf16)p;
        }
        *(bf16x4*)&Ps[w][(m * 16 + lc) * 72 + nt * 16 + lg * 4] = pk;
      }
    bf16x8 pa[2][2];
#pragma unroll
    for (int m = 0; m < 2; ++m) {
      pa[m][0] = *(const bf16x8*)&Ps[w][(m * 16 + lc) * 72 + lg * 8];
      pa[m][1] = *(const bf16x8*)&Ps[w][(m * 16 + lc) * 72 + 32 + lg * 8];
    }
    __builtin_amdgcn_s_setprio(1);
#pragma unroll
    for (int nt = 0; nt < 4; ++nt) {
      const bf16x8 v0 = *(const bf16x8*)&Vts[(nt * 16 + lc) * 72 + lg * 8];
      const bf16x8 v1 =
          *(const bf16x8*)&Vts[(nt * 16 + lc) * 72 + 32 + lg * 8];
#pragma unroll
      for (int m = 0; m < 2; ++m) {
        oacc[m][nt] = mfma16(pa[m][0], v0, oacc[m][nt]);
        oacc[m][nt] = mfma16(pa[m][1], v1, oacc[m][nt]);
      }
    }
    __builtin_amdgcn_s_setprio(0);
  }

#pragma unroll
  for (int m = 0; m < 2; ++m) {
    lacc[m] += __shfl_xor(lacc[m], 16);
    lacc[m] += __shfl_xor(lacc[m], 32);
  }

  if (direct) {
    float lr[2][4];
#pragma unroll
    for (int m = 0; m < 2; ++m)
#pragma unroll
      for (int r = 0; r < 4; ++r) lr[m][r] = __shfl(lacc[m], lg * 4 + r);
#pragma unroll
    for (int m = 0; m < 2; ++m)
#pragma unroll
      for (int nt = 0; nt < 4; ++nt)
#pragma unroll
        for (int r = 0; r < 4; ++r) {
          const int qrow = q0 + w * 32 + m * 16 + lg * 4 + r;
          const float val = oacc[m][nt][r] / lr[m][r];
          o[(size_t)(b * NS + qrow) * ND + h * 64 + nt * 16 + lc] =
              (bf16)val;
        }
  } else {
    const int slot = qt - 17;  // 0..14
    float* pob = po + (((size_t)(bh * 15 + slot)) * 2 + cc) * 4096;
#pragma unroll
    for (int m = 0; m < 2; ++m)
#pragma unroll
      for (int nt = 0; nt < 4; ++nt)
#pragma unroll
        for (int r = 0; r < 4; ++r) {
          const int row = w * 32 + m * 16 + lg * 4 + r;
          const int col = nt * 16 + lc;
          pob[row * 64 + col] = oacc[m][nt][r];
        }
    if (L < 16) {
      float* plb = pl + ((bh * 15 + slot) * 2 + cc) * 64;
      plb[w * 32 + L] = lacc[0];
      plb[w * 32 + 16 + L] = lacc[1];
    }
  }
}

// ---------------- attention partial combine (qt>=17 tiles) ----------------
__global__ __launch_bounds__(256) void attn_combine(
    const float* __restrict__ po, const float* __restrict__ pl,
    bf16* __restrict__ o) {
  const int slot = blockIdx.x;  // 0..14 -> qt = slot+17
  const int bh = blockIdx.y;    // 0..23
  const int qt = slot + 17;
  const int b = bh / NH, h = bh % NH;
  const float* poA = po + ((size_t)(bh * 15 + slot)) * 2 * 4096;
  const float* poB = poA + 4096;
  const float* plA = pl + (bh * 15 + slot) * 2 * 64;
  const float* plB = plA + 64;
  for (int e = threadIdx.x; e < 4096; e += 256) {
    const int q = e >> 6, hd = e & 63;
    const float val = (poA[e] + poB[e]) / (plA[q] + plB[q]);
    o[(size_t)(b * NS + qt * 64 + q) * ND + h * 64 + hd] = (bf16)val;
  }
}

// ---------------- Flash attention v9 (T2 tier: no partial workspace) ------
__global__ __launch_bounds__(128) void flash_attn_v7(
    const bf16* __restrict__ qkv, const bf16* __restrict__ vT,
    bf16* __restrict__ o) {
  const int nwg = gridDim.x * gridDim.y;  // 768 = 8 XCD * 96
  const int lin = xcd_swz(blockIdx.y * gridDim.x + blockIdx.x, nwg);
  const int xcd = lin / 96;
  const int i96 = lin % 96;
  const int bl = i96 >> 5;
  const int j = i96 & 31;
  const int bh = xcd * 3 + bl;
  const int b = bh / NH, h = bh % NH;
  int qt;
  if (bl == 0) qt = j;
  else if (bl == 1) qt = (j + 16) & 31;
  else qt = (j < 16) ? (31 - 2 * j) : (62 - 2 * j);
  const int q0 = qt * 64;
  const int tid = threadIdx.x;
  const int w = tid >> 6, L = tid & 63;
  const int lg = L >> 4, lc = L & 15;

  __shared__ bf16 Ks[2][64 * 72];
  __shared__ bf16 Vts[2][64 * 72];
  __shared__ bf16 Ps[2][32 * 72];

  const float QSCALE = 0.18033688011112042f;
  bf16x8 qf[2][2];
#pragma unroll
  for (int m = 0; m < 2; ++m) {
    const size_t tokq = (size_t)(b * NS + q0 + w * 32 + m * 16 + lc);
    const bf16* qp = qkv + tokq * (3 * ND) + h * 64 + lg * 8;
    const bf16x8 q0r = *(const bf16x8*)qp;
    const bf16x8 q1r = *(const bf16x8*)(qp + 32);
#pragma unroll
    for (int jj = 0; jj < 8; ++jj) {
      qf[m][0][jj] = (bf16)((float)q0r[jj] * QSCALE);
      qf[m][1][jj] = (bf16)((float)q1r[jj] * QSCALE);
    }
  }

  const int kr = tid >> 1, kc = (tid & 1) * 32;
  const bf16* kbase =
      qkv + (size_t)(b * NS + kr) * (3 * ND) + ND + h * 64 + kc;
  const bf16* vbase = vT + ((size_t)bh * 64 + kr) * NS + kc;

  f32x4 oacc[2][4];
#pragma unroll
  for (int m = 0; m < 2; ++m)
#pragma unroll
    for (int nt = 0; nt < 4; ++nt) oacc[m][nt] = (f32x4){0.f, 0.f, 0.f, 0.f};
  float lacc[2] = {0.f, 0.f};

  const int nkt = qt + 1;

  bf16x8 kreg[4], vreg[4];
#pragma unroll
  for (int p = 0; p < 4; ++p) {
    kreg[p] = *(const bf16x8*)(kbase + p * 8);
    vreg[p] = *(const bf16x8*)(vbase + p * 8);
  }
#pragma unroll
  for (int p = 0; p < 4; ++p) {
    *(bf16x8*)&Ks[0][kr * 72 + kc + p * 8] = kreg[p];
    *(bf16x8*)&Vts[0][kr * 72 + kc + p * 8] = vreg[p];
  }

  for (int kt = 0; kt < nkt; ++kt) {
    __syncthreads();
    const int cur = kt & 1;

    if (kt + 1 < nkt) {
      const bf16* kn = kbase + (size_t)(kt + 1) * 64 * (3 * ND);
      const bf16* vn = vbase + (size_t)(kt + 1) * 64;
#pragma unroll
      for (int p = 0; p < 4; ++p) {
        kreg[p] = *(const bf16x8*)(kn + p * 8);
        vreg[p] = *(const bf16x8*)(vn + p * 8);
      }
    }

    f32x4 s[2][4];
    __builtin_amdgcn_s_setprio(1);
#pragma unroll
    for (int nt = 0; nt < 4; ++nt) {
      const bf16x8 kb0 =
          *(const bf16x8*)&Ks[cur][(nt * 16 + lc) * 72 + lg * 8];
      const bf16x8 kb1 =
          *(const bf16x8*)&Ks[cur][(nt * 16 + lc) * 72 + 32 + lg * 8];
#pragma unroll
      for (int m = 0; m < 2; ++m) {
        f32x4 z = (f32x4){0.f, 0.f, 0.f, 0.f};
        s[m][nt] = mfma16(kb0, qf[m][0], z);
        s[m][nt] = mfma16(kb1, qf[m][1], s[m][nt]);
      }
    }
    __builtin_amdgcn_s_setprio(0);
    if (kt == nkt - 1) {
#pragma unroll
      for (int m = 0; m < 2; ++m)
#pragma unroll
        for (int nt = 0; nt < 4; ++nt)
#pragma unroll
          for (int r = 0; r < 4; ++r) {
            const int kv = nt * 16 + lg * 4 + r;
            const int qrow = w * 32 + m * 16 + lc;
            if (kv > qrow) s[m][nt][r] = -1.0e30f;
          }
    }
#pragma unroll
    for (int m = 0; m < 2; ++m)
#pragma unroll
      for (int nt = 0; nt < 4; ++nt) {
        bf16x4 pk;
#pragma unroll
        for (int r = 0; r < 4; ++r) {
          const float p = exp2f(fminf(s[m][nt][r], 20.f));
          lacc[m] += p;
          pk[r] = (bf16)p;
        }
        *(bf16x4*)&Ps[w][(m * 16 + lc) * 72 + nt * 16 + lg * 4] = pk;
      }
    bf16x8 pa[2][2];
#pragma unroll
    for (int m = 0; m < 2; ++m) {
      pa[m][0] = *(const bf16x8*)&Ps[w][(m * 16 + lc) * 72 + lg * 8];
      pa[m][1] = *(const bf16x8*)&Ps[w][(m * 16 + lc) * 72 + 32 + lg * 8];
    }

    if (kt + 1 < nkt) {
      const int nxt = cur ^ 1;
#pragma unroll
      for (int p = 0; p < 4; ++p) {
        *(bf16x8*)&Ks[nxt][kr * 72 + kc + p * 8] = kreg[p];
        *(bf16x8*)&Vts[nxt][kr * 72 + kc + p * 8] = vreg[p];
      }
    }

    __builtin_amdgcn_s_setprio(1);
#pragma unroll
    for (int nt = 0; nt < 4; ++nt) {
      const bf16x8 v0 =
          *(const bf16x8*)&Vts[cur][(nt * 16 + lc) * 72 + lg * 8];
      const bf16x8 v1 =
          *(const bf16x8*)&Vts[cur][(nt * 16 + lc) * 72 + 32 + lg * 8];
#pragma unroll
      for (int m = 0; m < 2; ++m) {
        oacc[m][nt] = mfma16(pa[m][0], v0, oacc[m][nt]);
        oacc[m][nt] = mfma16(pa[m][1], v1, oacc[m][nt]);
      }
    }
    __builtin_amdgcn_s_setprio(0);
  }

#pragma unroll
  for (int m = 0; m < 2; ++m) {
    lacc[m] += __shfl_xor(lacc[m], 16);
    lacc[m] += __shfl_xor(lacc[m], 32);
  }
  float lr[2][4];
#pragma unroll
  for (int m = 0; m < 2; ++m)
#pragma unroll
    for (int r = 0; r < 4; ++r) lr[m][r] = __shfl(lacc[m], lg * 4 + r);

#pragma unroll
  for (int m = 0; m < 2; ++m)
#pragma unroll
    for (int nt = 0; nt < 4; ++nt)
#pragma unroll
      for (int r = 0; r < 4; ++r) {
        const int qrow = q0 + w * 32 + m * 16 + lg * 4 + r;
        const float val = oacc[m][nt][r] / lr[m][r];
        o[(size_t)(b * NS + qrow) * ND + h * 64 + nt * 16 + lc] = (bf16)val;
      }
}

// ---------------- Flash attention v1 (fallback tiers, no vT) --------------
__global__ __launch_bounds__(256) void flash_attn_v1(
    const bf16* __restrict__ qkv, bf16* __restrict__ o) {
  const int bh = blockIdx.y;
  const int b = bh / NH, h = bh % NH;
  const int qt = gridDim.x - 1 - blockIdx.x;
  const int q0 = qt * 64;
  const int tid = threadIdx.x;
  const int w = tid >> 6, L = tid & 63;
  const int lg = L >> 4, lc = L & 15;

  __shared__ bf16 Ks[64 * 72];
  __shared__ bf16 Vts[64 * 72];
  __shared__ bf16 Ps[4][16 * 72];

  const float QSCALE = 0.18033688011112042f;
  const size_t tokq = (size_t)(b * NS + q0 + w * 16 + lc);
  const bf16* qp = qkv + tokq * (3 * ND) + h * 64 + lg * 8;
  const bf16x8 qr0 = *(const bf16x8*)qp;
  const bf16x8 qr1 = *(const bf16x8*)(qp + 32);
  bf16x8 qf0, qf1;
#pragma unroll
  for (int j = 0; j < 8; ++j) {
    qf0[j] = (bf16)((float)qr0[j] * QSCALE);
    qf1[j] = (bf16)((float)qr1[j] * QSCALE);
  }

  f32x4 oacc[4];
#pragma unroll
  for (int nt = 0; nt < 4; ++nt) oacc[nt] = (f32x4){0.f, 0.f, 0.f, 0.f};
  float lacc[4] = {0.f, 0.f, 0.f, 0.f};

  for (int kt = 0; kt <= qt; ++kt) {
    __syncthreads();
#pragma unroll
    for (int p = 0; p < 2; ++p) {
      const int r = (p * 256 + tid) >> 3;
      const int c = (tid & 7) * 8;
      const bf16* kp =
          qkv + (size_t)(b * NS + kt * 64 + r) * (3 * ND) + ND + h * 64 + c;
      const bf16x8 k8 = *(const bf16x8*)kp;
      *(bf16x8*)&Ks[r * 72 + c] = k8;
      const bf16x8 v8 = *(const bf16x8*)(kp + ND);
#pragma unroll
      for (int j = 0; j < 8; ++j) Vts[(c + j) * 72 + r] = v8[j];
    }
    __syncthreads();

    f32x4 s[4];
#pragma unroll
    for (int nt = 0; nt < 4; ++nt) {
      const bf16x8 b0 = *(const bf16x8*)&Ks[(nt * 16 + lc) * 72 + lg * 8];
      const bf16x8 b1 = *(const bf16x8*)&Ks[(nt * 16 + lc) * 72 + 32 + lg * 8];
      f32x4 z = (f32x4){0.f, 0.f, 0.f, 0.f};
      s[nt] = mfma16(qf0, b0, z);
      s[nt] = mfma16(qf1, b1, s[nt]);
    }
    if (kt == qt) {
#pragma unroll
      for (int nt = 0; nt < 4; ++nt)
#pragma unroll
        for (int r = 0; r < 4; ++r) {
          const int qrow = w * 16 + lg * 4 + r;
          const int kcol = nt * 16 + lc;
          if (kcol > qrow) s[nt][r] = -1.0e30f;
        }
    }
#pragma unroll
    for (int nt = 0; nt < 4; ++nt)
#pragma unroll
      for (int r = 0; r < 4; ++r) {
        const float p = exp2f(fminf(s[nt][r], 20.f));
        lacc[r] += p;
        Ps[w][(lg * 4 + r) * 72 + nt * 16 + lc] = (bf16)p;
      }
    __syncthreads();

    const bf16x8 p0 = *(const bf16x8*)&Ps[w][lc * 72 + lg * 8];
    const bf16x8 p1 = *(const bf16x8*)&Ps[w][lc * 72 + 32 + lg * 8];
#pragma unroll
    for (int nt = 0; nt < 4; ++nt) {
      const bf16x8 v0 = *(const bf16x8*)&Vts[(nt * 16 + lc) * 72 + lg * 8];
      const bf16x8 v1 = *(const bf16x8*)&Vts[(nt * 16 + lc) * 72 + 32 + lg * 8];
      oacc[nt] = mfma16(p0, v0, oacc[nt]);
      oacc[nt] = mfma16(p1, v1, oacc[nt]);
    }
  }

#pragma unroll
  for (int msk = 1; msk < 16; msk <<= 1)
#pragma unroll
    for (int r = 0; r < 4; ++r) lacc[r] += __shfl_xor(lacc[r], msk);

#pragma unroll
  for (int nt = 0; nt < 4; ++nt)
#pragma unroll
    for (int r = 0; r < 4; ++r) {
      const int qrow = q0 + w * 16 + lg * 4 + r;
      const float val = oacc[nt][r] / lacc[r];
      o[(size_t)(b * NS + qrow) * ND + h * 64 + nt * 16 + lc] = (bf16)val;
    }
}

// ---------------- launcher ----------------
extern "C" void kernel_launch(void* const* d_in, const int* in_sizes, int n_in,
                              void* d_out, int out_size, void* d_ws,
                              size_t ws_size, hipStream_t stream) {
  const void* x = d_in[0];
  const void* qkv_w = d_in[2];
  const void* qkv_b = d_in[3];
  const void* out_w = d_in[4];
  const void* out_b = d_in[5];
  const void* fc1_w = d_in[6];
  const void* fc1_b = d_in[7];
  const void* fc2_w = d_in[8];
  const void* fc2_b = d_in[9];
  const void* ln1_w = d_in[10];
  const void* ln1_b = d_in[11];
  const void* ln2_w = d_in[12];
  const void* ln2_b = d_in[13];
  (void)in_sizes; (void)n_in; (void)out_size;

  char* ws = (char*)d_ws;
  int* flag = (int*)ws;

  sniff_kernel<<<dim3(1), 256, 0, stream>>>((const ushort_t*)x, flag);

  const size_t T1 = 58210048, T2 = 51918592, T3 = 45627136, T4 = 39335680;

  if (ws_size >= T2) {
    bf16* wq = (bf16*)(ws + 256);
    bf16* wo = wq + 1769472;
    bf16* w1 = wo + 589824;
    bf16* w2 = w1 + 2359296;
    bf16* bq = w2 + 2359296;
    bf16* bo = bq + 2304;
    bf16* b1 = bo + 768;
    bf16* b2 = b1 + 3072;
    bf16* slotA = b2 + 768;
    bf16* vT = slotA + (size_t)NT * ND;
    bf16* slotB = vT + (size_t)NT * ND;
    bf16* hx = slotA, *oat = slotA, *h2 = slotA;
    bf16* qkv = slotB;
    float* po = (float*)(ws + 45627136);
    float* pl = po + (size_t)24 * 15 * 2 * 4096;
    const bool sp = ws_size >= T1;

    CvtArgs ca;
    ca.s[0] = qkv_w; ca.d[0] = wq; ca.n8[0] = 1769472 / 8;
    ca.s[1] = out_w; ca.d[1] = wo; ca.n8[1] = 589824 / 8;
    ca.s[2] = fc1_w; ca.d[2] = w1; ca.n8[2] = 2359296 / 8;
    ca.s[3] = fc2_w; ca.d[3] = w2; ca.n8[3] = 2359296 / 8;
    ca.s[4] = qkv_b; ca.d[4] = bq; ca.n8[4] = 2304 / 8;
    ca.s[5] = out_b; ca.d[5] = bo; ca.n8[5] = 768 / 8;
    ca.s[6] = fc1_b; ca.d[6] = b1; ca.n8[6] = 3072 / 8;
    ca.s[7] = fc2_b; ca.d[7] = b2; ca.n8[7] = 768 / 8;
    ca.total8 = (1769472 + 589824 + 2359296 + 2359296 + 2304 + 768 + 3072 +
                 768) / 8;
    cvt_all<<<dim3(880), 256, 0, stream>>>(ca, flag);

    ln_kernel<<<dim3(NT / 4), 256, 0, stream>>>(x, ln1_w, ln1_b, hx, flag);
    gemm_qkv64<<<dim3(18, 64), 256, 0, stream>>>(hx, wq, bq, qkv, vT);
    if (sp) {
      flash_attn_sp<<<dim3(47, 24), 128, 0, stream>>>(qkv, vT, oat, po, pl);
      attn_combine<<<dim3(15, 24), 256, 0, stream>>>(po, pl, oat);
    } else {
      flash_attn_v7<<<dim3(NS / 64, NB * NH), 128, 0, stream>>>(qkv, vT, oat);
    }
    gemm64<2, 64><<<dim3(12, 64), 256, 0, stream>>>(
        oat, wo, bo, x, d_out, ND, ND, 0, flag);
    ln_kernel<<<dim3(NT / 4), 256, 0, stream>>>(d_out, ln2_w, ln2_b, h2, flag);
    if (ws_size >= T1) {
      bf16* ff1 = slotB;
      gemm64<1, 64><<<dim3(48, 64), 256, 0, stream>>>(
          h2, w1, b1, nullptr, ff1, NF, ND, 0, flag);
      gemm64<2, 64><<<dim3(12, 64), 256, 0, stream>>>(
          ff1, w2, b2, d_out, d_out, ND, NF, 0, flag);
    } else {
      bf16* ff1c = slotB;
      for (int c = 0; c < 2; ++c) {
        gemm64<1, 64><<<dim3(48, 32), 256, 0, stream>>>(
            h2 + (size_t)c * 2048 * ND, w1, b1, nullptr, ff1c, NF, ND, 0, flag);
        gemm64<2, 64><<<dim3(12, 32), 256, 0, stream>>>(
            ff1c, w2, b2, d_out, d_out, ND, NF, c * 2048, flag);
      }
    }
  } else if (ws_size >= T4) {
    bf16* wq = (bf16*)(ws + 256);
    bf16* wo = wq + 1769472;
    bf16* w1 = wo + 589824;
    bf16* w2 = w1 + 2359296;
    bf16* bq = w2 + 2359296;
    bf16* bo = bq + 2304;
    bf16* b1 = bo + 768;
    bf16* b2 = b1 + 3072;
    bf16* slotA = b2 + 768;
    bf16* slotB = slotA + (size_t)NT * ND;
    bf16* hx = slotA, *oat = slotA, *h2 = slotA;
    bf16* qkv = slotB;

    CvtArgs ca;
    ca.s[0] = qkv_w; ca.d[0] = wq; ca.n8[0] = 1769472 / 8;
    ca.s[1] = out_w; ca.d[1] = wo; ca.n8[1] = 589824 / 8;
    ca.s[2] = fc1_w; ca.d[2] = w1; ca.n8[2] = 2359296 / 8;
    ca.s[3] = fc2_w; ca.d[3] = w2; ca.n8[3] = 2359296 / 8;
    ca.s[4] = qkv_b; ca.d[4] = bq; ca.n8[4] = 2304 / 8;
    ca.s[5] = out_b; ca.d[5] = bo; ca.n8[5] = 768 / 8;
    ca.s[6] = fc1_b; ca.d[6] = b1; ca.n8[6] = 3072 / 8;
    ca.s[7] = fc2_b; ca.d[7] = b2; ca.n8[7] = 768 / 8;
    ca.total8 = (1769472 + 589824 + 2359296 + 2359296 + 2304 + 768 + 3072 +
                 768) / 8;
    cvt_all<<<dim3(880), 256, 0, stream>>>(ca, flag);

    ln_kernel<<<dim3(NT / 4), 256, 0, stream>>>(x, ln1_w, ln1_b, hx, flag);
    gemm_fast<0, 128><<<dim3(18, 32), 256, 0, stream>>>(
        hx, wq, bq, nullptr, qkv, 3 * ND, ND, 0, flag);
    flash_attn_v1<<<dim3(NS / 64, NB * NH), 256, 0, stream>>>(qkv, oat);
    gemm64<2, 64><<<dim3(12, 64), 256, 0, stream>>>(
        oat, wo, bo, x, d_out, ND, ND, 0, flag);
    ln_kernel<<<dim3(NT / 4), 256, 0, stream>>>(d_out, ln2_w, ln2_b, h2, flag);
    if (ws_size >= T3) {
      bf16* ff1 = slotB;
      gemm64<1, 64><<<dim3(48, 64), 256, 0, stream>>>(
          h2, w1, b1, nullptr, ff1, NF, ND, 0, flag);
      gemm64<2, 64><<<dim3(12, 64), 256, 0, stream>>>(
          ff1, w2, b2, d_out, d_out, ND, NF, 0, flag);
    } else {
      bf16* ff1c = slotB;
      for (int c = 0; c < 2; ++c) {
        gemm64<1, 64><<<dim3(48, 32), 256, 0, stream>>>(
            h2 + (size_t)c * 2048 * ND, w1, b1, nullptr, ff1c, NF, ND, 0, flag);
        gemm64<2, 64><<<dim3(12, 32), 256, 0, stream>>>(
            ff1c, w2, b2, d_out, d_out, ND, NF, c * 2048, flag);
      }
    }
  } else {
    const size_t szTD = (size_t)NT * ND * sizeof(bf16);
    bf16* slotA = (bf16*)(ws + 256);
    bf16* qkv = (bf16*)(ws + 256 + szTD);
    bf16* hx = slotA, *oat = slotA, *h2 = slotA;
    bf16* ff1c = qkv;

    ln_kernel<<<dim3(NT / 4), 256, 0, stream>>>(x, ln1_w, ln1_b, hx, flag);
    gemm_bt<0><<<dim3(18, 32), 256, 0, stream>>>(
        hx, qkv_w, qkv_b, nullptr, qkv, 3 * ND, ND, 0, flag);
    flash_attn_v1<<<dim3(NS / 64, NB * NH), 256, 0, stream>>>(qkv, oat);
    gemm_bt<2><<<dim3(6, 32), 256, 0, stream>>>(
        oat, out_w, out_b, x, d_out, ND, ND, 0, flag);
    ln_kernel<<<dim3(NT / 4), 256, 0, stream>>>(d_out, ln2_w, ln2_b, h2, flag);
    for (int c = 0; c < 4; ++c) {
      gemm_bt<1><<<dim3(24, 8), 256, 0, stream>>>(
          h2 + (size_t)c * 1024 * ND, fc1_w, fc1_b, nullptr, ff1c, NF, ND, 0,
          flag);
      gemm_bt<2><<<dim3(6, 8), 256, 0, stream>>>(
          ff1c, fc2_w, fc2_b, d_out, d_out, ND, NF, c * 1024, flag);
    }
  }
}